// Round 16
// baseline (212.454 us; speedup 1.0000x reference)
//
#include <hip/hip_runtime.h>
#include <hip/hip_bf16.h>

typedef __attribute__((ext_vector_type(8))) short s8v;
typedef __attribute__((ext_vector_type(4))) float f4v;
typedef __attribute__((ext_vector_type(16))) float f16v;
typedef __attribute__((ext_vector_type(4))) unsigned u4v;

typedef __attribute__((address_space(1))) const void as1_void;
typedef __attribute__((address_space(3))) void as3_void;

__device__ __forceinline__ void gl16(const void* g, void* l) {
  __builtin_amdgcn_global_load_lds((as1_void*)g, (as3_void*)l, 16, 0, 0);
}

__device__ __forceinline__ float b2f(int u) {
  union { float f; unsigned i; } c; c.i = ((unsigned)(u & 0xFFFF)) << 16; return c.f;
}
__device__ __forceinline__ unsigned short f2b(float f) {   // RNE
  union { float f; unsigned i; } c; c.f = f;
  unsigned r = c.i + 0x7FFFu + ((c.i >> 16) & 1u);
  return (unsigned short)(r >> 16);
}
__device__ __forceinline__ unsigned pk2(float lo, float hi) {  // 2xbf16 pack
  unsigned u;
  asm("v_cvt_pk_bf16_f32 %0, %1, %2" : "=v"(u) : "v"(lo), "v"(hi));
  return u;
}

#define MFMA16(a, b, c) __builtin_amdgcn_mfma_f32_16x16x32_bf16((a), (b), (c), 0, 0, 0)
#define MFMA32(a, b, c) __builtin_amdgcn_mfma_f32_32x32x16_bf16((a), (b), (c), 0, 0, 0)

// XCD-aware bijective block remap (grid % 8 == 0): contiguous logical blocks per XCD.
__device__ __forceinline__ void xcd_remap(int nbn, int& bm, int& bn) {
  const int flat = blockIdx.x;
  const int u = (flat & 7) * ((int)gridDim.x >> 3) + (flat >> 3);
  bm = u / nbn;
  bn = u - bm * nbn;
}

// -------- fused prep: weight converts (+gu interleave) + rope tables + rmsnorm1 --------
struct Seg { const float* src; unsigned short* dst; int K; int N; int nbn; int nblocks; int mode; };
struct PrepArgs { Seg seg[9]; float* ct; float* st; const float* wn1; };

__global__ __launch_bounds__(256) void prep_k(PrepArgs a) {
  int b = blockIdx.x, si = 0;
  while (si < 8 && b >= a.seg[si].nblocks) { b -= a.seg[si].nblocks; ++si; }
  const Seg s = a.seg[si];
  const int tid = threadIdx.x;
  if (s.mode == 3) {               // rope tables [4096][32]
    const int t = b * 256 + tid;
    const int sq = t >> 5, d = t & 31;
    const float inv = powf(10000.0f, -(float)d * (1.0f / 32.0f));
    const float ang = (float)sq * inv;
    a.ct[t] = cosf(ang);
    a.st[t] = sinf(ang);
    return;
  }
  if (s.mode == 4) {               // rmsnorm1: x row b -> bf16
    const float* xr = s.src + (size_t)b * 768;
    float v0 = xr[tid], v1 = xr[tid + 256], v2 = xr[tid + 512];
    float ss = v0 * v0 + v1 * v1 + v2 * v2;
#pragma unroll
    for (int m = 1; m < 64; m <<= 1) ss += __shfl_xor(ss, m, 64);
    __shared__ float sred[4];
    if ((tid & 63) == 0) sred[tid >> 6] = ss;
    __syncthreads();
    const float tot = sred[0] + sred[1] + sred[2] + sred[3];
    const float rn = rsqrtf(tot * (1.0f / 768.0f) + 1e-6f);
    unsigned short* orow = s.dst + (size_t)b * 768;
    orow[tid]       = f2b(v0 * rn * a.wn1[tid]);
    orow[tid + 256] = f2b(v1 * rn * a.wn1[tid + 256]);
    orow[tid + 512] = f2b(v2 * rn * a.wn1[tid + 512]);
    return;
  }
  __shared__ float tile[32][33];
  const int tx = tid & 31, ty = tid >> 5;
  const int bn = b % s.nbn, bk = b / s.nbn;
#pragma unroll
  for (int i = 0; i < 32; i += 8)
    tile[ty + i][tx] = s.src[(size_t)(bk * 32 + ty + i) * s.N + bn * 32 + tx];
  __syncthreads();
#pragma unroll
  for (int i = 0; i < 32; i += 8) {
    int row;
    if (s.mode == 0)      row = bn * 32 + ty + i;
    else                  row = bn * 64 + (s.mode == 2 ? 32 : 0) + ty + i;
    s.dst[(size_t)row * s.K + bk * 32 + tx] = f2b(tile[tx][ty + i]);
  }
}

// ---------------- RMSNorm: bf16 in -> bf16 out, D=768 ----------------
__global__ __launch_bounds__(256) void rmsnorm_b16_k(const unsigned short* __restrict__ x,
    const float* __restrict__ w, unsigned short* __restrict__ out) {
  const int row = blockIdx.x, tid = threadIdx.x;
  const unsigned short* xr = x + (size_t)row * 768;
  float v0 = b2f(xr[tid]), v1 = b2f(xr[tid + 256]), v2 = b2f(xr[tid + 512]);
  float ss = v0 * v0 + v1 * v1 + v2 * v2;
#pragma unroll
  for (int m = 1; m < 64; m <<= 1) ss += __shfl_xor(ss, m, 64);
  __shared__ float sred[4];
  if ((tid & 63) == 0) sred[tid >> 6] = ss;
  __syncthreads();
  const float tot = sred[0] + sred[1] + sred[2] + sred[3];
  const float rn = rsqrtf(tot * (1.0f / 768.0f) + 1e-6f);
  unsigned short* orow = out + (size_t)row * 768;
  orow[tid]       = f2b(v0 * rn * w[tid]);
  orow[tid + 256] = f2b(v1 * rn * w[tid + 256]);
  orow[tid + 512] = f2b(v2 * rn * w[tid + 512]);
}

// ---------------- GEMM template: BM x BN tile, 256 thr, 3-buffer counted-vmcnt pipeline ----
// EPI 2: bf16 store + RoPE (bn<12 heads) + Q pre-scale by 0.125*log2e (bn covering q cols)
// EPI 4: bf16 store of (v + Rf[fp32])           (wo + residual -> h bf16)
// EPI 5: fp32 store of (v + b2f(Rb[bf16]))      (down + residual -> d_out)
template <int EPI, int BM, int BN>
__global__ __launch_bounds__(256) void gemm_bt(const unsigned short* __restrict__ A,
    const unsigned short* __restrict__ Bt, unsigned short* __restrict__ Cb,
    float* __restrict__ Cf, const float* __restrict__ Rf, const unsigned short* __restrict__ Rb,
    int K, int ldc, const float* __restrict__ ct, const float* __restrict__ st, int nbn) {
  constexpr int ABYTES = BM * 32 * 2;
  constexpr int BBYTES = BN * 32 * 2;
  constexpr int APASS = BM / 64, BPASS = BN / 64;
  constexpr int LPS = APASS + BPASS;
  constexpr bool W2x2 = (BN == 128);
  constexpr int MR = W2x2 ? (BM / 32) : (BM / 64);
  __shared__ unsigned short As[3 * BM * 32];
  __shared__ unsigned short Bs[3 * BN * 32];
  const int tid = threadIdx.x;
  const int lane = tid & 63, wid = tid >> 6;
  const int wrow = W2x2 ? (wid >> 1) * (BM / 2) : wid * (BM / 4);
  const int wcol = W2x2 ? (wid & 1) * 64 : 0;
  const int l15 = lane & 15, l4 = lane >> 4;
  int bm, bn;
  xcd_remap(nbn, bm, bn);

  f4v acc[MR][4] = {};

  const int o0 = tid * 16, o1 = tid * 16 + 4096;
  const int r0 = o0 >> 6, c0 = o0 & 63;
  const int r1 = o1 >> 6, c1 = o1 & 63;
  const size_t ldab = (size_t)K * 2;
  const char* Abyte = (const char*)A;
  const char* Bbyte = (const char*)Bt;
  const size_t a0 = (size_t)(bm * BM + r0) * ldab + c0;
  const size_t a1 = (size_t)(bm * BM + (APASS == 2 ? r1 : r0)) * ldab + c1;
  const size_t b0 = (size_t)(bn * BN + r0) * ldab + c0;
  const size_t b1 = (size_t)(bn * BN + (BPASS == 2 ? r1 : r0)) * ldab + c1;
  char* AsB = (char*)As;
  char* BsB = (char*)Bs;
  const int uoff = wid << 10;

#define STAGEK(I, SL) do { const size_t kb = (size_t)(I) * 64;                 \
    char* Aw = AsB + (SL) * ABYTES;                                            \
    char* Bw = BsB + (SL) * BBYTES;                                            \
    gl16(Abyte + a0 + kb, Aw + uoff);                                          \
    if constexpr (APASS == 2) gl16(Abyte + a1 + kb, Aw + uoff + 4096);         \
    gl16(Bbyte + b0 + kb, Bw + uoff);                                          \
    if constexpr (BPASS == 2) gl16(Bbyte + b1 + kb, Bw + uoff + 4096); } while (0)

  const int NI = K >> 5;
  STAGEK(0, 0);
  STAGEK(1, 1);
  int sel = 0, nsl = 2;

  for (int i = 0; i < NI; ++i) {
    if (i < NI - 1) {
      if constexpr (LPS == 4)      asm volatile("s_waitcnt vmcnt(4)" ::: "memory");
      else if constexpr (LPS == 3) asm volatile("s_waitcnt vmcnt(3)" ::: "memory");
      else                         asm volatile("s_waitcnt vmcnt(2)" ::: "memory");
    } else {
      asm volatile("s_waitcnt vmcnt(0)" ::: "memory");
    }
    __builtin_amdgcn_s_barrier();
    __builtin_amdgcn_sched_barrier(0);
    if (i + 2 < NI) STAGEK(i + 2, nsl);
    const char* Ar = AsB + sel * ABYTES;
    const char* Br = BsB + sel * BBYTES;
    s8v af[MR], bf[4];
#pragma unroll
    for (int m = 0; m < MR; ++m)
      af[m] = *(const s8v*)(Ar + (wrow + m * 16 + l15) * 64 + l4 * 16);
#pragma unroll
    for (int n = 0; n < 4; ++n)
      bf[n] = *(const s8v*)(Br + (wcol + n * 16 + l15) * 64 + l4 * 16);
    __builtin_amdgcn_s_setprio(1);
#pragma unroll
    for (int m = 0; m < MR; ++m)
#pragma unroll
      for (int n = 0; n < 4; ++n) acc[m][n] = MFMA16(af[m], bf[n], acc[m][n]);
    __builtin_amdgcn_s_setprio(0);
    sel = (sel == 2) ? 0 : sel + 1;
    nsl = (nsl == 2) ? 0 : nsl + 1;
  }
#undef STAGEK

  const int row0 = bm * BM + wrow;
  const int col0 = bn * BN + wcol;

  if constexpr (EPI == 2) {        // RoPE + Q pre-scale (BN=128: wave spans one head)
    const int colw = col0;         // this wave's 64-col span start
    if (colw < 1536) {             // q|k region: RoPE
#pragma unroll
      for (int m = 0; m < MR; ++m)
#pragma unroll
        for (int r = 0; r < 4; ++r) {
          const int row = row0 + m * 16 + l4 * 4 + r;
#pragma unroll
          for (int n = 0; n < 2; ++n) {
            const int d = n * 16 + l15;
            const float c  = ct[row * 32 + d];
            const float sn = st[row * 32 + d];
            const float aa = acc[m][n][r], bb = acc[m][n + 2][r];
            acc[m][n][r]     = aa * c - bb * sn;
            acc[m][n + 2][r] = bb * c + aa * sn;
          }
        }
    }
    if (colw < 768) {              // q region: pre-scale
      const float QSC = 0.18033688011112042f;
#pragma unroll
      for (int m = 0; m < MR; ++m)
#pragma unroll
        for (int n = 0; n < 4; ++n)
#pragma unroll
          for (int r = 0; r < 4; ++r) acc[m][n][r] *= QSC;
    }
  }

#pragma unroll
  for (int m = 0; m < MR; ++m)
#pragma unroll
    for (int n = 0; n < 4; ++n)
#pragma unroll
      for (int r = 0; r < 4; ++r) {
        const int row = row0 + m * 16 + l4 * 4 + r;
        const int col = col0 + n * 16 + l15;
        const float v = acc[m][n][r];
        const size_t idx = (size_t)row * ldc + col;
        if (EPI == 4)      Cb[idx] = f2b(v + Rf[idx]);
        else if (EPI == 5) Cf[idx] = v + b2f(Rb[idx]);
        else               Cb[idx] = f2b(v);
      }
}

// ---------------- big GEMM: 256(M)x128(N) tile, 512 thr, 8 waves (4Mx2N), BK=32 ----------------
template <int EPI>
__global__ __launch_bounds__(512, 2) void gemm_big(const unsigned short* __restrict__ A,
    const unsigned short* __restrict__ Bt, unsigned short* __restrict__ Cb,
    int K, int ldc, int nbn) {
  constexpr int ABYTES = 256 * 32 * 2;
  constexpr int BBYTES = 128 * 32 * 2;
  __shared__ unsigned short As[3 * 256 * 32];
  __shared__ unsigned short Bs[3 * 128 * 32];
  const int tid = threadIdx.x;
  const int lane = tid & 63, wid = tid >> 6;
  const int wm = wid >> 1, wn = wid & 1;
  const int wrow = wm * 64, wcol = wn * 64;
  const int l15 = lane & 15, l4 = lane >> 4;
  int bm, bn;
  xcd_remap(nbn, bm, bn);

  f4v acc[4][4] = {};

  const size_t ldab = (size_t)K * 2;
  const char* Ab = (const char*)A;
  const char* Bb = (const char*)Bt;
  const int lrow = lane >> 2, lch = (lane & 3) * 16;
  const size_t aS0 = (size_t)(bm * 256 + wid * 16 + lrow) * ldab + lch;
  const size_t aS1 = (size_t)(bm * 256 + (wid + 8) * 16 + lrow) * ldab + lch;
  const size_t bS  = (size_t)(bn * 128 + wid * 16 + lrow) * ldab + lch;
  char* AsB = (char*)As;
  char* BsB = (char*)Bs;
  const int uA0 = wid << 10, uA1 = (wid + 8) << 10, uB = wid << 10;

#define STAGEK(I, SL) do { const size_t kb = (size_t)(I) * 64;                 \
    gl16(Ab + aS0 + kb, AsB + (SL) * ABYTES + uA0);                            \
    gl16(Ab + aS1 + kb, AsB + (SL) * ABYTES + uA1);                            \
    gl16(Bb + bS  + kb, BsB + (SL) * BBYTES + uB); } while (0)

  const int NI = K >> 5;
  STAGEK(0, 0);
  STAGEK(1, 1);
  int sel = 0, nsl = 2;

  for (int i = 0; i < NI; ++i) {
    if (i < NI - 1) asm volatile("s_waitcnt vmcnt(3)" ::: "memory");
    else            asm volatile("s_waitcnt vmcnt(0)" ::: "memory");
    __builtin_amdgcn_s_barrier();
    __builtin_amdgcn_sched_barrier(0);
    if (i + 2 < NI) STAGEK(i + 2, nsl);
    const char* Ar = AsB + sel * ABYTES;
    const char* Br = BsB + sel * BBYTES;
    s8v af[4], bf[4];
#pragma unroll
    for (int m = 0; m < 4; ++m)
      af[m] = *(const s8v*)(Ar + (wrow + m * 16 + l15) * 64 + l4 * 16);
#pragma unroll
    for (int n = 0; n < 4; ++n)
      bf[n] = *(const s8v*)(Br + (wcol + n * 16 + l15) * 64 + l4 * 16);
    __builtin_amdgcn_s_setprio(1);
#pragma unroll
    for (int m = 0; m < 4; ++m)
#pragma unroll
      for (int n = 0; n < 4; ++n) acc[m][n] = MFMA16(af[m], bf[n], acc[m][n]);
    __builtin_amdgcn_s_setprio(0);
    sel = (sel == 2) ? 0 : sel + 1;
    nsl = (nsl == 2) ? 0 : nsl + 1;
  }
#undef STAGEK

  const int row0 = bm * 256 + wrow;
  const int col0 = bn * 128 + wcol;

  if (EPI == 3) {                  // silu(g)*u, g at n<2, u at n+2
    const int colb = (bn * 2 + wn) * 32;
#pragma unroll
    for (int m = 0; m < 4; ++m)
#pragma unroll
      for (int n = 0; n < 2; ++n)
#pragma unroll
        for (int r = 0; r < 4; ++r) {
          const int row = row0 + m * 16 + l4 * 4 + r;
          const float g = acc[m][n][r], u = acc[m][n + 2][r];
          const float val = g * u / (1.0f + __expf(-g));
          Cb[(size_t)row * 2048 + colb + n * 16 + l15] = f2b(val);
        }
    return;
  }

#pragma unroll
  for (int m = 0; m < 4; ++m)
#pragma unroll
    for (int n = 0; n < 4; ++n)
#pragma unroll
      for (int r = 0; r < 4; ++r) {
        const int row = row0 + m * 16 + l4 * 4 + r;
        const int col = col0 + n * 16 + l15;
        Cb[(size_t)row * ldc + col] = f2b(acc[m][n][r]);
      }
}

// ---------------- causal flash attention: 32x32 swapped-QK, 2-way parity, NO online max ----------------
__global__ __launch_bounds__(256, 4) void flash_k(const unsigned short* __restrict__ qkv,
    uint2* __restrict__ Opart, float* __restrict__ ml) {
  const int kh = blockIdx.x, p = blockIdx.y, h = blockIdx.z;
  const int qbA = 63 - p;
  const int tid = threadIdx.x;
  const int wv = tid >> 6, lane = tid & 63;
  const int l31 = lane & 31, h8 = lane >> 5;
  const int myqb = (wv & 1) ? p : qbA;
  const int qrel = (wv >> 1) * 32 + l31;
  const int q_abs = myqb * 64 + qrel;

  __shared__ unsigned short Ks[2][64 * 72];
  __shared__ unsigned short Vt[2][64 * 72];

  const unsigned short* qp = qkv + h * 64;
  const unsigned short* kp = qkv + 768 + h * 64;
  const unsigned short* vp = qkv + 1536 + h * 64;

  s8v qf[4];
#pragma unroll
  for (int cc = 0; cc < 4; ++cc)
    qf[cc] = *(const s8v*)(qp + (size_t)q_abs * 2304 + cc * 16 + h8 * 8);

  f16v o0 = {}, o1 = {};
  float lp = 0.f;

  const int krow = tid >> 3, kc = (tid & 7) * 8;
  const int vj = tid & 31, vd0 = (tid >> 5) * 8;

  s8v ka, kb, va, vb;
#define LOADT(T) do { const size_t k0n = (size_t)(T) * 64;                    \
    ka = *(const s8v*)(kp + (k0n + krow) * 2304 + kc);                        \
    kb = *(const s8v*)(kp + (k0n + krow + 32) * 2304 + kc);                   \
    va = *(const s8v*)(vp + (k0n + 2 * vj) * 2304 + vd0);                     \
    vb = *(const s8v*)(vp + (k0n + 2 * vj + 1) * 2304 + vd0); } while (0)
#define WRITET(BUF) do {                                                      \
    *(s8v*)(Ks[BUF] + krow * 72 + kc) = ka;                                   \
    *(s8v*)(Ks[BUF] + (krow + 32) * 72 + kc) = kb;                            \
    unsigned* vtw = (unsigned*)(Vt[BUF] + (size_t)vd0 * 72 + 2 * vj);         \
    _Pragma("unroll")                                                         \
    for (int i = 0; i < 8; ++i)                                               \
      vtw[i * 36] = ((unsigned)(unsigned short)va[i]) |                       \
                    (((unsigned)(unsigned short)vb[i]) << 16); } while (0)

  LOADT(kh);
  WRITET(0);
  if (kh + 2 <= qbA) LOADT(kh + 2);
  __syncthreads();

  for (int t = kh; t <= qbA; t += 2) {
    const int cur = (t >> 1) & 1;
    if (t <= myqb) {
      f16v s0 = {}, s1 = {};
      __builtin_amdgcn_s_setprio(1);
#pragma unroll
      for (int cc = 0; cc < 4; ++cc) {
        const s8v kf0 = *(const s8v*)(Ks[cur] + l31 * 72 + cc * 16 + h8 * 8);
        const s8v kf1 = *(const s8v*)(Ks[cur] + (32 + l31) * 72 + cc * 16 + h8 * 8);
        s0 = MFMA32(kf0, qf[cc], s0);
        s1 = MFMA32(kf1, qf[cc], s1);
      }
      __builtin_amdgcn_s_setprio(0);
      if (t == myqb) {
#pragma unroll
        for (int rr = 0; rr < 16; ++rr) {
          const int koff = (rr & 3) + 8 * (rr >> 2) + 4 * h8;
          if (koff > qrel) s0[rr] = -1e30f;
          if (koff + 32 > qrel) s1[rr] = -1e30f;
        }
      }
#pragma unroll
      for (int rr = 0; rr < 16; ++rr) {
        s0[rr] = exp2f(s0[rr]);
        s1[rr] = exp2f(s1[rr]);
      }
      float sm[8];
#pragma unroll
      for (int i = 0; i < 8; ++i) sm[i] = (s0[i] + s0[i + 8]) + (s1[i] + s1[i + 8]);
#pragma unroll
      for (int i = 0; i < 4; ++i) sm[i] += sm[i + 4];
      lp += (sm[0] + sm[1]) + (sm[2] + sm[3]);

      unsigned pk0[8], pk1[8];
#pragma unroll
      for (int g = 0; g < 4; ++g)
#pragma unroll
        for (int j = 0; j < 2; ++j) {
          pk0[g * 2 + j] = pk2(s0[g * 4 + 2 * j], s0[g * 4 + 2 * j + 1]);
          pk1[g * 2 + j] = pk2(s1[g * 4 + 2 * j], s1[g * 4 + 2 * j + 1]);
        }
      __builtin_amdgcn_s_setprio(1);
#pragma unroll
      for (int cc = 0; cc < 4; ++cc) {
        const int g0 = (cc & 1) * 2, g1 = g0 + 1;
        const unsigned pA0 = (cc & 2) ? pk1[g0 * 2 + 0] : pk0[g0 * 2 + 0];
        const unsigned pA1 = (cc & 2) ? pk1[g0 * 2 + 1] : pk0[g0 * 2 + 1];
        const unsigned pB0 = (cc & 2) ? pk1[g1 * 2 + 0] : pk0[g1 * 2 + 0];
        const unsigned pB1 = (cc & 2) ? pk1[g1 * 2 + 1] : pk0[g1 * 2 + 1];
        const unsigned t00 = __shfl_xor((int)pA0, 32);
        const unsigned t01 = __shfl_xor((int)pA1, 32);
        const unsigned t10 = __shfl_xor((int)pB0, 32);
        const unsigned t11 = __shfl_xor((int)pB1, 32);
        union { u4v u; s8v s; } pf;
        pf.u[0] = h8 ? t10 : pA0;
        pf.u[1] = h8 ? t11 : pA1;
        pf.u[2] = h8 ? pB0 : t00;
        pf.u[3] = h8 ? pB1 : t01;
        const s8v vf0 = *(const s8v*)(Vt[cur] + l31 * 72 + cc * 16 + h8 * 8);
        const s8v vf1 = *(const s8v*)(Vt[cur] + (32 + l31) * 72 + cc * 16 + h8 * 8);
        o0 = MFMA32(vf0, pf.s, o0);
        o1 = MFMA32(vf1, pf.s, o1);
      }
      __builtin_amdgcn_s_setprio(0);
    }
    if (t + 2 <= qbA) {
      WRITET(cur ^ 1);
      if (t + 4 <= qbA) LOADT(t + 4);
      __syncthreads();
    }
  }

  lp += __shfl_xor(lp, 32);

  const size_t obase = ((size_t)kh * 12 + h) * 16 * 4096;
#pragma unroll
  for (int g = 0; g < 4; ++g) {
    const uint2 v0 = make_uint2(pk2(o0[g * 4], o0[g * 4 + 1]), pk2(o0[g * 4 + 2], o0[g * 4 + 3]));
    const uint2 v1 = make_uint2(pk2(o1[g * 4], o1[g * 4 + 1]), pk2(o1[g * 4 + 2], o1[g * 4 + 3]));
    Opart[obase + (size_t)(2 * g + h8) * 4096 + q_abs] = v0;
    Opart[obase + (size_t)(8 + 2 * g + h8) * 4096 + q_abs] = v1;
  }
  if (h8 == 0)
    ml[((size_t)kh * 12 + h) * 4096 + q_abs] = lp;
#undef LOADT
#undef WRITET
}

// ---------------- combine 2 key-parity partials -> attn bf16 [q][768] ----------------
__global__ __launch_bounds__(256) void combine_k(const uint2* __restrict__ Opart,
    const float* __restrict__ ml, unsigned short* __restrict__ out) {
  const int u = blockIdx.x * 256 + threadIdx.x;
  const int q = u & 4095;
  const int rest = u >> 12;
  const int dgrp = rest & 15;
  const int h = rest >> 4;
  const float l0 = ml[h * 4096 + q];
  const float l1 = ml[12 * 4096 + h * 4096 + q];
  const float inv = 1.0f / (l0 + l1);
  const size_t idx = ((size_t)h * 16 + dgrp) * 4096 + q;
  const uint2 a = Opart[idx];
  const uint2 b = Opart[(size_t)12 * 16 * 4096 + idx];
  const int dbase = (dgrp < 8) ? 4 * dgrp : 32 + 4 * (dgrp - 8);
  ushort4 r;
  r.x = f2b((b2f(a.x) + b2f(b.x)) * inv);
  r.y = f2b((b2f(a.x >> 16) + b2f(b.x >> 16)) * inv);
  r.z = f2b((b2f(a.y) + b2f(b.y)) * inv);
  r.w = f2b((b2f(a.y >> 16) + b2f(b.y >> 16)) * inv);
  *(ushort4*)(out + (size_t)q * 768 + h * 64 + dbase) = r;
}

extern "C" void kernel_launch(void* const* d_in, const int* in_sizes, int n_in,
                              void* d_out, int out_size, void* d_ws, size_t ws_size,
                              hipStream_t stream) {
  const float* x    = (const float*)d_in[0];
  const float* w_q  = (const float*)d_in[1];
  const float* w_k  = (const float*)d_in[2];
  const float* w_v  = (const float*)d_in[3];
  const float* w_o  = (const float*)d_in[4];
  const float* w_g  = (const float*)d_in[5];
  const float* w_u  = (const float*)d_in[6];
  const float* w_d  = (const float*)d_in[7];
  const float* w_n1 = (const float*)d_in[8];
  const float* w_n2 = (const float*)d_in[9];
  (void)in_sizes; (void)n_in; (void)out_size; (void)ws_size;

  char* ws = (char*)d_ws;
  size_t off = 0;
  auto alloc = [&](size_t bytes) { char* p = ws + off; off += (bytes + 255) & ~(size_t)255; return p; };
  unsigned short* wqkvT = (unsigned short*)alloc(2304ull * 768 * 2);
  unsigned short* woT   = (unsigned short*)alloc(768ull * 768 * 2);
  unsigned short* wguT  = (unsigned short*)alloc(4096ull * 768 * 2);
  unsigned short* wdT   = (unsigned short*)alloc(768ull * 2048 * 2);
  float* ct             = (float*)alloc(4096ull * 32 * 4);
  float* st             = (float*)alloc(4096ull * 32 * 4);
  unsigned short* xn    = (unsigned short*)alloc(4096ull * 768 * 2);
  unsigned short* qkv   = (unsigned short*)alloc(4096ull * 2304 * 2);
  unsigned short* attn  = (unsigned short*)alloc(4096ull * 768 * 2);
  unsigned short* hb16  = (unsigned short*)alloc(4096ull * 768 * 2);
  unsigned short* ybuf  = (unsigned short*)alloc(4096ull * 768 * 2);
  unsigned short* ffn   = (unsigned short*)alloc(4096ull * 2048 * 2);
  uint2* Opart          = (uint2*)alloc(2ull * 12 * 16 * 4096 * 8);
  float* mlb            = (float*)alloc(2ull * 12 * 4096 * 4);

  PrepArgs pa;
  pa.seg[0] = { w_q, wqkvT,                 768,  768, 24,  576, 0 };
  pa.seg[1] = { w_k, wqkvT + 768 * 768,     768,  768, 24,  576, 0 };
  pa.seg[2] = { w_v, wqkvT + 2 * 768 * 768, 768,  768, 24,  576, 0 };
  pa.seg[3] = { w_o, woT,                   768,  768, 24,  576, 0 };
  pa.seg[4] = { w_g, wguT,                  768, 2048, 64, 1536, 1 };
  pa.seg[5] = { w_u, wguT,                  768, 2048, 64, 1536, 2 };
  pa.seg[6] = { w_d, wdT,                  2048,  768, 24, 1536, 0 };
  pa.seg[7] = { nullptr, nullptr, 0, 0, 0, 512, 3 };
  pa.seg[8] = { x, xn, 0, 0, 0, 4096, 4 };
  pa.ct = ct; pa.st = st; pa.wn1 = w_n1;
  const int prep_blocks = 576 * 4 + 1536 * 3 + 512 + 4096;   // 11520

  prep_k<<<prep_blocks, 256, 0, stream>>>(pa);
  // qkv = xn @ [Wq|Wk|Wv] + RoPE + Q pre-scale; 1152 blocks = 64(M/64) x 18(N/128), 4.5/CU
  gemm_bt<2, 64, 128><<<1152, 256, 0, stream>>>(xn, wqkvT, qkv, nullptr, nullptr, nullptr, 768, 2304, ct, st, 18);
  flash_k<<<dim3(2, 32, 12), 256, 0, stream>>>(qkv, Opart, mlb);
  combine_k<<<3072, 256, 0, stream>>>(Opart, mlb, attn);
  // h = attn @ Wo + x (bf16 out); 768 blocks = 64 x 12, exactly 3/CU
  gemm_bt<4, 64, 64><<<768, 256, 0, stream>>>(attn, woT, hb16, nullptr, x, nullptr, 768, 768, nullptr, nullptr, 12);
  rmsnorm_b16_k<<<4096, 256, 0, stream>>>(hb16, w_n2, ybuf);
  // ffn = silu(y@Wg)*(y@Wu); 512 blocks = 16 x 32, exactly 2/CU
  gemm_big<3><<<512, 512, 0, stream>>>(ybuf, wguT, ffn, 768, 2048, 32);
  // out = ffn @ Wd + h(bf16); 768 blocks = 64 x 12, exactly 3/CU
  gemm_bt<5, 64, 64><<<768, 256, 0, stream>>>(ffn, wdT, nullptr, (float*)d_out, nullptr, hb16, 2048, 768, nullptr, nullptr, 12);
}

// Round 17
// 201.435 us; speedup vs baseline: 1.0547x; 1.0547x over previous
//
#include <hip/hip_runtime.h>
#include <hip/hip_bf16.h>

typedef __attribute__((ext_vector_type(8))) short s8v;
typedef __attribute__((ext_vector_type(4))) float f4v;
typedef __attribute__((ext_vector_type(16))) float f16v;
typedef __attribute__((ext_vector_type(4))) unsigned u4v;

typedef __attribute__((address_space(1))) const void as1_void;
typedef __attribute__((address_space(3))) void as3_void;

__device__ __forceinline__ void gl16(const void* g, void* l) {
  __builtin_amdgcn_global_load_lds((as1_void*)g, (as3_void*)l, 16, 0, 0);
}

__device__ __forceinline__ float b2f(int u) {
  union { float f; unsigned i; } c; c.i = ((unsigned)(u & 0xFFFF)) << 16; return c.f;
}
__device__ __forceinline__ unsigned short f2b(float f) {   // RNE
  union { float f; unsigned i; } c; c.f = f;
  unsigned r = c.i + 0x7FFFu + ((c.i >> 16) & 1u);
  return (unsigned short)(r >> 16);
}
__device__ __forceinline__ unsigned pk2(float lo, float hi) {  // 2xbf16 pack
  unsigned u;
  asm("v_cvt_pk_bf16_f32 %0, %1, %2" : "=v"(u) : "v"(lo), "v"(hi));
  return u;
}

#define MFMA16(a, b, c) __builtin_amdgcn_mfma_f32_16x16x32_bf16((a), (b), (c), 0, 0, 0)
#define MFMA32(a, b, c) __builtin_amdgcn_mfma_f32_32x32x16_bf16((a), (b), (c), 0, 0, 0)

// XCD-aware bijective block remap (grid % 8 == 0): contiguous logical blocks per XCD.
__device__ __forceinline__ void xcd_remap(int nbn, int& bm, int& bn) {
  const int flat = blockIdx.x;
  const int u = (flat & 7) * ((int)gridDim.x >> 3) + (flat >> 3);
  bm = u / nbn;
  bn = u - bm * nbn;
}

// -------- fused prep: weight converts (+gu interleave) + rope tables + rmsnorm1 --------
struct Seg { const float* src; unsigned short* dst; int K; int N; int nbn; int nblocks; int mode; };
struct PrepArgs { Seg seg[9]; float* ct; float* st; const float* wn1; };

__global__ __launch_bounds__(256) void prep_k(PrepArgs a) {
  int b = blockIdx.x, si = 0;
  while (si < 8 && b >= a.seg[si].nblocks) { b -= a.seg[si].nblocks; ++si; }
  const Seg s = a.seg[si];
  const int tid = threadIdx.x;
  if (s.mode == 3) {               // rope tables [4096][32]
    const int t = b * 256 + tid;
    const int sq = t >> 5, d = t & 31;
    const float inv = powf(10000.0f, -(float)d * (1.0f / 32.0f));
    const float ang = (float)sq * inv;
    a.ct[t] = cosf(ang);
    a.st[t] = sinf(ang);
    return;
  }
  if (s.mode == 4) {               // rmsnorm1: x row b -> bf16
    const float* xr = s.src + (size_t)b * 768;
    float v0 = xr[tid], v1 = xr[tid + 256], v2 = xr[tid + 512];
    float ss = v0 * v0 + v1 * v1 + v2 * v2;
#pragma unroll
    for (int m = 1; m < 64; m <<= 1) ss += __shfl_xor(ss, m, 64);
    __shared__ float sred[4];
    if ((tid & 63) == 0) sred[tid >> 6] = ss;
    __syncthreads();
    const float tot = sred[0] + sred[1] + sred[2] + sred[3];
    const float rn = rsqrtf(tot * (1.0f / 768.0f) + 1e-6f);
    unsigned short* orow = s.dst + (size_t)b * 768;
    orow[tid]       = f2b(v0 * rn * a.wn1[tid]);
    orow[tid + 256] = f2b(v1 * rn * a.wn1[tid + 256]);
    orow[tid + 512] = f2b(v2 * rn * a.wn1[tid + 512]);
    return;
  }
  __shared__ float tile[32][33];
  const int tx = tid & 31, ty = tid >> 5;
  const int bn = b % s.nbn, bk = b / s.nbn;
#pragma unroll
  for (int i = 0; i < 32; i += 8)
    tile[ty + i][tx] = s.src[(size_t)(bk * 32 + ty + i) * s.N + bn * 32 + tx];
  __syncthreads();
#pragma unroll
  for (int i = 0; i < 32; i += 8) {
    int row;
    if (s.mode == 0)      row = bn * 32 + ty + i;
    else                  row = bn * 64 + (s.mode == 2 ? 32 : 0) + ty + i;
    s.dst[(size_t)row * s.K + bk * 32 + tx] = f2b(tile[tx][ty + i]);
  }
}

// ---------------- RMSNorm: bf16 in -> bf16 out, D=768 ----------------
__global__ __launch_bounds__(256) void rmsnorm_b16_k(const unsigned short* __restrict__ x,
    const float* __restrict__ w, unsigned short* __restrict__ out) {
  const int row = blockIdx.x, tid = threadIdx.x;
  const unsigned short* xr = x + (size_t)row * 768;
  float v0 = b2f(xr[tid]), v1 = b2f(xr[tid + 256]), v2 = b2f(xr[tid + 512]);
  float ss = v0 * v0 + v1 * v1 + v2 * v2;
#pragma unroll
  for (int m = 1; m < 64; m <<= 1) ss += __shfl_xor(ss, m, 64);
  __shared__ float sred[4];
  if ((tid & 63) == 0) sred[tid >> 6] = ss;
  __syncthreads();
  const float tot = sred[0] + sred[1] + sred[2] + sred[3];
  const float rn = rsqrtf(tot * (1.0f / 768.0f) + 1e-6f);
  unsigned short* orow = out + (size_t)row * 768;
  orow[tid]       = f2b(v0 * rn * w[tid]);
  orow[tid + 256] = f2b(v1 * rn * w[tid + 256]);
  orow[tid + 512] = f2b(v2 * rn * w[tid + 512]);
}

// ---------------- GEMM template: BM x BN tile, 256 thr, 3-buffer counted-vmcnt pipeline ----
// EPI 2: bf16 store + RoPE (cols<1536) + Q pre-scale (cols<768); BM=BN=128
// EPI 4: bf16 store of (v + Rf[fp32])           (wo + residual -> h bf16)
// EPI 5: fp32 store of (v + b2f(Rb[bf16]))      (down + residual -> d_out)
template <int EPI, int BM, int BN>
__global__ __launch_bounds__(256) void gemm_bt(const unsigned short* __restrict__ A,
    const unsigned short* __restrict__ Bt, unsigned short* __restrict__ Cb,
    float* __restrict__ Cf, const float* __restrict__ Rf, const unsigned short* __restrict__ Rb,
    int K, int ldc, const float* __restrict__ ct, const float* __restrict__ st, int nbn) {
  constexpr int ABYTES = BM * 32 * 2;
  constexpr int BBYTES = BN * 32 * 2;
  constexpr int APASS = BM / 64, BPASS = BN / 64;
  constexpr int LPS = APASS + BPASS;
  constexpr bool W2x2 = (BN == 128);
  constexpr int MR = W2x2 ? (BM / 32) : (BM / 64);
  __shared__ unsigned short As[3 * BM * 32];
  __shared__ unsigned short Bs[3 * BN * 32];
  const int tid = threadIdx.x;
  const int lane = tid & 63, wid = tid >> 6;
  const int wrow = W2x2 ? (wid >> 1) * (BM / 2) : wid * (BM / 4);
  const int wcol = W2x2 ? (wid & 1) * 64 : 0;
  const int l15 = lane & 15, l4 = lane >> 4;
  int bm, bn;
  xcd_remap(nbn, bm, bn);

  f4v acc[MR][4] = {};

  const int o0 = tid * 16, o1 = tid * 16 + 4096;
  const int r0 = o0 >> 6, c0 = o0 & 63;
  const int r1 = o1 >> 6, c1 = o1 & 63;
  const size_t ldab = (size_t)K * 2;
  const char* Abyte = (const char*)A;
  const char* Bbyte = (const char*)Bt;
  const size_t a0 = (size_t)(bm * BM + r0) * ldab + c0;
  const size_t a1 = (size_t)(bm * BM + (APASS == 2 ? r1 : r0)) * ldab + c1;
  const size_t b0 = (size_t)(bn * BN + r0) * ldab + c0;
  const size_t b1 = (size_t)(bn * BN + (BPASS == 2 ? r1 : r0)) * ldab + c1;
  char* AsB = (char*)As;
  char* BsB = (char*)Bs;
  const int uoff = wid << 10;

#define STAGEK(I, SL) do { const size_t kb = (size_t)(I) * 64;                 \
    char* Aw = AsB + (SL) * ABYTES;                                            \
    char* Bw = BsB + (SL) * BBYTES;                                            \
    gl16(Abyte + a0 + kb, Aw + uoff);                                          \
    if constexpr (APASS == 2) gl16(Abyte + a1 + kb, Aw + uoff + 4096);         \
    gl16(Bbyte + b0 + kb, Bw + uoff);                                          \
    if constexpr (BPASS == 2) gl16(Bbyte + b1 + kb, Bw + uoff + 4096); } while (0)

  const int NI = K >> 5;
  STAGEK(0, 0);
  STAGEK(1, 1);
  int sel = 0, nsl = 2;

  for (int i = 0; i < NI; ++i) {
    if (i < NI - 1) {
      if constexpr (LPS == 4)      asm volatile("s_waitcnt vmcnt(4)" ::: "memory");
      else if constexpr (LPS == 3) asm volatile("s_waitcnt vmcnt(3)" ::: "memory");
      else                         asm volatile("s_waitcnt vmcnt(2)" ::: "memory");
    } else {
      asm volatile("s_waitcnt vmcnt(0)" ::: "memory");
    }
    __builtin_amdgcn_s_barrier();
    __builtin_amdgcn_sched_barrier(0);
    if (i + 2 < NI) STAGEK(i + 2, nsl);
    const char* Ar = AsB + sel * ABYTES;
    const char* Br = BsB + sel * BBYTES;
    s8v af[MR], bf[4];
#pragma unroll
    for (int m = 0; m < MR; ++m)
      af[m] = *(const s8v*)(Ar + (wrow + m * 16 + l15) * 64 + l4 * 16);
#pragma unroll
    for (int n = 0; n < 4; ++n)
      bf[n] = *(const s8v*)(Br + (wcol + n * 16 + l15) * 64 + l4 * 16);
    __builtin_amdgcn_s_setprio(1);
#pragma unroll
    for (int m = 0; m < MR; ++m)
#pragma unroll
      for (int n = 0; n < 4; ++n) acc[m][n] = MFMA16(af[m], bf[n], acc[m][n]);
    __builtin_amdgcn_s_setprio(0);
    sel = (sel == 2) ? 0 : sel + 1;
    nsl = (nsl == 2) ? 0 : nsl + 1;
  }
#undef STAGEK

  const int row0 = bm * BM + wrow;
  const int col0 = bn * BN + wcol;

  if constexpr (EPI == 2) {        // RoPE + Q pre-scale (BN=128: wave spans one head)
    const int colw = col0;
    if (colw < 1536) {             // q|k region: RoPE
#pragma unroll
      for (int m = 0; m < MR; ++m)
#pragma unroll
        for (int r = 0; r < 4; ++r) {
          const int row = row0 + m * 16 + l4 * 4 + r;
#pragma unroll
          for (int n = 0; n < 2; ++n) {
            const int d = n * 16 + l15;
            const float c  = ct[row * 32 + d];
            const float sn = st[row * 32 + d];
            const float aa = acc[m][n][r], bb = acc[m][n + 2][r];
            acc[m][n][r]     = aa * c - bb * sn;
            acc[m][n + 2][r] = bb * c + aa * sn;
          }
        }
    }
    if (colw < 768) {              // q region: pre-scale by 0.125*log2e
      const float QSC = 0.18033688011112042f;
#pragma unroll
      for (int m = 0; m < MR; ++m)
#pragma unroll
        for (int n = 0; n < 4; ++n)
#pragma unroll
          for (int r = 0; r < 4; ++r) acc[m][n][r] *= QSC;
    }
  }

#pragma unroll
  for (int m = 0; m < MR; ++m)
#pragma unroll
    for (int n = 0; n < 4; ++n)
#pragma unroll
      for (int r = 0; r < 4; ++r) {
        const int row = row0 + m * 16 + l4 * 4 + r;
        const int col = col0 + n * 16 + l15;
        const float v = acc[m][n][r];
        const size_t idx = (size_t)row * ldc + col;
        if (EPI == 4)      Cb[idx] = f2b(v + Rf[idx]);
        else if (EPI == 5) Cf[idx] = v + b2f(Rb[idx]);
        else               Cb[idx] = f2b(v);
      }
}

// ---------------- big GEMM: 256(M)x128(N) tile, 512 thr, 8 waves (4Mx2N), BK=32 ----------------
template <int EPI>
__global__ __launch_bounds__(512, 2) void gemm_big(const unsigned short* __restrict__ A,
    const unsigned short* __restrict__ Bt, unsigned short* __restrict__ Cb,
    int K, int ldc, int nbn) {
  constexpr int ABYTES = 256 * 32 * 2;
  constexpr int BBYTES = 128 * 32 * 2;
  __shared__ unsigned short As[3 * 256 * 32];
  __shared__ unsigned short Bs[3 * 128 * 32];
  const int tid = threadIdx.x;
  const int lane = tid & 63, wid = tid >> 6;
  const int wm = wid >> 1, wn = wid & 1;
  const int wrow = wm * 64, wcol = wn * 64;
  const int l15 = lane & 15, l4 = lane >> 4;
  int bm, bn;
  xcd_remap(nbn, bm, bn);

  f4v acc[4][4] = {};

  const size_t ldab = (size_t)K * 2;
  const char* Ab = (const char*)A;
  const char* Bb = (const char*)Bt;
  const int lrow = lane >> 2, lch = (lane & 3) * 16;
  const size_t aS0 = (size_t)(bm * 256 + wid * 16 + lrow) * ldab + lch;
  const size_t aS1 = (size_t)(bm * 256 + (wid + 8) * 16 + lrow) * ldab + lch;
  const size_t bS  = (size_t)(bn * 128 + wid * 16 + lrow) * ldab + lch;
  char* AsB = (char*)As;
  char* BsB = (char*)Bs;
  const int uA0 = wid << 10, uA1 = (wid + 8) << 10, uB = wid << 10;

#define STAGEK(I, SL) do { const size_t kb = (size_t)(I) * 64;                 \
    gl16(Ab + aS0 + kb, AsB + (SL) * ABYTES + uA0);                            \
    gl16(Ab + aS1 + kb, AsB + (SL) * ABYTES + uA1);                            \
    gl16(Bb + bS  + kb, BsB + (SL) * BBYTES + uB); } while (0)

  const int NI = K >> 5;
  STAGEK(0, 0);
  STAGEK(1, 1);
  int sel = 0, nsl = 2;

  for (int i = 0; i < NI; ++i) {
    if (i < NI - 1) asm volatile("s_waitcnt vmcnt(3)" ::: "memory");
    else            asm volatile("s_waitcnt vmcnt(0)" ::: "memory");
    __builtin_amdgcn_s_barrier();
    __builtin_amdgcn_sched_barrier(0);
    if (i + 2 < NI) STAGEK(i + 2, nsl);
    const char* Ar = AsB + sel * ABYTES;
    const char* Br = BsB + sel * BBYTES;
    s8v af[4], bf[4];
#pragma unroll
    for (int m = 0; m < 4; ++m)
      af[m] = *(const s8v*)(Ar + (wrow + m * 16 + l15) * 64 + l4 * 16);
#pragma unroll
    for (int n = 0; n < 4; ++n)
      bf[n] = *(const s8v*)(Br + (wcol + n * 16 + l15) * 64 + l4 * 16);
    __builtin_amdgcn_s_setprio(1);
#pragma unroll
    for (int m = 0; m < 4; ++m)
#pragma unroll
      for (int n = 0; n < 4; ++n) acc[m][n] = MFMA16(af[m], bf[n], acc[m][n]);
    __builtin_amdgcn_s_setprio(0);
    sel = (sel == 2) ? 0 : sel + 1;
    nsl = (nsl == 2) ? 0 : nsl + 1;
  }
#undef STAGEK

  const int row0 = bm * 256 + wrow;
  const int col0 = bn * 128 + wcol;

  if (EPI == 3) {                  // silu(g)*u, g at n<2, u at n+2
    const int colb = (bn * 2 + wn) * 32;
#pragma unroll
    for (int m = 0; m < 4; ++m)
#pragma unroll
      for (int n = 0; n < 2; ++n)
#pragma unroll
        for (int r = 0; r < 4; ++r) {
          const int row = row0 + m * 16 + l4 * 4 + r;
          const float g = acc[m][n][r], u = acc[m][n + 2][r];
          const float val = g * u / (1.0f + __expf(-g));
          Cb[(size_t)row * 2048 + colb + n * 16 + l15] = f2b(val);
        }
    return;
  }

#pragma unroll
  for (int m = 0; m < 4; ++m)
#pragma unroll
    for (int n = 0; n < 4; ++n)
#pragma unroll
      for (int r = 0; r < 4; ++r) {
        const int row = row0 + m * 16 + l4 * 4 + r;
        const int col = col0 + n * 16 + l15;
        Cb[(size_t)row * ldc + col] = f2b(acc[m][n][r]);
      }
}

// ---------------- causal flash attention: 32x32 swapped-QK, 2-way parity, NO online max ----------------
__global__ __launch_bounds__(256, 4) void flash_k(const unsigned short* __restrict__ qkv,
    uint2* __restrict__ Opart, float* __restrict__ ml) {
  const int kh = blockIdx.x, p = blockIdx.y, h = blockIdx.z;
  const int qbA = 63 - p;
  const int tid = threadIdx.x;
  const int wv = tid >> 6, lane = tid & 63;
  const int l31 = lane & 31, h8 = lane >> 5;
  const int myqb = (wv & 1) ? p : qbA;
  const int qrel = (wv >> 1) * 32 + l31;
  const int q_abs = myqb * 64 + qrel;

  __shared__ unsigned short Ks[2][64 * 72];
  __shared__ unsigned short Vt[2][64 * 72];

  const unsigned short* qp = qkv + h * 64;
  const unsigned short* kp = qkv + 768 + h * 64;
  const unsigned short* vp = qkv + 1536 + h * 64;

  s8v qf[4];
#pragma unroll
  for (int cc = 0; cc < 4; ++cc)
    qf[cc] = *(const s8v*)(qp + (size_t)q_abs * 2304 + cc * 16 + h8 * 8);

  f16v o0 = {}, o1 = {};
  float lp = 0.f;

  const int krow = tid >> 3, kc = (tid & 7) * 8;
  const int vj = tid & 31, vd0 = (tid >> 5) * 8;

  s8v ka, kb, va, vb;
#define LOADT(T) do { const size_t k0n = (size_t)(T) * 64;                    \
    ka = *(const s8v*)(kp + (k0n + krow) * 2304 + kc);                        \
    kb = *(const s8v*)(kp + (k0n + krow + 32) * 2304 + kc);                   \
    va = *(const s8v*)(vp + (k0n + 2 * vj) * 2304 + vd0);                     \
    vb = *(const s8v*)(vp + (k0n + 2 * vj + 1) * 2304 + vd0); } while (0)
#define WRITET(BUF) do {                                                      \
    *(s8v*)(Ks[BUF] + krow * 72 + kc) = ka;                                   \
    *(s8v*)(Ks[BUF] + (krow + 32) * 72 + kc) = kb;                            \
    unsigned* vtw = (unsigned*)(Vt[BUF] + (size_t)vd0 * 72 + 2 * vj);         \
    _Pragma("unroll")                                                         \
    for (int i = 0; i < 8; ++i)                                               \
      vtw[i * 36] = ((unsigned)(unsigned short)va[i]) |                       \
                    (((unsigned)(unsigned short)vb[i]) << 16); } while (0)

  LOADT(kh);
  WRITET(0);
  if (kh + 2 <= qbA) LOADT(kh + 2);
  __syncthreads();

  for (int t = kh; t <= qbA; t += 2) {
    const int cur = (t >> 1) & 1;
    if (t <= myqb) {
      f16v s0 = {}, s1 = {};
      __builtin_amdgcn_s_setprio(1);
#pragma unroll
      for (int cc = 0; cc < 4; ++cc) {
        const s8v kf0 = *(const s8v*)(Ks[cur] + l31 * 72 + cc * 16 + h8 * 8);
        const s8v kf1 = *(const s8v*)(Ks[cur] + (32 + l31) * 72 + cc * 16 + h8 * 8);
        s0 = MFMA32(kf0, qf[cc], s0);
        s1 = MFMA32(kf1, qf[cc], s1);
      }
      __builtin_amdgcn_s_setprio(0);
      if (t == myqb) {
#pragma unroll
        for (int rr = 0; rr < 16; ++rr) {
          const int koff = (rr & 3) + 8 * (rr >> 2) + 4 * h8;
          if (koff > qrel) s0[rr] = -1e30f;
          if (koff + 32 > qrel) s1[rr] = -1e30f;
        }
      }
#pragma unroll
      for (int rr = 0; rr < 16; ++rr) {
        s0[rr] = exp2f(s0[rr]);
        s1[rr] = exp2f(s1[rr]);
      }
      float sm[8];
#pragma unroll
      for (int i = 0; i < 8; ++i) sm[i] = (s0[i] + s0[i + 8]) + (s1[i] + s1[i + 8]);
#pragma unroll
      for (int i = 0; i < 4; ++i) sm[i] += sm[i + 4];
      lp += (sm[0] + sm[1]) + (sm[2] + sm[3]);

      unsigned pk0[8], pk1[8];
#pragma unroll
      for (int g = 0; g < 4; ++g)
#pragma unroll
        for (int j = 0; j < 2; ++j) {
          pk0[g * 2 + j] = pk2(s0[g * 4 + 2 * j], s0[g * 4 + 2 * j + 1]);
          pk1[g * 2 + j] = pk2(s1[g * 4 + 2 * j], s1[g * 4 + 2 * j + 1]);
        }
      __builtin_amdgcn_s_setprio(1);
#pragma unroll
      for (int cc = 0; cc < 4; ++cc) {
        const int g0 = (cc & 1) * 2, g1 = g0 + 1;
        const unsigned pA0 = (cc & 2) ? pk1[g0 * 2 + 0] : pk0[g0 * 2 + 0];
        const unsigned pA1 = (cc & 2) ? pk1[g0 * 2 + 1] : pk0[g0 * 2 + 1];
        const unsigned pB0 = (cc & 2) ? pk1[g1 * 2 + 0] : pk0[g1 * 2 + 0];
        const unsigned pB1 = (cc & 2) ? pk1[g1 * 2 + 1] : pk0[g1 * 2 + 1];
        const unsigned t00 = __shfl_xor((int)pA0, 32);
        const unsigned t01 = __shfl_xor((int)pA1, 32);
        const unsigned t10 = __shfl_xor((int)pB0, 32);
        const unsigned t11 = __shfl_xor((int)pB1, 32);
        union { u4v u; s8v s; } pf;
        pf.u[0] = h8 ? t10 : pA0;
        pf.u[1] = h8 ? t11 : pA1;
        pf.u[2] = h8 ? pB0 : t00;
        pf.u[3] = h8 ? pB1 : t01;
        const s8v vf0 = *(const s8v*)(Vt[cur] + l31 * 72 + cc * 16 + h8 * 8);
        const s8v vf1 = *(const s8v*)(Vt[cur] + (32 + l31) * 72 + cc * 16 + h8 * 8);
        o0 = MFMA32(vf0, pf.s, o0);
        o1 = MFMA32(vf1, pf.s, o1);
      }
      __builtin_amdgcn_s_setprio(0);
    }
    if (t + 2 <= qbA) {
      WRITET(cur ^ 1);
      if (t + 4 <= qbA) LOADT(t + 4);
      __syncthreads();
    }
  }

  lp += __shfl_xor(lp, 32);

  const size_t obase = ((size_t)kh * 12 + h) * 16 * 4096;
#pragma unroll
  for (int g = 0; g < 4; ++g) {
    const uint2 v0 = make_uint2(pk2(o0[g * 4], o0[g * 4 + 1]), pk2(o0[g * 4 + 2], o0[g * 4 + 3]));
    const uint2 v1 = make_uint2(pk2(o1[g * 4], o1[g * 4 + 1]), pk2(o1[g * 4 + 2], o1[g * 4 + 3]));
    Opart[obase + (size_t)(2 * g + h8) * 4096 + q_abs] = v0;
    Opart[obase + (size_t)(8 + 2 * g + h8) * 4096 + q_abs] = v1;
  }
  if (h8 == 0)
    ml[((size_t)kh * 12 + h) * 4096 + q_abs] = lp;
#undef LOADT
#undef WRITET
}

// ---------------- combine 2 key-parity partials -> attn bf16 [q][768] ----------------
__global__ __launch_bounds__(256) void combine_k(const uint2* __restrict__ Opart,
    const float* __restrict__ ml, unsigned short* __restrict__ out) {
  const int u = blockIdx.x * 256 + threadIdx.x;
  const int q = u & 4095;
  const int rest = u >> 12;
  const int dgrp = rest & 15;
  const int h = rest >> 4;
  const float l0 = ml[h * 4096 + q];
  const float l1 = ml[12 * 4096 + h * 4096 + q];
  const float inv = 1.0f / (l0 + l1);
  const size_t idx = ((size_t)h * 16 + dgrp) * 4096 + q;
  const uint2 a = Opart[idx];
  const uint2 b = Opart[(size_t)12 * 16 * 4096 + idx];
  const int dbase = (dgrp < 8) ? 4 * dgrp : 32 + 4 * (dgrp - 8);
  ushort4 r;
  r.x = f2b((b2f(a.x) + b2f(b.x)) * inv);
  r.y = f2b((b2f(a.x >> 16) + b2f(b.x >> 16)) * inv);
  r.z = f2b((b2f(a.y) + b2f(b.y)) * inv);
  r.w = f2b((b2f(a.y >> 16) + b2f(b.y >> 16)) * inv);
  *(ushort4*)(out + (size_t)q * 768 + h * 64 + dbase) = r;
}

extern "C" void kernel_launch(void* const* d_in, const int* in_sizes, int n_in,
                              void* d_out, int out_size, void* d_ws, size_t ws_size,
                              hipStream_t stream) {
  const float* x    = (const float*)d_in[0];
  const float* w_q  = (const float*)d_in[1];
  const float* w_k  = (const float*)d_in[2];
  const float* w_v  = (const float*)d_in[3];
  const float* w_o  = (const float*)d_in[4];
  const float* w_g  = (const float*)d_in[5];
  const float* w_u  = (const float*)d_in[6];
  const float* w_d  = (const float*)d_in[7];
  const float* w_n1 = (const float*)d_in[8];
  const float* w_n2 = (const float*)d_in[9];
  (void)in_sizes; (void)n_in; (void)out_size; (void)ws_size;

  char* ws = (char*)d_ws;
  size_t off = 0;
  auto alloc = [&](size_t bytes) { char* p = ws + off; off += (bytes + 255) & ~(size_t)255; return p; };
  unsigned short* wqkvT = (unsigned short*)alloc(2304ull * 768 * 2);
  unsigned short* woT   = (unsigned short*)alloc(768ull * 768 * 2);
  unsigned short* wguT  = (unsigned short*)alloc(4096ull * 768 * 2);
  unsigned short* wdT   = (unsigned short*)alloc(768ull * 2048 * 2);
  float* ct             = (float*)alloc(4096ull * 32 * 4);
  float* st             = (float*)alloc(4096ull * 32 * 4);
  unsigned short* xn    = (unsigned short*)alloc(4096ull * 768 * 2);
  unsigned short* qkv   = (unsigned short*)alloc(4096ull * 2304 * 2);
  unsigned short* attn  = (unsigned short*)alloc(4096ull * 768 * 2);
  unsigned short* hb16  = (unsigned short*)alloc(4096ull * 768 * 2);
  unsigned short* ybuf  = (unsigned short*)alloc(4096ull * 768 * 2);
  unsigned short* ffn   = (unsigned short*)alloc(4096ull * 2048 * 2);
  uint2* Opart          = (uint2*)alloc(2ull * 12 * 16 * 4096 * 8);
  float* mlb            = (float*)alloc(2ull * 12 * 4096 * 4);

  PrepArgs pa;
  pa.seg[0] = { w_q, wqkvT,                 768,  768, 24,  576, 0 };
  pa.seg[1] = { w_k, wqkvT + 768 * 768,     768,  768, 24,  576, 0 };
  pa.seg[2] = { w_v, wqkvT + 2 * 768 * 768, 768,  768, 24,  576, 0 };
  pa.seg[3] = { w_o, woT,                   768,  768, 24,  576, 0 };
  pa.seg[4] = { w_g, wguT,                  768, 2048, 64, 1536, 1 };
  pa.seg[5] = { w_u, wguT,                  768, 2048, 64, 1536, 2 };
  pa.seg[6] = { w_d, wdT,                  2048,  768, 24, 1536, 0 };
  pa.seg[7] = { nullptr, nullptr, 0, 0, 0, 512, 3 };
  pa.seg[8] = { x, xn, 0, 0, 0, 4096, 4 };
  pa.ct = ct; pa.st = st; pa.wn1 = w_n1;
  const int prep_blocks = 576 * 4 + 1536 * 3 + 512 + 4096;   // 11520

  prep_k<<<prep_blocks, 256, 0, stream>>>(pa);
  // qkv = xn @ [Wq|Wk|Wv] + RoPE + Q pre-scale; 576 blocks = 32(M/128) x 18(N/128)
  gemm_bt<2, 128, 128><<<576, 256, 0, stream>>>(xn, wqkvT, qkv, nullptr, nullptr, nullptr, 768, 2304, ct, st, 18);
  flash_k<<<dim3(2, 32, 12), 256, 0, stream>>>(qkv, Opart, mlb);
  combine_k<<<3072, 256, 0, stream>>>(Opart, mlb, attn);
  // h = attn @ Wo + x (bf16 out); 768 blocks = 64 x 12, exactly 3/CU
  gemm_bt<4, 64, 64><<<768, 256, 0, stream>>>(attn, woT, hb16, nullptr, x, nullptr, 768, 768, nullptr, nullptr, 12);
  rmsnorm_b16_k<<<4096, 256, 0, stream>>>(hb16, w_n2, ybuf);
  // ffn = silu(y@Wg)*(y@Wu); 512 blocks = 16 x 32, exactly 2/CU
  gemm_big<3><<<512, 512, 0, stream>>>(ybuf, wguT, ffn, 768, 2048, 32);
  // out = ffn @ Wd + h(bf16); 768 blocks = 64 x 12, exactly 3/CU
  gemm_bt<5, 64, 64><<<768, 256, 0, stream>>>(ffn, wdT, nullptr, (float*)d_out, nullptr, hb16, 2048, 768, nullptr, nullptr, 12);
}

// Round 18
// 201.052 us; speedup vs baseline: 1.0567x; 1.0019x over previous
//
#include <hip/hip_runtime.h>
#include <hip/hip_bf16.h>

typedef __attribute__((ext_vector_type(8))) short s8v;
typedef __attribute__((ext_vector_type(4))) float f4v;
typedef __attribute__((ext_vector_type(16))) float f16v;
typedef __attribute__((ext_vector_type(4))) unsigned u4v;

typedef __attribute__((address_space(1))) const void as1_void;
typedef __attribute__((address_space(3))) void as3_void;

__device__ __forceinline__ void gl16(const void* g, void* l) {
  __builtin_amdgcn_global_load_lds((as1_void*)g, (as3_void*)l, 16, 0, 0);
}

__device__ __forceinline__ float b2f(int u) {
  union { float f; unsigned i; } c; c.i = ((unsigned)(u & 0xFFFF)) << 16; return c.f;
}
__device__ __forceinline__ unsigned short f2b(float f) {   // RNE
  union { float f; unsigned i; } c; c.f = f;
  unsigned r = c.i + 0x7FFFu + ((c.i >> 16) & 1u);
  return (unsigned short)(r >> 16);
}
__device__ __forceinline__ unsigned pk2(float lo, float hi) {  // 2xbf16 pack
  unsigned u;
  asm("v_cvt_pk_bf16_f32 %0, %1, %2" : "=v"(u) : "v"(lo), "v"(hi));
  return u;
}

#define MFMA16(a, b, c) __builtin_amdgcn_mfma_f32_16x16x32_bf16((a), (b), (c), 0, 0, 0)
#define MFMA32(a, b, c) __builtin_amdgcn_mfma_f32_32x32x16_bf16((a), (b), (c), 0, 0, 0)

// XCD-aware bijective block remap (grid % 8 == 0): contiguous logical blocks per XCD.
__device__ __forceinline__ void xcd_remap(int nbn, int& bm, int& bn) {
  const int flat = blockIdx.x;
  const int u = (flat & 7) * ((int)gridDim.x >> 3) + (flat >> 3);
  bm = u / nbn;
  bn = u - bm * nbn;
}

// -------- fused prep: weight converts (+gu interleave +w_norm2 fold) + rope + rmsnorm1 --------
struct Seg { const float* src; unsigned short* dst; int K; int N; int nbn; int nblocks; int mode; };
struct PrepArgs { Seg seg[9]; float* ct; float* st; const float* wn1; const float* wn2; };

__global__ __launch_bounds__(256) void prep_k(PrepArgs a) {
  int b = blockIdx.x, si = 0;
  while (si < 8 && b >= a.seg[si].nblocks) { b -= a.seg[si].nblocks; ++si; }
  const Seg s = a.seg[si];
  const int tid = threadIdx.x;
  if (s.mode == 3) {               // rope tables [4096][32]
    const int t = b * 256 + tid;
    const int sq = t >> 5, d = t & 31;
    const float inv = powf(10000.0f, -(float)d * (1.0f / 32.0f));
    const float ang = (float)sq * inv;
    a.ct[t] = cosf(ang);
    a.st[t] = sinf(ang);
    return;
  }
  if (s.mode == 4) {               // rmsnorm1: x row b -> bf16
    const float* xr = s.src + (size_t)b * 768;
    float v0 = xr[tid], v1 = xr[tid + 256], v2 = xr[tid + 512];
    float ss = v0 * v0 + v1 * v1 + v2 * v2;
#pragma unroll
    for (int m = 1; m < 64; m <<= 1) ss += __shfl_xor(ss, m, 64);
    __shared__ float sred[4];
    if ((tid & 63) == 0) sred[tid >> 6] = ss;
    __syncthreads();
    const float tot = sred[0] + sred[1] + sred[2] + sred[3];
    const float rn = rsqrtf(tot * (1.0f / 768.0f) + 1e-6f);
    unsigned short* orow = s.dst + (size_t)b * 768;
    orow[tid]       = f2b(v0 * rn * a.wn1[tid]);
    orow[tid + 256] = f2b(v1 * rn * a.wn1[tid + 256]);
    orow[tid + 512] = f2b(v2 * rn * a.wn1[tid + 512]);
    return;
  }
  __shared__ float tile[32][33];
  const int tx = tid & 31, ty = tid >> 5;
  const int bn = b % s.nbn, bk = b / s.nbn;
#pragma unroll
  for (int i = 0; i < 32; i += 8)
    tile[ty + i][tx] = s.src[(size_t)(bk * 32 + ty + i) * s.N + bn * 32 + tx];
  __syncthreads();
  const float kscale = (s.mode == 1 || s.mode == 2) ? a.wn2[bk * 32 + tx] : 1.0f;
#pragma unroll
  for (int i = 0; i < 32; i += 8) {
    int row;
    if (s.mode == 0)      row = bn * 32 + ty + i;
    else                  row = bn * 64 + (s.mode == 2 ? 32 : 0) + ty + i;
    s.dst[(size_t)row * s.K + bk * 32 + tx] = f2b(tile[tx][ty + i] * kscale);
  }
}

// ---------------- per-row inverse-RMS of h (bf16): rn2[row] = rsqrt(mean(h^2)+eps) ----------------
__global__ __launch_bounds__(256) void rn2_k(const unsigned short* __restrict__ x,
    float* __restrict__ rn2) {
  const int row = blockIdx.x, tid = threadIdx.x;
  const unsigned short* xr = x + (size_t)row * 768;
  float v0 = b2f(xr[tid]), v1 = b2f(xr[tid + 256]), v2 = b2f(xr[tid + 512]);
  float ss = v0 * v0 + v1 * v1 + v2 * v2;
#pragma unroll
  for (int m = 1; m < 64; m <<= 1) ss += __shfl_xor(ss, m, 64);
  __shared__ float sred[4];
  if ((tid & 63) == 0) sred[tid >> 6] = ss;
  __syncthreads();
  if (tid == 0) {
    const float tot = sred[0] + sred[1] + sred[2] + sred[3];
    rn2[row] = rsqrtf(tot * (1.0f / 768.0f) + 1e-6f);
  }
}

// ---------------- GEMM template: BM x BN tile, 256 thr, 3-buffer counted-vmcnt pipeline ----
// EPI 2: bf16 store + RoPE (cols<1536) + Q pre-scale (cols<768); BM=BN=128
// EPI 4: bf16 store of (v + Rf[fp32])           (wo + residual -> h bf16)
// EPI 5: fp32 store of (v + b2f(Rb[bf16]))      (down + residual -> d_out)
template <int EPI, int BM, int BN>
__global__ __launch_bounds__(256) void gemm_bt(const unsigned short* __restrict__ A,
    const unsigned short* __restrict__ Bt, unsigned short* __restrict__ Cb,
    float* __restrict__ Cf, const float* __restrict__ Rf, const unsigned short* __restrict__ Rb,
    int K, int ldc, const float* __restrict__ ct, const float* __restrict__ st, int nbn) {
  constexpr int ABYTES = BM * 32 * 2;
  constexpr int BBYTES = BN * 32 * 2;
  constexpr int APASS = BM / 64, BPASS = BN / 64;
  constexpr int LPS = APASS + BPASS;
  constexpr bool W2x2 = (BN == 128);
  constexpr int MR = W2x2 ? (BM / 32) : (BM / 64);
  __shared__ unsigned short As[3 * BM * 32];
  __shared__ unsigned short Bs[3 * BN * 32];
  const int tid = threadIdx.x;
  const int lane = tid & 63, wid = tid >> 6;
  const int wrow = W2x2 ? (wid >> 1) * (BM / 2) : wid * (BM / 4);
  const int wcol = W2x2 ? (wid & 1) * 64 : 0;
  const int l15 = lane & 15, l4 = lane >> 4;
  int bm, bn;
  xcd_remap(nbn, bm, bn);

  f4v acc[MR][4] = {};

  const int o0 = tid * 16, o1 = tid * 16 + 4096;
  const int r0 = o0 >> 6, c0 = o0 & 63;
  const int r1 = o1 >> 6, c1 = o1 & 63;
  const size_t ldab = (size_t)K * 2;
  const char* Abyte = (const char*)A;
  const char* Bbyte = (const char*)Bt;
  const size_t a0 = (size_t)(bm * BM + r0) * ldab + c0;
  const size_t a1 = (size_t)(bm * BM + (APASS == 2 ? r1 : r0)) * ldab + c1;
  const size_t b0 = (size_t)(bn * BN + r0) * ldab + c0;
  const size_t b1 = (size_t)(bn * BN + (BPASS == 2 ? r1 : r0)) * ldab + c1;
  char* AsB = (char*)As;
  char* BsB = (char*)Bs;
  const int uoff = wid << 10;

#define STAGEK(I, SL) do { const size_t kb = (size_t)(I) * 64;                 \
    char* Aw = AsB + (SL) * ABYTES;                                            \
    char* Bw = BsB + (SL) * BBYTES;                                            \
    gl16(Abyte + a0 + kb, Aw + uoff);                                          \
    if constexpr (APASS == 2) gl16(Abyte + a1 + kb, Aw + uoff + 4096);         \
    gl16(Bbyte + b0 + kb, Bw + uoff);                                          \
    if constexpr (BPASS == 2) gl16(Bbyte + b1 + kb, Bw + uoff + 4096); } while (0)

  const int NI = K >> 5;
  STAGEK(0, 0);
  STAGEK(1, 1);
  int sel = 0, nsl = 2;

  for (int i = 0; i < NI; ++i) {
    if (i < NI - 1) {
      if constexpr (LPS == 4)      asm volatile("s_waitcnt vmcnt(4)" ::: "memory");
      else if constexpr (LPS == 3) asm volatile("s_waitcnt vmcnt(3)" ::: "memory");
      else                         asm volatile("s_waitcnt vmcnt(2)" ::: "memory");
    } else {
      asm volatile("s_waitcnt vmcnt(0)" ::: "memory");
    }
    __builtin_amdgcn_s_barrier();
    __builtin_amdgcn_sched_barrier(0);
    if (i + 2 < NI) STAGEK(i + 2, nsl);
    const char* Ar = AsB + sel * ABYTES;
    const char* Br = BsB + sel * BBYTES;
    s8v af[MR], bf[4];
#pragma unroll
    for (int m = 0; m < MR; ++m)
      af[m] = *(const s8v*)(Ar + (wrow + m * 16 + l15) * 64 + l4 * 16);
#pragma unroll
    for (int n = 0; n < 4; ++n)
      bf[n] = *(const s8v*)(Br + (wcol + n * 16 + l15) * 64 + l4 * 16);
    __builtin_amdgcn_s_setprio(1);
#pragma unroll
    for (int m = 0; m < MR; ++m)
#pragma unroll
      for (int n = 0; n < 4; ++n) acc[m][n] = MFMA16(af[m], bf[n], acc[m][n]);
    __builtin_amdgcn_s_setprio(0);
    sel = (sel == 2) ? 0 : sel + 1;
    nsl = (nsl == 2) ? 0 : nsl + 1;
  }
#undef STAGEK

  const int row0 = bm * BM + wrow;
  const int col0 = bn * BN + wcol;

  if constexpr (EPI == 2) {        // RoPE + Q pre-scale (BN=128: wave spans one head)
    const int colw = col0;
    if (colw < 1536) {             // q|k region: RoPE
#pragma unroll
      for (int m = 0; m < MR; ++m)
#pragma unroll
        for (int r = 0; r < 4; ++r) {
          const int row = row0 + m * 16 + l4 * 4 + r;
#pragma unroll
          for (int n = 0; n < 2; ++n) {
            const int d = n * 16 + l15;
            const float c  = ct[row * 32 + d];
            const float sn = st[row * 32 + d];
            const float aa = acc[m][n][r], bb = acc[m][n + 2][r];
            acc[m][n][r]     = aa * c - bb * sn;
            acc[m][n + 2][r] = bb * c + aa * sn;
          }
        }
    }
    if (colw < 768) {              // q region: pre-scale by 0.125*log2e
      const float QSC = 0.18033688011112042f;
#pragma unroll
      for (int m = 0; m < MR; ++m)
#pragma unroll
        for (int n = 0; n < 4; ++n)
#pragma unroll
          for (int r = 0; r < 4; ++r) acc[m][n][r] *= QSC;
    }
  }

#pragma unroll
  for (int m = 0; m < MR; ++m)
#pragma unroll
    for (int n = 0; n < 4; ++n)
#pragma unroll
      for (int r = 0; r < 4; ++r) {
        const int row = row0 + m * 16 + l4 * 4 + r;
        const int col = col0 + n * 16 + l15;
        const float v = acc[m][n][r];
        const size_t idx = (size_t)row * ldc + col;
        if (EPI == 4)      Cb[idx] = f2b(v + Rf[idx]);
        else if (EPI == 5) Cf[idx] = v + b2f(Rb[idx]);
        else               Cb[idx] = f2b(v);
      }
}

// ---------------- big GEMM: 256(M)x128(N) tile, 512 thr, 8 waves (4Mx2N), BK=32 ----------------
// EPI 3: rn2[row]-scaled silu(g)*u from 32-interleaved (w_norm2-folded) B rows -> bf16
template <int EPI>
__global__ __launch_bounds__(512, 2) void gemm_big(const unsigned short* __restrict__ A,
    const unsigned short* __restrict__ Bt, unsigned short* __restrict__ Cb,
    const float* __restrict__ rn2, int K, int ldc, int nbn) {
  constexpr int ABYTES = 256 * 32 * 2;
  constexpr int BBYTES = 128 * 32 * 2;
  __shared__ unsigned short As[3 * 256 * 32];
  __shared__ unsigned short Bs[3 * 128 * 32];
  const int tid = threadIdx.x;
  const int lane = tid & 63, wid = tid >> 6;
  const int wm = wid >> 1, wn = wid & 1;
  const int wrow = wm * 64, wcol = wn * 64;
  const int l15 = lane & 15, l4 = lane >> 4;
  int bm, bn;
  xcd_remap(nbn, bm, bn);

  f4v acc[4][4] = {};

  const size_t ldab = (size_t)K * 2;
  const char* Ab = (const char*)A;
  const char* Bb = (const char*)Bt;
  const int lrow = lane >> 2, lch = (lane & 3) * 16;
  const size_t aS0 = (size_t)(bm * 256 + wid * 16 + lrow) * ldab + lch;
  const size_t aS1 = (size_t)(bm * 256 + (wid + 8) * 16 + lrow) * ldab + lch;
  const size_t bS  = (size_t)(bn * 128 + wid * 16 + lrow) * ldab + lch;
  char* AsB = (char*)As;
  char* BsB = (char*)Bs;
  const int uA0 = wid << 10, uA1 = (wid + 8) << 10, uB = wid << 10;

#define STAGEK(I, SL) do { const size_t kb = (size_t)(I) * 64;                 \
    gl16(Ab + aS0 + kb, AsB + (SL) * ABYTES + uA0);                            \
    gl16(Ab + aS1 + kb, AsB + (SL) * ABYTES + uA1);                            \
    gl16(Bb + bS  + kb, BsB + (SL) * BBYTES + uB); } while (0)

  const int NI = K >> 5;
  STAGEK(0, 0);
  STAGEK(1, 1);
  int sel = 0, nsl = 2;

  for (int i = 0; i < NI; ++i) {
    if (i < NI - 1) asm volatile("s_waitcnt vmcnt(3)" ::: "memory");
    else            asm volatile("s_waitcnt vmcnt(0)" ::: "memory");
    __builtin_amdgcn_s_barrier();
    __builtin_amdgcn_sched_barrier(0);
    if (i + 2 < NI) STAGEK(i + 2, nsl);
    const char* Ar = AsB + sel * ABYTES;
    const char* Br = BsB + sel * BBYTES;
    s8v af[4], bf[4];
#pragma unroll
    for (int m = 0; m < 4; ++m)
      af[m] = *(const s8v*)(Ar + (wrow + m * 16 + l15) * 64 + l4 * 16);
#pragma unroll
    for (int n = 0; n < 4; ++n)
      bf[n] = *(const s8v*)(Br + (wcol + n * 16 + l15) * 64 + l4 * 16);
    __builtin_amdgcn_s_setprio(1);
#pragma unroll
    for (int m = 0; m < 4; ++m)
#pragma unroll
      for (int n = 0; n < 4; ++n) acc[m][n] = MFMA16(af[m], bf[n], acc[m][n]);
    __builtin_amdgcn_s_setprio(0);
    sel = (sel == 2) ? 0 : sel + 1;
    nsl = (nsl == 2) ? 0 : nsl + 1;
  }
#undef STAGEK

  const int row0 = bm * 256 + wrow;
  const int col0 = bn * 128 + wcol;

  if (EPI == 3) {                  // val = silu(rn*g) * (rn*u); rn applied before nonlinearity
    const int colb = (bn * 2 + wn) * 32;
#pragma unroll
    for (int m = 0; m < 4; ++m)
#pragma unroll
      for (int r = 0; r < 4; ++r) {
        const int row = row0 + m * 16 + l4 * 4 + r;
        const float rn = rn2[row];
#pragma unroll
        for (int n = 0; n < 2; ++n) {
          const float g = acc[m][n][r] * rn, u = acc[m][n + 2][r] * rn;
          const float val = g * u / (1.0f + __expf(-g));
          Cb[(size_t)row * 2048 + colb + n * 16 + l15] = f2b(val);
        }
      }
    return;
  }

#pragma unroll
  for (int m = 0; m < 4; ++m)
#pragma unroll
    for (int n = 0; n < 4; ++n)
#pragma unroll
      for (int r = 0; r < 4; ++r) {
        const int row = row0 + m * 16 + l4 * 4 + r;
        const int col = col0 + n * 16 + l15;
        Cb[(size_t)row * ldc + col] = f2b(acc[m][n][r]);
      }
}

// ---------------- causal flash attention: 32x32 swapped-QK, 2-way parity, NO online max ----------------
__global__ __launch_bounds__(256, 4) void flash_k(const unsigned short* __restrict__ qkv,
    uint2* __restrict__ Opart, float* __restrict__ ml) {
  const int kh = blockIdx.x, p = blockIdx.y, h = blockIdx.z;
  const int qbA = 63 - p;
  const int tid = threadIdx.x;
  const int wv = tid >> 6, lane = tid & 63;
  const int l31 = lane & 31, h8 = lane >> 5;
  const int myqb = (wv & 1) ? p : qbA;
  const int qrel = (wv >> 1) * 32 + l31;
  const int q_abs = myqb * 64 + qrel;

  __shared__ unsigned short Ks[2][64 * 72];
  __shared__ unsigned short Vt[2][64 * 72];

  const unsigned short* qp = qkv + h * 64;
  const unsigned short* kp = qkv + 768 + h * 64;
  const unsigned short* vp = qkv + 1536 + h * 64;

  s8v qf[4];
#pragma unroll
  for (int cc = 0; cc < 4; ++cc)
    qf[cc] = *(const s8v*)(qp + (size_t)q_abs * 2304 + cc * 16 + h8 * 8);

  f16v o0 = {}, o1 = {};
  float lp = 0.f;

  const int krow = tid >> 3, kc = (tid & 7) * 8;
  const int vj = tid & 31, vd0 = (tid >> 5) * 8;

  s8v ka, kb, va, vb;
#define LOADT(T) do { const size_t k0n = (size_t)(T) * 64;                    \
    ka = *(const s8v*)(kp + (k0n + krow) * 2304 + kc);                        \
    kb = *(const s8v*)(kp + (k0n + krow + 32) * 2304 + kc);                   \
    va = *(const s8v*)(vp + (k0n + 2 * vj) * 2304 + vd0);                     \
    vb = *(const s8v*)(vp + (k0n + 2 * vj + 1) * 2304 + vd0); } while (0)
#define WRITET(BUF) do {                                                      \
    *(s8v*)(Ks[BUF] + krow * 72 + kc) = ka;                                   \
    *(s8v*)(Ks[BUF] + (krow + 32) * 72 + kc) = kb;                            \
    unsigned* vtw = (unsigned*)(Vt[BUF] + (size_t)vd0 * 72 + 2 * vj);         \
    _Pragma("unroll")                                                         \
    for (int i = 0; i < 8; ++i)                                               \
      vtw[i * 36] = ((unsigned)(unsigned short)va[i]) |                       \
                    (((unsigned)(unsigned short)vb[i]) << 16); } while (0)

  LOADT(kh);
  WRITET(0);
  if (kh + 2 <= qbA) LOADT(kh + 2);
  __syncthreads();

  for (int t = kh; t <= qbA; t += 2) {
    const int cur = (t >> 1) & 1;
    if (t <= myqb) {
      f16v s0 = {}, s1 = {};
      __builtin_amdgcn_s_setprio(1);
#pragma unroll
      for (int cc = 0; cc < 4; ++cc) {
        const s8v kf0 = *(const s8v*)(Ks[cur] + l31 * 72 + cc * 16 + h8 * 8);
        const s8v kf1 = *(const s8v*)(Ks[cur] + (32 + l31) * 72 + cc * 16 + h8 * 8);
        s0 = MFMA32(kf0, qf[cc], s0);
        s1 = MFMA32(kf1, qf[cc], s1);
      }
      __builtin_amdgcn_s_setprio(0);
      if (t == myqb) {
#pragma unroll
        for (int rr = 0; rr < 16; ++rr) {
          const int koff = (rr & 3) + 8 * (rr >> 2) + 4 * h8;
          if (koff > qrel) s0[rr] = -1e30f;
          if (koff + 32 > qrel) s1[rr] = -1e30f;
        }
      }
#pragma unroll
      for (int rr = 0; rr < 16; ++rr) {
        s0[rr] = exp2f(s0[rr]);
        s1[rr] = exp2f(s1[rr]);
      }
      float sm[8];
#pragma unroll
      for (int i = 0; i < 8; ++i) sm[i] = (s0[i] + s0[i + 8]) + (s1[i] + s1[i + 8]);
#pragma unroll
      for (int i = 0; i < 4; ++i) sm[i] += sm[i + 4];
      lp += (sm[0] + sm[1]) + (sm[2] + sm[3]);

      unsigned pk0[8], pk1[8];
#pragma unroll
      for (int g = 0; g < 4; ++g)
#pragma unroll
        for (int j = 0; j < 2; ++j) {
          pk0[g * 2 + j] = pk2(s0[g * 4 + 2 * j], s0[g * 4 + 2 * j + 1]);
          pk1[g * 2 + j] = pk2(s1[g * 4 + 2 * j], s1[g * 4 + 2 * j + 1]);
        }
      __builtin_amdgcn_s_setprio(1);
#pragma unroll
      for (int cc = 0; cc < 4; ++cc) {
        const int g0 = (cc & 1) * 2, g1 = g0 + 1;
        const unsigned pA0 = (cc & 2) ? pk1[g0 * 2 + 0] : pk0[g0 * 2 + 0];
        const unsigned pA1 = (cc & 2) ? pk1[g0 * 2 + 1] : pk0[g0 * 2 + 1];
        const unsigned pB0 = (cc & 2) ? pk1[g1 * 2 + 0] : pk0[g1 * 2 + 0];
        const unsigned pB1 = (cc & 2) ? pk1[g1 * 2 + 1] : pk0[g1 * 2 + 1];
        const unsigned t00 = __shfl_xor((int)pA0, 32);
        const unsigned t01 = __shfl_xor((int)pA1, 32);
        const unsigned t10 = __shfl_xor((int)pB0, 32);
        const unsigned t11 = __shfl_xor((int)pB1, 32);
        union { u4v u; s8v s; } pf;
        pf.u[0] = h8 ? t10 : pA0;
        pf.u[1] = h8 ? t11 : pA1;
        pf.u[2] = h8 ? pB0 : t00;
        pf.u[3] = h8 ? pB1 : t01;
        const s8v vf0 = *(const s8v*)(Vt[cur] + l31 * 72 + cc * 16 + h8 * 8);
        const s8v vf1 = *(const s8v*)(Vt[cur] + (32 + l31) * 72 + cc * 16 + h8 * 8);
        o0 = MFMA32(vf0, pf.s, o0);
        o1 = MFMA32(vf1, pf.s, o1);
      }
      __builtin_amdgcn_s_setprio(0);
    }
    if (t + 2 <= qbA) {
      WRITET(cur ^ 1);
      if (t + 4 <= qbA) LOADT(t + 4);
      __syncthreads();
    }
  }

  lp += __shfl_xor(lp, 32);

  const size_t obase = ((size_t)kh * 12 + h) * 16 * 4096;
#pragma unroll
  for (int g = 0; g < 4; ++g) {
    const uint2 v0 = make_uint2(pk2(o0[g * 4], o0[g * 4 + 1]), pk2(o0[g * 4 + 2], o0[g * 4 + 3]));
    const uint2 v1 = make_uint2(pk2(o1[g * 4], o1[g * 4 + 1]), pk2(o1[g * 4 + 2], o1[g * 4 + 3]));
    Opart[obase + (size_t)(2 * g + h8) * 4096 + q_abs] = v0;
    Opart[obase + (size_t)(8 + 2 * g + h8) * 4096 + q_abs] = v1;
  }
  if (h8 == 0)
    ml[((size_t)kh * 12 + h) * 4096 + q_abs] = lp;
#undef LOADT
#undef WRITET
}

// ---------------- combine 2 key-parity partials -> attn bf16 [q][768] ----------------
__global__ __launch_bounds__(256) void combine_k(const uint2* __restrict__ Opart,
    const float* __restrict__ ml, unsigned short* __restrict__ out) {
  const int u = blockIdx.x * 256 + threadIdx.x;
  const int q = u & 4095;
  const int rest = u >> 12;
  const int dgrp = rest & 15;
  const int h = rest >> 4;
  const float l0 = ml[h * 4096 + q];
  const float l1 = ml[12 * 4096 + h * 4096 + q];
  const float inv = 1.0f / (l0 + l1);
  const size_t idx = ((size_t)h * 16 + dgrp) * 4096 + q;
  const uint2 a = Opart[idx];
  const uint2 b = Opart[(size_t)12 * 16 * 4096 + idx];
  const int dbase = (dgrp < 8) ? 4 * dgrp : 32 + 4 * (dgrp - 8);
  ushort4 r;
  r.x = f2b((b2f(a.x) + b2f(b.x)) * inv);
  r.y = f2b((b2f(a.x >> 16) + b2f(b.x >> 16)) * inv);
  r.z = f2b((b2f(a.y) + b2f(b.y)) * inv);
  r.w = f2b((b2f(a.y >> 16) + b2f(b.y >> 16)) * inv);
  *(ushort4*)(out + (size_t)q * 768 + h * 64 + dbase) = r;
}

extern "C" void kernel_launch(void* const* d_in, const int* in_sizes, int n_in,
                              void* d_out, int out_size, void* d_ws, size_t ws_size,
                              hipStream_t stream) {
  const float* x    = (const float*)d_in[0];
  const float* w_q  = (const float*)d_in[1];
  const float* w_k  = (const float*)d_in[2];
  const float* w_v  = (const float*)d_in[3];
  const float* w_o  = (const float*)d_in[4];
  const float* w_g  = (const float*)d_in[5];
  const float* w_u  = (const float*)d_in[6];
  const float* w_d  = (const float*)d_in[7];
  const float* w_n1 = (const float*)d_in[8];
  const float* w_n2 = (const float*)d_in[9];
  (void)in_sizes; (void)n_in; (void)out_size; (void)ws_size;

  char* ws = (char*)d_ws;
  size_t off = 0;
  auto alloc = [&](size_t bytes) { char* p = ws + off; off += (bytes + 255) & ~(size_t)255; return p; };
  unsigned short* wqkvT = (unsigned short*)alloc(2304ull * 768 * 2);
  unsigned short* woT   = (unsigned short*)alloc(768ull * 768 * 2);
  unsigned short* wguT  = (unsigned short*)alloc(4096ull * 768 * 2);
  unsigned short* wdT   = (unsigned short*)alloc(768ull * 2048 * 2);
  float* ct             = (float*)alloc(4096ull * 32 * 4);
  float* st             = (float*)alloc(4096ull * 32 * 4);
  unsigned short* xn    = (unsigned short*)alloc(4096ull * 768 * 2);
  unsigned short* qkv   = (unsigned short*)alloc(4096ull * 2304 * 2);
  unsigned short* attn  = (unsigned short*)alloc(4096ull * 768 * 2);
  unsigned short* hb16  = (unsigned short*)alloc(4096ull * 768 * 2);
  float* rn2            = (float*)alloc(4096ull * 4);
  unsigned short* ffn   = (unsigned short*)alloc(4096ull * 2048 * 2);
  uint2* Opart          = (uint2*)alloc(2ull * 12 * 16 * 4096 * 8);
  float* mlb            = (float*)alloc(2ull * 12 * 4096 * 4);

  PrepArgs pa;
  pa.seg[0] = { w_q, wqkvT,                 768,  768, 24,  576, 0 };
  pa.seg[1] = { w_k, wqkvT + 768 * 768,     768,  768, 24,  576, 0 };
  pa.seg[2] = { w_v, wqkvT + 2 * 768 * 768, 768,  768, 24,  576, 0 };
  pa.seg[3] = { w_o, woT,                   768,  768, 24,  576, 0 };
  pa.seg[4] = { w_g, wguT,                  768, 2048, 64, 1536, 1 };
  pa.seg[5] = { w_u, wguT,                  768, 2048, 64, 1536, 2 };
  pa.seg[6] = { w_d, wdT,                  2048,  768, 24, 1536, 0 };
  pa.seg[7] = { nullptr, nullptr, 0, 0, 0, 512, 3 };
  pa.seg[8] = { x, xn, 0, 0, 0, 4096, 4 };
  pa.ct = ct; pa.st = st; pa.wn1 = w_n1; pa.wn2 = w_n2;
  const int prep_blocks = 576 * 4 + 1536 * 3 + 512 + 4096;   // 11520

  prep_k<<<prep_blocks, 256, 0, stream>>>(pa);
  // qkv = xn @ [Wq|Wk|Wv] + RoPE + Q pre-scale; 576 blocks = 32(M/128) x 18(N/128)
  gemm_bt<2, 128, 128><<<576, 256, 0, stream>>>(xn, wqkvT, qkv, nullptr, nullptr, nullptr, 768, 2304, ct, st, 18);
  flash_k<<<dim3(2, 32, 12), 256, 0, stream>>>(qkv, Opart, mlb);
  combine_k<<<3072, 256, 0, stream>>>(Opart, mlb, attn);
  // h = attn @ Wo + x (bf16 out); 768 blocks = 64 x 12, exactly 3/CU
  gemm_bt<4, 64, 64><<<768, 256, 0, stream>>>(attn, woT, hb16, nullptr, x, nullptr, 768, 768, nullptr, nullptr, 12);
  // rn2[row] = rsqrt(mean(h^2)+eps) -- w_norm2 folded into wguT at prep
  rn2_k<<<4096, 256, 0, stream>>>(hb16, rn2);
  // ffn = silu(rn*(h@Wg'))*(rn*(h@Wu')); 512 blocks = 16 x 32, exactly 2/CU
  gemm_big<3><<<512, 512, 0, stream>>>(hb16, wguT, ffn, rn2, 768, 2048, 32);
  // out = ffn @ Wd + h(bf16); 768 blocks = 64 x 12, exactly 3/CU
  gemm_bt<5, 64, 64><<<768, 256, 0, stream>>>(ffn, wdT, nullptr, (float*)d_out, nullptr, hb16, 2048, 768, nullptr, nullptr, 12);
}

// Round 19
// 198.753 us; speedup vs baseline: 1.0689x; 1.0116x over previous
//
#include <hip/hip_runtime.h>
#include <hip/hip_bf16.h>

typedef __attribute__((ext_vector_type(8))) short s8v;
typedef __attribute__((ext_vector_type(4))) float f4v;
typedef __attribute__((ext_vector_type(16))) float f16v;
typedef __attribute__((ext_vector_type(4))) unsigned u4v;

typedef __attribute__((address_space(1))) const void as1_void;
typedef __attribute__((address_space(3))) void as3_void;

__device__ __forceinline__ void gl16(const void* g, void* l) {
  __builtin_amdgcn_global_load_lds((as1_void*)g, (as3_void*)l, 16, 0, 0);
}

__device__ __forceinline__ float b2f(int u) {
  union { float f; unsigned i; } c; c.i = ((unsigned)(u & 0xFFFF)) << 16; return c.f;
}
__device__ __forceinline__ unsigned short f2b(float f) {   // RNE
  union { float f; unsigned i; } c; c.f = f;
  unsigned r = c.i + 0x7FFFu + ((c.i >> 16) & 1u);
  return (unsigned short)(r >> 16);
}
__device__ __forceinline__ unsigned pk2(float lo, float hi) {  // 2xbf16 pack
  unsigned u;
  asm("v_cvt_pk_bf16_f32 %0, %1, %2" : "=v"(u) : "v"(lo), "v"(hi));
  return u;
}

#define MFMA16(a, b, c) __builtin_amdgcn_mfma_f32_16x16x32_bf16((a), (b), (c), 0, 0, 0)
#define MFMA32(a, b, c) __builtin_amdgcn_mfma_f32_32x32x16_bf16((a), (b), (c), 0, 0, 0)

// XCD-aware bijective block remap (grid % 8 == 0): contiguous logical blocks per XCD.
__device__ __forceinline__ void xcd_remap(int nbn, int& bm, int& bn) {
  const int flat = blockIdx.x;
  const int u = (flat & 7) * ((int)gridDim.x >> 3) + (flat >> 3);
  bm = u / nbn;
  bn = u - bm * nbn;
}

// -------- fused prep: weight converts (+gu interleave +w_norm2 fold) + rope + rmsnorm1 --------
struct Seg { const float* src; unsigned short* dst; int K; int N; int nbn; int nblocks; int mode; };
struct PrepArgs { Seg seg[9]; float* ct; float* st; const float* wn1; const float* wn2; };

__global__ __launch_bounds__(256) void prep_k(PrepArgs a) {
  int b = blockIdx.x, si = 0;
  while (si < 8 && b >= a.seg[si].nblocks) { b -= a.seg[si].nblocks; ++si; }
  const Seg s = a.seg[si];
  const int tid = threadIdx.x;
  if (s.mode == 3) {               // rope tables [4096][32]
    const int t = b * 256 + tid;
    const int sq = t >> 5, d = t & 31;
    const float inv = powf(10000.0f, -(float)d * (1.0f / 32.0f));
    const float ang = (float)sq * inv;
    a.ct[t] = cosf(ang);
    a.st[t] = sinf(ang);
    return;
  }
  if (s.mode == 4) {               // rmsnorm1: x row b -> bf16
    const float* xr = s.src + (size_t)b * 768;
    float v0 = xr[tid], v1 = xr[tid + 256], v2 = xr[tid + 512];
    float ss = v0 * v0 + v1 * v1 + v2 * v2;
#pragma unroll
    for (int m = 1; m < 64; m <<= 1) ss += __shfl_xor(ss, m, 64);
    __shared__ float sred[4];
    if ((tid & 63) == 0) sred[tid >> 6] = ss;
    __syncthreads();
    const float tot = sred[0] + sred[1] + sred[2] + sred[3];
    const float rn = rsqrtf(tot * (1.0f / 768.0f) + 1e-6f);
    unsigned short* orow = s.dst + (size_t)b * 768;
    orow[tid]       = f2b(v0 * rn * a.wn1[tid]);
    orow[tid + 256] = f2b(v1 * rn * a.wn1[tid + 256]);
    orow[tid + 512] = f2b(v2 * rn * a.wn1[tid + 512]);
    return;
  }
  __shared__ float tile[32][33];
  const int tx = tid & 31, ty = tid >> 5;
  const int bn = b % s.nbn, bk = b / s.nbn;
#pragma unroll
  for (int i = 0; i < 32; i += 8)
    tile[ty + i][tx] = s.src[(size_t)(bk * 32 + ty + i) * s.N + bn * 32 + tx];
  __syncthreads();
  const float kscale = (s.mode == 1 || s.mode == 2) ? a.wn2[bk * 32 + tx] : 1.0f;
#pragma unroll
  for (int i = 0; i < 32; i += 8) {
    int row;
    if (s.mode == 0)      row = bn * 32 + ty + i;
    else                  row = bn * 64 + (s.mode == 2 ? 32 : 0) + ty + i;
    s.dst[(size_t)row * s.K + bk * 32 + tx] = f2b(tile[tx][ty + i] * kscale);
  }
}

// ---------------- per-row inverse-RMS of h (bf16): rn2[row] = rsqrt(mean(h^2)+eps) ----------------
__global__ __launch_bounds__(256) void rn2_k(const unsigned short* __restrict__ x,
    float* __restrict__ rn2) {
  const int row = blockIdx.x, tid = threadIdx.x;
  const unsigned short* xr = x + (size_t)row * 768;
  float v0 = b2f(xr[tid]), v1 = b2f(xr[tid + 256]), v2 = b2f(xr[tid + 512]);
  float ss = v0 * v0 + v1 * v1 + v2 * v2;
#pragma unroll
  for (int m = 1; m < 64; m <<= 1) ss += __shfl_xor(ss, m, 64);
  __shared__ float sred[4];
  if ((tid & 63) == 0) sred[tid >> 6] = ss;
  __syncthreads();
  if (tid == 0) {
    const float tot = sred[0] + sred[1] + sred[2] + sred[3];
    rn2[row] = rsqrtf(tot * (1.0f / 768.0f) + 1e-6f);
  }
}

// ---------------- GEMM template: BM x BN tile, 256 thr, 3-buffer counted-vmcnt, BK=32 ----
// EPI 2: bf16 store + RoPE (cols<1536) + Q pre-scale (cols<768); BM=BN=128
template <int EPI, int BM, int BN>
__global__ __launch_bounds__(256) void gemm_bt(const unsigned short* __restrict__ A,
    const unsigned short* __restrict__ Bt, unsigned short* __restrict__ Cb,
    float* __restrict__ Cf, const float* __restrict__ Rf, const unsigned short* __restrict__ Rb,
    int K, int ldc, const float* __restrict__ ct, const float* __restrict__ st, int nbn) {
  constexpr int ABYTES = BM * 32 * 2;
  constexpr int BBYTES = BN * 32 * 2;
  constexpr int APASS = BM / 64, BPASS = BN / 64;
  constexpr int LPS = APASS + BPASS;
  constexpr bool W2x2 = (BN == 128);
  constexpr int MR = W2x2 ? (BM / 32) : (BM / 64);
  __shared__ unsigned short As[3 * BM * 32];
  __shared__ unsigned short Bs[3 * BN * 32];
  const int tid = threadIdx.x;
  const int lane = tid & 63, wid = tid >> 6;
  const int wrow = W2x2 ? (wid >> 1) * (BM / 2) : wid * (BM / 4);
  const int wcol = W2x2 ? (wid & 1) * 64 : 0;
  const int l15 = lane & 15, l4 = lane >> 4;
  int bm, bn;
  xcd_remap(nbn, bm, bn);

  f4v acc[MR][4] = {};

  const int o0 = tid * 16, o1 = tid * 16 + 4096;
  const int r0 = o0 >> 6, c0 = o0 & 63;
  const int r1 = o1 >> 6, c1 = o1 & 63;
  const size_t ldab = (size_t)K * 2;
  const char* Abyte = (const char*)A;
  const char* Bbyte = (const char*)Bt;
  const size_t a0 = (size_t)(bm * BM + r0) * ldab + c0;
  const size_t a1 = (size_t)(bm * BM + (APASS == 2 ? r1 : r0)) * ldab + c1;
  const size_t b0 = (size_t)(bn * BN + r0) * ldab + c0;
  const size_t b1 = (size_t)(bn * BN + (BPASS == 2 ? r1 : r0)) * ldab + c1;
  char* AsB = (char*)As;
  char* BsB = (char*)Bs;
  const int uoff = wid << 10;

#define STAGEK(I, SL) do { const size_t kb = (size_t)(I) * 64;                 \
    char* Aw = AsB + (SL) * ABYTES;                                            \
    char* Bw = BsB + (SL) * BBYTES;                                            \
    gl16(Abyte + a0 + kb, Aw + uoff);                                          \
    if constexpr (APASS == 2) gl16(Abyte + a1 + kb, Aw + uoff + 4096);         \
    gl16(Bbyte + b0 + kb, Bw + uoff);                                          \
    if constexpr (BPASS == 2) gl16(Bbyte + b1 + kb, Bw + uoff + 4096); } while (0)

  const int NI = K >> 5;
  STAGEK(0, 0);
  STAGEK(1, 1);
  int sel = 0, nsl = 2;

  for (int i = 0; i < NI; ++i) {
    if (i < NI - 1) {
      if constexpr (LPS == 4)      asm volatile("s_waitcnt vmcnt(4)" ::: "memory");
      else if constexpr (LPS == 3) asm volatile("s_waitcnt vmcnt(3)" ::: "memory");
      else                         asm volatile("s_waitcnt vmcnt(2)" ::: "memory");
    } else {
      asm volatile("s_waitcnt vmcnt(0)" ::: "memory");
    }
    __builtin_amdgcn_s_barrier();
    __builtin_amdgcn_sched_barrier(0);
    if (i + 2 < NI) STAGEK(i + 2, nsl);
    const char* Ar = AsB + sel * ABYTES;
    const char* Br = BsB + sel * BBYTES;
    s8v af[MR], bf[4];
#pragma unroll
    for (int m = 0; m < MR; ++m)
      af[m] = *(const s8v*)(Ar + (wrow + m * 16 + l15) * 64 + l4 * 16);
#pragma unroll
    for (int n = 0; n < 4; ++n)
      bf[n] = *(const s8v*)(Br + (wcol + n * 16 + l15) * 64 + l4 * 16);
    __builtin_amdgcn_s_setprio(1);
#pragma unroll
    for (int m = 0; m < MR; ++m)
#pragma unroll
      for (int n = 0; n < 4; ++n) acc[m][n] = MFMA16(af[m], bf[n], acc[m][n]);
    __builtin_amdgcn_s_setprio(0);
    sel = (sel == 2) ? 0 : sel + 1;
    nsl = (nsl == 2) ? 0 : nsl + 1;
  }
#undef STAGEK

  const int row0 = bm * BM + wrow;
  const int col0 = bn * BN + wcol;

  if constexpr (EPI == 2) {        // RoPE + Q pre-scale (BN=128: wave spans one head)
    const int colw = col0;
    if (colw < 1536) {             // q|k region: RoPE
#pragma unroll
      for (int m = 0; m < MR; ++m)
#pragma unroll
        for (int r = 0; r < 4; ++r) {
          const int row = row0 + m * 16 + l4 * 4 + r;
#pragma unroll
          for (int n = 0; n < 2; ++n) {
            const int d = n * 16 + l15;
            const float c  = ct[row * 32 + d];
            const float sn = st[row * 32 + d];
            const float aa = acc[m][n][r], bb = acc[m][n + 2][r];
            acc[m][n][r]     = aa * c - bb * sn;
            acc[m][n + 2][r] = bb * c + aa * sn;
          }
        }
    }
    if (colw < 768) {              // q region: pre-scale by 0.125*log2e
      const float QSC = 0.18033688011112042f;
#pragma unroll
      for (int m = 0; m < MR; ++m)
#pragma unroll
        for (int n = 0; n < 4; ++n)
#pragma unroll
          for (int r = 0; r < 4; ++r) acc[m][n][r] *= QSC;
    }
  }

#pragma unroll
  for (int m = 0; m < MR; ++m)
#pragma unroll
    for (int n = 0; n < 4; ++n)
#pragma unroll
      for (int r = 0; r < 4; ++r) {
        const int row = row0 + m * 16 + l4 * 4 + r;
        const int col = col0 + n * 16 + l15;
        const float v = acc[m][n][r];
        const size_t idx = (size_t)row * ldc + col;
        if (EPI == 4)      Cb[idx] = f2b(v + Rf[idx]);
        else if (EPI == 5) Cf[idx] = v + b2f(Rb[idx]);
        else               Cb[idx] = f2b(v);
      }
}

// ---------------- 64x64 GEMM, BK=64: 3-buffer counted vmcnt(4), 8 MFMA/iter ----------------
// EPI 4: bf16 store of (v + Rf[fp32]);  EPI 5: fp32 store of (v + b2f(Rb[bf16]))
template <int EPI>
__global__ __launch_bounds__(256) void gemm_k64(const unsigned short* __restrict__ A,
    const unsigned short* __restrict__ Bt, unsigned short* __restrict__ Cb,
    float* __restrict__ Cf, const float* __restrict__ Rf, const unsigned short* __restrict__ Rb,
    int K, int ldc, int nbn) {
  constexpr int TBYTES = 64 * 64 * 2;   // 8 KB per operand per stage
  __shared__ unsigned short As[3 * 64 * 64];
  __shared__ unsigned short Bs[3 * 64 * 64];
  const int tid = threadIdx.x;
  const int lane = tid & 63, wid = tid >> 6;
  const int wrow = wid * 16;
  const int l15 = lane & 15, l4 = lane >> 4;
  int bm, bn;
  xcd_remap(nbn, bm, bn);

  f4v acc[4] = {};

  // staging: thread t <-> byte t*16 of each 8KB half (rows of 128B)
  const int r0 = tid >> 3, c0 = (tid & 7) * 16;
  const size_t ldab = (size_t)K * 2;
  const char* Abyte = (const char*)A;
  const char* Bbyte = (const char*)Bt;
  const size_t a0 = (size_t)(bm * 64 + r0) * ldab + c0;
  const size_t a1 = (size_t)(bm * 64 + 32 + r0) * ldab + c0;
  const size_t b0 = (size_t)(bn * 64 + r0) * ldab + c0;
  const size_t b1 = (size_t)(bn * 64 + 32 + r0) * ldab + c0;
  char* AsB = (char*)As;
  char* BsB = (char*)Bs;
  const int uoff = wid << 10;

#define STAGEK(I, SL) do { const size_t kb = (size_t)(I) * 128;                \
    char* Aw = AsB + (SL) * TBYTES;                                            \
    char* Bw = BsB + (SL) * TBYTES;                                            \
    gl16(Abyte + a0 + kb, Aw + uoff);                                          \
    gl16(Abyte + a1 + kb, Aw + uoff + 4096);                                   \
    gl16(Bbyte + b0 + kb, Bw + uoff);                                          \
    gl16(Bbyte + b1 + kb, Bw + uoff + 4096); } while (0)

  const int NI = K >> 6;
  STAGEK(0, 0);
  STAGEK(1, 1);
  int sel = 0, nsl = 2;

  for (int i = 0; i < NI; ++i) {
    if (i < NI - 1) asm volatile("s_waitcnt vmcnt(4)" ::: "memory");
    else            asm volatile("s_waitcnt vmcnt(0)" ::: "memory");
    __builtin_amdgcn_s_barrier();
    __builtin_amdgcn_sched_barrier(0);
    if (i + 2 < NI) STAGEK(i + 2, nsl);
    const char* Ar = AsB + sel * TBYTES;
    const char* Br = BsB + sel * TBYTES;
#pragma unroll
    for (int kk = 0; kk < 2; ++kk) {
      const s8v af = *(const s8v*)(Ar + (wrow + l15) * 128 + kk * 64 + l4 * 16);
      s8v bf[4];
#pragma unroll
      for (int n = 0; n < 4; ++n)
        bf[n] = *(const s8v*)(Br + (n * 16 + l15) * 128 + kk * 64 + l4 * 16);
      __builtin_amdgcn_s_setprio(1);
#pragma unroll
      for (int n = 0; n < 4; ++n) acc[n] = MFMA16(af, bf[n], acc[n]);
      __builtin_amdgcn_s_setprio(0);
    }
    sel = (sel == 2) ? 0 : sel + 1;
    nsl = (nsl == 2) ? 0 : nsl + 1;
  }
#undef STAGEK

  const int row0 = bm * 64 + wrow;
  const int col0 = bn * 64;
#pragma unroll
  for (int n = 0; n < 4; ++n)
#pragma unroll
    for (int r = 0; r < 4; ++r) {
      const int row = row0 + l4 * 4 + r;
      const int col = col0 + n * 16 + l15;
      const float v = acc[n][r];
      const size_t idx = (size_t)row * ldc + col;
      if (EPI == 4) Cb[idx] = f2b(v + Rf[idx]);
      else          Cf[idx] = v + b2f(Rb[idx]);
    }
}

// ---------------- big GEMM: 256(M)x128(N) tile, 512 thr, 8 waves (4Mx2N), BK=32 ----------------
// EPI 3: rn2[row]-scaled silu(g)*u from 32-interleaved (w_norm2-folded) B rows -> bf16
template <int EPI>
__global__ __launch_bounds__(512, 2) void gemm_big(const unsigned short* __restrict__ A,
    const unsigned short* __restrict__ Bt, unsigned short* __restrict__ Cb,
    const float* __restrict__ rn2, int K, int ldc, int nbn) {
  constexpr int ABYTES = 256 * 32 * 2;
  constexpr int BBYTES = 128 * 32 * 2;
  __shared__ unsigned short As[3 * 256 * 32];
  __shared__ unsigned short Bs[3 * 128 * 32];
  const int tid = threadIdx.x;
  const int lane = tid & 63, wid = tid >> 6;
  const int wm = wid >> 1, wn = wid & 1;
  const int wrow = wm * 64, wcol = wn * 64;
  const int l15 = lane & 15, l4 = lane >> 4;
  int bm, bn;
  xcd_remap(nbn, bm, bn);

  f4v acc[4][4] = {};

  const size_t ldab = (size_t)K * 2;
  const char* Ab = (const char*)A;
  const char* Bb = (const char*)Bt;
  const int lrow = lane >> 2, lch = (lane & 3) * 16;
  const size_t aS0 = (size_t)(bm * 256 + wid * 16 + lrow) * ldab + lch;
  const size_t aS1 = (size_t)(bm * 256 + (wid + 8) * 16 + lrow) * ldab + lch;
  const size_t bS  = (size_t)(bn * 128 + wid * 16 + lrow) * ldab + lch;
  char* AsB = (char*)As;
  char* BsB = (char*)Bs;
  const int uA0 = wid << 10, uA1 = (wid + 8) << 10, uB = wid << 10;

#define STAGEK(I, SL) do { const size_t kb = (size_t)(I) * 64;                 \
    gl16(Ab + aS0 + kb, AsB + (SL) * ABYTES + uA0);                            \
    gl16(Ab + aS1 + kb, AsB + (SL) * ABYTES + uA1);                            \
    gl16(Bb + bS  + kb, BsB + (SL) * BBYTES + uB); } while (0)

  const int NI = K >> 5;
  STAGEK(0, 0);
  STAGEK(1, 1);
  int sel = 0, nsl = 2;

  for (int i = 0; i < NI; ++i) {
    if (i < NI - 1) asm volatile("s_waitcnt vmcnt(3)" ::: "memory");
    else            asm volatile("s_waitcnt vmcnt(0)" ::: "memory");
    __builtin_amdgcn_s_barrier();
    __builtin_amdgcn_sched_barrier(0);
    if (i + 2 < NI) STAGEK(i + 2, nsl);
    const char* Ar = AsB + sel * ABYTES;
    const char* Br = BsB + sel * BBYTES;
    s8v af[4], bf[4];
#pragma unroll
    for (int m = 0; m < 4; ++m)
      af[m] = *(const s8v*)(Ar + (wrow + m * 16 + l15) * 64 + l4 * 16);
#pragma unroll
    for (int n = 0; n < 4; ++n)
      bf[n] = *(const s8v*)(Br + (wcol + n * 16 + l15) * 64 + l4 * 16);
    __builtin_amdgcn_s_setprio(1);
#pragma unroll
    for (int m = 0; m < 4; ++m)
#pragma unroll
      for (int n = 0; n < 4; ++n) acc[m][n] = MFMA16(af[m], bf[n], acc[m][n]);
    __builtin_amdgcn_s_setprio(0);
    sel = (sel == 2) ? 0 : sel + 1;
    nsl = (nsl == 2) ? 0 : nsl + 1;
  }
#undef STAGEK

  const int row0 = bm * 256 + wrow;
  const int col0 = bn * 128 + wcol;

  if (EPI == 3) {                  // val = silu(rn*g) * (rn*u)
    const int colb = (bn * 2 + wn) * 32;
#pragma unroll
    for (int m = 0; m < 4; ++m)
#pragma unroll
      for (int r = 0; r < 4; ++r) {
        const int row = row0 + m * 16 + l4 * 4 + r;
        const float rn = rn2[row];
#pragma unroll
        for (int n = 0; n < 2; ++n) {
          const float g = acc[m][n][r] * rn, u = acc[m][n + 2][r] * rn;
          const float val = g * u / (1.0f + __expf(-g));
          Cb[(size_t)row * 2048 + colb + n * 16 + l15] = f2b(val);
        }
      }
    return;
  }

#pragma unroll
  for (int m = 0; m < 4; ++m)
#pragma unroll
    for (int n = 0; n < 4; ++n)
#pragma unroll
      for (int r = 0; r < 4; ++r) {
        const int row = row0 + m * 16 + l4 * 4 + r;
        const int col = col0 + n * 16 + l15;
        Cb[(size_t)row * ldc + col] = f2b(acc[m][n][r]);
      }
}

// ---------------- causal flash attention: 32x32 swapped-QK, 2-way parity, NO online max ----------------
__global__ __launch_bounds__(256, 4) void flash_k(const unsigned short* __restrict__ qkv,
    uint2* __restrict__ Opart, float* __restrict__ ml) {
  const int kh = blockIdx.x, p = blockIdx.y, h = blockIdx.z;
  const int qbA = 63 - p;
  const int tid = threadIdx.x;
  const int wv = tid >> 6, lane = tid & 63;
  const int l31 = lane & 31, h8 = lane >> 5;
  const int myqb = (wv & 1) ? p : qbA;
  const int qrel = (wv >> 1) * 32 + l31;
  const int q_abs = myqb * 64 + qrel;

  __shared__ unsigned short Ks[2][64 * 72];
  __shared__ unsigned short Vt[2][64 * 72];

  const unsigned short* qp = qkv + h * 64;
  const unsigned short* kp = qkv + 768 + h * 64;
  const unsigned short* vp = qkv + 1536 + h * 64;

  s8v qf[4];
#pragma unroll
  for (int cc = 0; cc < 4; ++cc)
    qf[cc] = *(const s8v*)(qp + (size_t)q_abs * 2304 + cc * 16 + h8 * 8);

  f16v o0 = {}, o1 = {};
  float lp = 0.f;

  const int krow = tid >> 3, kc = (tid & 7) * 8;
  const int vj = tid & 31, vd0 = (tid >> 5) * 8;

  s8v ka, kb, va, vb;
#define LOADT(T) do { const size_t k0n = (size_t)(T) * 64;                    \
    ka = *(const s8v*)(kp + (k0n + krow) * 2304 + kc);                        \
    kb = *(const s8v*)(kp + (k0n + krow + 32) * 2304 + kc);                   \
    va = *(const s8v*)(vp + (k0n + 2 * vj) * 2304 + vd0);                     \
    vb = *(const s8v*)(vp + (k0n + 2 * vj + 1) * 2304 + vd0); } while (0)
#define WRITET(BUF) do {                                                      \
    *(s8v*)(Ks[BUF] + krow * 72 + kc) = ka;                                   \
    *(s8v*)(Ks[BUF] + (krow + 32) * 72 + kc) = kb;                            \
    unsigned* vtw = (unsigned*)(Vt[BUF] + (size_t)vd0 * 72 + 2 * vj);         \
    _Pragma("unroll")                                                         \
    for (int i = 0; i < 8; ++i)                                               \
      vtw[i * 36] = ((unsigned)(unsigned short)va[i]) |                       \
                    (((unsigned)(unsigned short)vb[i]) << 16); } while (0)

  LOADT(kh);
  WRITET(0);
  if (kh + 2 <= qbA) LOADT(kh + 2);
  __syncthreads();

  for (int t = kh; t <= qbA; t += 2) {
    const int cur = (t >> 1) & 1;
    if (t <= myqb) {
      f16v s0 = {}, s1 = {};
      __builtin_amdgcn_s_setprio(1);
#pragma unroll
      for (int cc = 0; cc < 4; ++cc) {
        const s8v kf0 = *(const s8v*)(Ks[cur] + l31 * 72 + cc * 16 + h8 * 8);
        const s8v kf1 = *(const s8v*)(Ks[cur] + (32 + l31) * 72 + cc * 16 + h8 * 8);
        s0 = MFMA32(kf0, qf[cc], s0);
        s1 = MFMA32(kf1, qf[cc], s1);
      }
      __builtin_amdgcn_s_setprio(0);
      if (t == myqb) {
#pragma unroll
        for (int rr = 0; rr < 16; ++rr) {
          const int koff = (rr & 3) + 8 * (rr >> 2) + 4 * h8;
          if (koff > qrel) s0[rr] = -1e30f;
          if (koff + 32 > qrel) s1[rr] = -1e30f;
        }
      }
#pragma unroll
      for (int rr = 0; rr < 16; ++rr) {
        s0[rr] = exp2f(s0[rr]);
        s1[rr] = exp2f(s1[rr]);
      }
      float sm[8];
#pragma unroll
      for (int i = 0; i < 8; ++i) sm[i] = (s0[i] + s0[i + 8]) + (s1[i] + s1[i + 8]);
#pragma unroll
      for (int i = 0; i < 4; ++i) sm[i] += sm[i + 4];
      lp += (sm[0] + sm[1]) + (sm[2] + sm[3]);

      unsigned pk0[8], pk1[8];
#pragma unroll
      for (int g = 0; g < 4; ++g)
#pragma unroll
        for (int j = 0; j < 2; ++j) {
          pk0[g * 2 + j] = pk2(s0[g * 4 + 2 * j], s0[g * 4 + 2 * j + 1]);
          pk1[g * 2 + j] = pk2(s1[g * 4 + 2 * j], s1[g * 4 + 2 * j + 1]);
        }
      __builtin_amdgcn_s_setprio(1);
#pragma unroll
      for (int cc = 0; cc < 4; ++cc) {
        const int g0 = (cc & 1) * 2, g1 = g0 + 1;
        const unsigned pA0 = (cc & 2) ? pk1[g0 * 2 + 0] : pk0[g0 * 2 + 0];
        const unsigned pA1 = (cc & 2) ? pk1[g0 * 2 + 1] : pk0[g0 * 2 + 1];
        const unsigned pB0 = (cc & 2) ? pk1[g1 * 2 + 0] : pk0[g1 * 2 + 0];
        const unsigned pB1 = (cc & 2) ? pk1[g1 * 2 + 1] : pk0[g1 * 2 + 1];
        const unsigned t00 = __shfl_xor((int)pA0, 32);
        const unsigned t01 = __shfl_xor((int)pA1, 32);
        const unsigned t10 = __shfl_xor((int)pB0, 32);
        const unsigned t11 = __shfl_xor((int)pB1, 32);
        union { u4v u; s8v s; } pf;
        pf.u[0] = h8 ? t10 : pA0;
        pf.u[1] = h8 ? t11 : pA1;
        pf.u[2] = h8 ? pB0 : t00;
        pf.u[3] = h8 ? pB1 : t01;
        const s8v vf0 = *(const s8v*)(Vt[cur] + l31 * 72 + cc * 16 + h8 * 8);
        const s8v vf1 = *(const s8v*)(Vt[cur] + (32 + l31) * 72 + cc * 16 + h8 * 8);
        o0 = MFMA32(vf0, pf.s, o0);
        o1 = MFMA32(vf1, pf.s, o1);
      }
      __builtin_amdgcn_s_setprio(0);
    }
    if (t + 2 <= qbA) {
      WRITET(cur ^ 1);
      if (t + 4 <= qbA) LOADT(t + 4);
      __syncthreads();
    }
  }

  lp += __shfl_xor(lp, 32);

  const size_t obase = ((size_t)kh * 12 + h) * 16 * 4096;
#pragma unroll
  for (int g = 0; g < 4; ++g) {
    const uint2 v0 = make_uint2(pk2(o0[g * 4], o0[g * 4 + 1]), pk2(o0[g * 4 + 2], o0[g * 4 + 3]));
    const uint2 v1 = make_uint2(pk2(o1[g * 4], o1[g * 4 + 1]), pk2(o1[g * 4 + 2], o1[g * 4 + 3]));
    Opart[obase + (size_t)(2 * g + h8) * 4096 + q_abs] = v0;
    Opart[obase + (size_t)(8 + 2 * g + h8) * 4096 + q_abs] = v1;
  }
  if (h8 == 0)
    ml[((size_t)kh * 12 + h) * 4096 + q_abs] = lp;
#undef LOADT
#undef WRITET
}

// ---------------- combine 2 key-parity partials -> attn bf16 [q][768] ----------------
__global__ __launch_bounds__(256) void combine_k(const uint2* __restrict__ Opart,
    const float* __restrict__ ml, unsigned short* __restrict__ out) {
  const int u = blockIdx.x * 256 + threadIdx.x;
  const int q = u & 4095;
  const int rest = u >> 12;
  const int dgrp = rest & 15;
  const int h = rest >> 4;
  const float l0 = ml[h * 4096 + q];
  const float l1 = ml[12 * 4096 + h * 4096 + q];
  const float inv = 1.0f / (l0 + l1);
  const size_t idx = ((size_t)h * 16 + dgrp) * 4096 + q;
  const uint2 a = Opart[idx];
  const uint2 b = Opart[(size_t)12 * 16 * 4096 + idx];
  const int dbase = (dgrp < 8) ? 4 * dgrp : 32 + 4 * (dgrp - 8);
  ushort4 r;
  r.x = f2b((b2f(a.x) + b2f(b.x)) * inv);
  r.y = f2b((b2f(a.x >> 16) + b2f(b.x >> 16)) * inv);
  r.z = f2b((b2f(a.y) + b2f(b.y)) * inv);
  r.w = f2b((b2f(a.y >> 16) + b2f(b.y >> 16)) * inv);
  *(ushort4*)(out + (size_t)q * 768 + h * 64 + dbase) = r;
}

extern "C" void kernel_launch(void* const* d_in, const int* in_sizes, int n_in,
                              void* d_out, int out_size, void* d_ws, size_t ws_size,
                              hipStream_t stream) {
  const float* x    = (const float*)d_in[0];
  const float* w_q  = (const float*)d_in[1];
  const float* w_k  = (const float*)d_in[2];
  const float* w_v  = (const float*)d_in[3];
  const float* w_o  = (const float*)d_in[4];
  const float* w_g  = (const float*)d_in[5];
  const float* w_u  = (const float*)d_in[6];
  const float* w_d  = (const float*)d_in[7];
  const float* w_n1 = (const float*)d_in[8];
  const float* w_n2 = (const float*)d_in[9];
  (void)in_sizes; (void)n_in; (void)out_size; (void)ws_size;

  char* ws = (char*)d_ws;
  size_t off = 0;
  auto alloc = [&](size_t bytes) { char* p = ws + off; off += (bytes + 255) & ~(size_t)255; return p; };
  unsigned short* wqkvT = (unsigned short*)alloc(2304ull * 768 * 2);
  unsigned short* woT   = (unsigned short*)alloc(768ull * 768 * 2);
  unsigned short* wguT  = (unsigned short*)alloc(4096ull * 768 * 2);
  unsigned short* wdT   = (unsigned short*)alloc(768ull * 2048 * 2);
  float* ct             = (float*)alloc(4096ull * 32 * 4);
  float* st             = (float*)alloc(4096ull * 32 * 4);
  unsigned short* xn    = (unsigned short*)alloc(4096ull * 768 * 2);
  unsigned short* qkv   = (unsigned short*)alloc(4096ull * 2304 * 2);
  unsigned short* attn  = (unsigned short*)alloc(4096ull * 768 * 2);
  unsigned short* hb16  = (unsigned short*)alloc(4096ull * 768 * 2);
  float* rn2            = (float*)alloc(4096ull * 4);
  unsigned short* ffn   = (unsigned short*)alloc(4096ull * 2048 * 2);
  uint2* Opart          = (uint2*)alloc(2ull * 12 * 16 * 4096 * 8);
  float* mlb            = (float*)alloc(2ull * 12 * 4096 * 4);

  PrepArgs pa;
  pa.seg[0] = { w_q, wqkvT,                 768,  768, 24,  576, 0 };
  pa.seg[1] = { w_k, wqkvT + 768 * 768,     768,  768, 24,  576, 0 };
  pa.seg[2] = { w_v, wqkvT + 2 * 768 * 768, 768,  768, 24,  576, 0 };
  pa.seg[3] = { w_o, woT,                   768,  768, 24,  576, 0 };
  pa.seg[4] = { w_g, wguT,                  768, 2048, 64, 1536, 1 };
  pa.seg[5] = { w_u, wguT,                  768, 2048, 64, 1536, 2 };
  pa.seg[6] = { w_d, wdT,                  2048,  768, 24, 1536, 0 };
  pa.seg[7] = { nullptr, nullptr, 0, 0, 0, 512, 3 };
  pa.seg[8] = { x, xn, 0, 0, 0, 4096, 4 };
  pa.ct = ct; pa.st = st; pa.wn1 = w_n1; pa.wn2 = w_n2;
  const int prep_blocks = 576 * 4 + 1536 * 3 + 512 + 4096;   // 11520

  prep_k<<<prep_blocks, 256, 0, stream>>>(pa);
  // qkv = xn @ [Wq|Wk|Wv] + RoPE + Q pre-scale; 576 blocks = 32(M/128) x 18(N/128)
  gemm_bt<2, 128, 128><<<576, 256, 0, stream>>>(xn, wqkvT, qkv, nullptr, nullptr, nullptr, 768, 2304, ct, st, 18);
  flash_k<<<dim3(2, 32, 12), 256, 0, stream>>>(qkv, Opart, mlb);
  combine_k<<<3072, 256, 0, stream>>>(Opart, mlb, attn);
  // h = attn @ Wo + x (bf16 out); BK=64, 768 blocks = 64 x 12, 3/CU
  gemm_k64<4><<<768, 256, 0, stream>>>(attn, woT, hb16, nullptr, x, nullptr, 768, 768, 12);
  // rn2[row] = rsqrt(mean(h^2)+eps) -- w_norm2 folded into wguT at prep
  rn2_k<<<4096, 256, 0, stream>>>(hb16, rn2);
  // ffn = silu(rn*(h@Wg'))*(rn*(h@Wu')); 512 blocks = 16 x 32, exactly 2/CU
  gemm_big<3><<<512, 512, 0, stream>>>(hb16, wguT, ffn, rn2, 768, 2048, 32);
  // out = ffn @ Wd + h(bf16); BK=64, 768 blocks = 64 x 12, 3/CU
  gemm_k64<5><<<768, 256, 0, stream>>>(ffn, wdT, nullptr, (float*)d_out, nullptr, hb16, 2048, 768, 12);
}

// Round 20
// 197.484 us; speedup vs baseline: 1.0758x; 1.0064x over previous
//
#include <hip/hip_runtime.h>
#include <hip/hip_bf16.h>

typedef __attribute__((ext_vector_type(8))) short s8v;
typedef __attribute__((ext_vector_type(4))) float f4v;
typedef __attribute__((ext_vector_type(16))) float f16v;
typedef __attribute__((ext_vector_type(4))) unsigned u4v;

typedef __attribute__((address_space(1))) const void as1_void;
typedef __attribute__((address_space(3))) void as3_void;

__device__ __forceinline__ void gl16(const void* g, void* l) {
  __builtin_amdgcn_global_load_lds((as1_void*)g, (as3_void*)l, 16, 0, 0);
}

__device__ __forceinline__ float b2f(int u) {
  union { float f; unsigned i; } c; c.i = ((unsigned)(u & 0xFFFF)) << 16; return c.f;
}
__device__ __forceinline__ unsigned short f2b(float f) {   // RNE
  union { float f; unsigned i; } c; c.f = f;
  unsigned r = c.i + 0x7FFFu + ((c.i >> 16) & 1u);
  return (unsigned short)(r >> 16);
}
__device__ __forceinline__ unsigned pk2(float lo, float hi) {  // 2xbf16 pack
  unsigned u;
  asm("v_cvt_pk_bf16_f32 %0, %1, %2" : "=v"(u) : "v"(lo), "v"(hi));
  return u;
}

#define MFMA16(a, b, c) __builtin_amdgcn_mfma_f32_16x16x32_bf16((a), (b), (c), 0, 0, 0)
#define MFMA32(a, b, c) __builtin_amdgcn_mfma_f32_32x32x16_bf16((a), (b), (c), 0, 0, 0)

// XCD-aware bijective block remap (grid % 8 == 0): contiguous logical blocks per XCD.
__device__ __forceinline__ void xcd_remap(int nbn, int& bm, int& bn) {
  const int flat = blockIdx.x;
  const int u = (flat & 7) * ((int)gridDim.x >> 3) + (flat >> 3);
  bm = u / nbn;
  bn = u - bm * nbn;
}

// -------- fused prep: weight converts (+gu interleave +w_norm2 fold) + rope + rmsnorm1 --------
struct Seg { const float* src; unsigned short* dst; int K; int N; int nbn; int nblocks; int mode; };
struct PrepArgs { Seg seg[9]; float* ct; float* st; const float* wn1; const float* wn2; };

__global__ __launch_bounds__(256) void prep_k(PrepArgs a) {
  int b = blockIdx.x, si = 0;
  while (si < 8 && b >= a.seg[si].nblocks) { b -= a.seg[si].nblocks; ++si; }
  const Seg s = a.seg[si];
  const int tid = threadIdx.x;
  if (s.mode == 3) {               // rope tables [4096][32]
    const int t = b * 256 + tid;
    const int sq = t >> 5, d = t & 31;
    const float inv = powf(10000.0f, -(float)d * (1.0f / 32.0f));
    const float ang = (float)sq * inv;
    a.ct[t] = cosf(ang);
    a.st[t] = sinf(ang);
    return;
  }
  if (s.mode == 4) {               // rmsnorm1: x row b -> bf16
    const float* xr = s.src + (size_t)b * 768;
    float v0 = xr[tid], v1 = xr[tid + 256], v2 = xr[tid + 512];
    float ss = v0 * v0 + v1 * v1 + v2 * v2;
#pragma unroll
    for (int m = 1; m < 64; m <<= 1) ss += __shfl_xor(ss, m, 64);
    __shared__ float sred[4];
    if ((tid & 63) == 0) sred[tid >> 6] = ss;
    __syncthreads();
    const float tot = sred[0] + sred[1] + sred[2] + sred[3];
    const float rn = rsqrtf(tot * (1.0f / 768.0f) + 1e-6f);
    unsigned short* orow = s.dst + (size_t)b * 768;
    orow[tid]       = f2b(v0 * rn * a.wn1[tid]);
    orow[tid + 256] = f2b(v1 * rn * a.wn1[tid + 256]);
    orow[tid + 512] = f2b(v2 * rn * a.wn1[tid + 512]);
    return;
  }
  __shared__ float tile[32][33];
  const int tx = tid & 31, ty = tid >> 5;
  const int bn = b % s.nbn, bk = b / s.nbn;
#pragma unroll
  for (int i = 0; i < 32; i += 8)
    tile[ty + i][tx] = s.src[(size_t)(bk * 32 + ty + i) * s.N + bn * 32 + tx];
  __syncthreads();
  const float kscale = (s.mode == 1 || s.mode == 2) ? a.wn2[bk * 32 + tx] : 1.0f;
#pragma unroll
  for (int i = 0; i < 32; i += 8) {
    int row;
    if (s.mode == 0)      row = bn * 32 + ty + i;
    else                  row = bn * 64 + (s.mode == 2 ? 32 : 0) + ty + i;
    s.dst[(size_t)row * s.K + bk * 32 + tx] = f2b(tile[tx][ty + i] * kscale);
  }
}

// ---------------- GEMM template: BM x BN tile, 256 thr, 3-buffer counted-vmcnt, BK=32 ----
// EPI 2: bf16 store + RoPE (cols<1536) + Q pre-scale (cols<768); BM=BN=128
template <int EPI, int BM, int BN>
__global__ __launch_bounds__(256) void gemm_bt(const unsigned short* __restrict__ A,
    const unsigned short* __restrict__ Bt, unsigned short* __restrict__ Cb,
    float* __restrict__ Cf, const float* __restrict__ Rf, const unsigned short* __restrict__ Rb,
    int K, int ldc, const float* __restrict__ ct, const float* __restrict__ st, int nbn) {
  constexpr int ABYTES = BM * 32 * 2;
  constexpr int BBYTES = BN * 32 * 2;
  constexpr int APASS = BM / 64, BPASS = BN / 64;
  constexpr int LPS = APASS + BPASS;
  constexpr bool W2x2 = (BN == 128);
  constexpr int MR = W2x2 ? (BM / 32) : (BM / 64);
  __shared__ unsigned short As[3 * BM * 32];
  __shared__ unsigned short Bs[3 * BN * 32];
  const int tid = threadIdx.x;
  const int lane = tid & 63, wid = tid >> 6;
  const int wrow = W2x2 ? (wid >> 1) * (BM / 2) : wid * (BM / 4);
  const int wcol = W2x2 ? (wid & 1) * 64 : 0;
  const int l15 = lane & 15, l4 = lane >> 4;
  int bm, bn;
  xcd_remap(nbn, bm, bn);

  f4v acc[MR][4] = {};

  const int o0 = tid * 16, o1 = tid * 16 + 4096;
  const int r0 = o0 >> 6, c0 = o0 & 63;
  const int r1 = o1 >> 6, c1 = o1 & 63;
  const size_t ldab = (size_t)K * 2;
  const char* Abyte = (const char*)A;
  const char* Bbyte = (const char*)Bt;
  const size_t a0 = (size_t)(bm * BM + r0) * ldab + c0;
  const size_t a1 = (size_t)(bm * BM + (APASS == 2 ? r1 : r0)) * ldab + c1;
  const size_t b0 = (size_t)(bn * BN + r0) * ldab + c0;
  const size_t b1 = (size_t)(bn * BN + (BPASS == 2 ? r1 : r0)) * ldab + c1;
  char* AsB = (char*)As;
  char* BsB = (char*)Bs;
  const int uoff = wid << 10;

#define STAGEK(I, SL) do { const size_t kb = (size_t)(I) * 64;                 \
    char* Aw = AsB + (SL) * ABYTES;                                            \
    char* Bw = BsB + (SL) * BBYTES;                                            \
    gl16(Abyte + a0 + kb, Aw + uoff);                                          \
    if constexpr (APASS == 2) gl16(Abyte + a1 + kb, Aw + uoff + 4096);         \
    gl16(Bbyte + b0 + kb, Bw + uoff);                                          \
    if constexpr (BPASS == 2) gl16(Bbyte + b1 + kb, Bw + uoff + 4096); } while (0)

  const int NI = K >> 5;
  STAGEK(0, 0);
  STAGEK(1, 1);
  int sel = 0, nsl = 2;

  for (int i = 0; i < NI; ++i) {
    if (i < NI - 1) {
      if constexpr (LPS == 4)      asm volatile("s_waitcnt vmcnt(4)" ::: "memory");
      else if constexpr (LPS == 3) asm volatile("s_waitcnt vmcnt(3)" ::: "memory");
      else                         asm volatile("s_waitcnt vmcnt(2)" ::: "memory");
    } else {
      asm volatile("s_waitcnt vmcnt(0)" ::: "memory");
    }
    __builtin_amdgcn_s_barrier();
    __builtin_amdgcn_sched_barrier(0);
    if (i + 2 < NI) STAGEK(i + 2, nsl);
    const char* Ar = AsB + sel * ABYTES;
    const char* Br = BsB + sel * BBYTES;
    s8v af[MR], bf[4];
#pragma unroll
    for (int m = 0; m < MR; ++m)
      af[m] = *(const s8v*)(Ar + (wrow + m * 16 + l15) * 64 + l4 * 16);
#pragma unroll
    for (int n = 0; n < 4; ++n)
      bf[n] = *(const s8v*)(Br + (wcol + n * 16 + l15) * 64 + l4 * 16);
    __builtin_amdgcn_s_setprio(1);
#pragma unroll
    for (int m = 0; m < MR; ++m)
#pragma unroll
      for (int n = 0; n < 4; ++n) acc[m][n] = MFMA16(af[m], bf[n], acc[m][n]);
    __builtin_amdgcn_s_setprio(0);
    sel = (sel == 2) ? 0 : sel + 1;
    nsl = (nsl == 2) ? 0 : nsl + 1;
  }
#undef STAGEK

  const int row0 = bm * BM + wrow;
  const int col0 = bn * BN + wcol;

  if constexpr (EPI == 2) {        // RoPE + Q pre-scale (BN=128: wave spans one head)
    const int colw = col0;
    if (colw < 1536) {             // q|k region: RoPE
#pragma unroll
      for (int m = 0; m < MR; ++m)
#pragma unroll
        for (int r = 0; r < 4; ++r) {
          const int row = row0 + m * 16 + l4 * 4 + r;
#pragma unroll
          for (int n = 0; n < 2; ++n) {
            const int d = n * 16 + l15;
            const float c  = ct[row * 32 + d];
            const float sn = st[row * 32 + d];
            const float aa = acc[m][n][r], bb = acc[m][n + 2][r];
            acc[m][n][r]     = aa * c - bb * sn;
            acc[m][n + 2][r] = bb * c + aa * sn;
          }
        }
    }
    if (colw < 768) {              // q region: pre-scale by 0.125*log2e
      const float QSC = 0.18033688011112042f;
#pragma unroll
      for (int m = 0; m < MR; ++m)
#pragma unroll
        for (int n = 0; n < 4; ++n)
#pragma unroll
          for (int r = 0; r < 4; ++r) acc[m][n][r] *= QSC;
    }
  }

#pragma unroll
  for (int m = 0; m < MR; ++m)
#pragma unroll
    for (int n = 0; n < 4; ++n)
#pragma unroll
      for (int r = 0; r < 4; ++r) {
        const int row = row0 + m * 16 + l4 * 4 + r;
        const int col = col0 + n * 16 + l15;
        const float v = acc[m][n][r];
        const size_t idx = (size_t)row * ldc + col;
        Cb[idx] = f2b(v);
      }
}

// ---------------- 64x64 GEMM, BK=64: 3-buffer counted vmcnt(4), 8 MFMA/iter ----------------
// EPI 4: bf16 store of h=(v+Rf[fp32]) + atomic row-sum of h^2 into ssq (wo)
// EPI 5: fp32 store of (v + b2f(Rb[bf16]))  (down + residual -> d_out)
template <int EPI>
__global__ __launch_bounds__(256) void gemm_k64(const unsigned short* __restrict__ A,
    const unsigned short* __restrict__ Bt, unsigned short* __restrict__ Cb,
    float* __restrict__ Cf, const float* __restrict__ Rf, const unsigned short* __restrict__ Rb,
    float* __restrict__ ssq, int K, int ldc, int nbn) {
  constexpr int TBYTES = 64 * 64 * 2;   // 8 KB per operand per stage
  __shared__ unsigned short As[3 * 64 * 64];
  __shared__ unsigned short Bs[3 * 64 * 64];
  const int tid = threadIdx.x;
  const int lane = tid & 63, wid = tid >> 6;
  const int wrow = wid * 16;
  const int l15 = lane & 15, l4 = lane >> 4;
  int bm, bn;
  xcd_remap(nbn, bm, bn);

  f4v acc[4] = {};

  const int r0 = tid >> 3, c0 = (tid & 7) * 16;
  const size_t ldab = (size_t)K * 2;
  const char* Abyte = (const char*)A;
  const char* Bbyte = (const char*)Bt;
  const size_t a0 = (size_t)(bm * 64 + r0) * ldab + c0;
  const size_t a1 = (size_t)(bm * 64 + 32 + r0) * ldab + c0;
  const size_t b0 = (size_t)(bn * 64 + r0) * ldab + c0;
  const size_t b1 = (size_t)(bn * 64 + 32 + r0) * ldab + c0;
  char* AsB = (char*)As;
  char* BsB = (char*)Bs;
  const int uoff = wid << 10;

#define STAGEK(I, SL) do { const size_t kb = (size_t)(I) * 128;                \
    char* Aw = AsB + (SL) * TBYTES;                                            \
    char* Bw = BsB + (SL) * TBYTES;                                            \
    gl16(Abyte + a0 + kb, Aw + uoff);                                          \
    gl16(Abyte + a1 + kb, Aw + uoff + 4096);                                   \
    gl16(Bbyte + b0 + kb, Bw + uoff);                                          \
    gl16(Bbyte + b1 + kb, Bw + uoff + 4096); } while (0)

  const int NI = K >> 6;
  STAGEK(0, 0);
  STAGEK(1, 1);
  int sel = 0, nsl = 2;

  for (int i = 0; i < NI; ++i) {
    if (i < NI - 1) asm volatile("s_waitcnt vmcnt(4)" ::: "memory");
    else            asm volatile("s_waitcnt vmcnt(0)" ::: "memory");
    __builtin_amdgcn_s_barrier();
    __builtin_amdgcn_sched_barrier(0);
    if (i + 2 < NI) STAGEK(i + 2, nsl);
    const char* Ar = AsB + sel * TBYTES;
    const char* Br = BsB + sel * TBYTES;
#pragma unroll
    for (int kk = 0; kk < 2; ++kk) {
      const s8v af = *(const s8v*)(Ar + (wrow + l15) * 128 + kk * 64 + l4 * 16);
      s8v bf[4];
#pragma unroll
      for (int n = 0; n < 4; ++n)
        bf[n] = *(const s8v*)(Br + (n * 16 + l15) * 128 + kk * 64 + l4 * 16);
      __builtin_amdgcn_s_setprio(1);
#pragma unroll
      for (int n = 0; n < 4; ++n) acc[n] = MFMA16(af, bf[n], acc[n]);
      __builtin_amdgcn_s_setprio(0);
    }
    sel = (sel == 2) ? 0 : sel + 1;
    nsl = (nsl == 2) ? 0 : nsl + 1;
  }
#undef STAGEK

  const int row0 = bm * 64 + wrow;
  const int col0 = bn * 64;
#pragma unroll
  for (int r = 0; r < 4; ++r) {
    const int row = row0 + l4 * 4 + r;
    float ps = 0.f;
#pragma unroll
    for (int n = 0; n < 4; ++n) {
      const int col = col0 + n * 16 + l15;
      const float v = acc[n][r];
      const size_t idx = (size_t)row * ldc + col;
      if (EPI == 4) {
        const float hv = v + Rf[idx];
        Cb[idx] = f2b(hv);
        ps += hv * hv;
      } else {
        Cf[idx] = v + b2f(Rb[idx]);
      }
    }
    if (EPI == 4) {                 // reduce over the 16 l15 lanes -> one atomic per (row, block)
#pragma unroll
      for (int mm = 1; mm < 16; mm <<= 1) ps += __shfl_xor(ps, mm, 64);
      if (l15 == 0) atomicAdd(&ssq[row], ps);
    }
  }
}

// ---------------- big GEMM: 256(M)x128(N) tile, 512 thr, 8 waves (4Mx2N), BK=32 ----------------
// EPI 3: rn-scaled silu(g)*u; rn computed inline from ssq (sum of h^2 per row)
template <int EPI>
__global__ __launch_bounds__(512, 2) void gemm_big(const unsigned short* __restrict__ A,
    const unsigned short* __restrict__ Bt, unsigned short* __restrict__ Cb,
    const float* __restrict__ ssq, int K, int ldc, int nbn) {
  constexpr int ABYTES = 256 * 32 * 2;
  constexpr int BBYTES = 128 * 32 * 2;
  __shared__ unsigned short As[3 * 256 * 32];
  __shared__ unsigned short Bs[3 * 128 * 32];
  const int tid = threadIdx.x;
  const int lane = tid & 63, wid = tid >> 6;
  const int wm = wid >> 1, wn = wid & 1;
  const int wrow = wm * 64, wcol = wn * 64;
  const int l15 = lane & 15, l4 = lane >> 4;
  int bm, bn;
  xcd_remap(nbn, bm, bn);

  f4v acc[4][4] = {};

  const size_t ldab = (size_t)K * 2;
  const char* Ab = (const char*)A;
  const char* Bb = (const char*)Bt;
  const int lrow = lane >> 2, lch = (lane & 3) * 16;
  const size_t aS0 = (size_t)(bm * 256 + wid * 16 + lrow) * ldab + lch;
  const size_t aS1 = (size_t)(bm * 256 + (wid + 8) * 16 + lrow) * ldab + lch;
  const size_t bS  = (size_t)(bn * 128 + wid * 16 + lrow) * ldab + lch;
  char* AsB = (char*)As;
  char* BsB = (char*)Bs;
  const int uA0 = wid << 10, uA1 = (wid + 8) << 10, uB = wid << 10;

#define STAGEK(I, SL) do { const size_t kb = (size_t)(I) * 64;                 \
    gl16(Ab + aS0 + kb, AsB + (SL) * ABYTES + uA0);                            \
    gl16(Ab + aS1 + kb, AsB + (SL) * ABYTES + uA1);                            \
    gl16(Bb + bS  + kb, BsB + (SL) * BBYTES + uB); } while (0)

  const int NI = K >> 5;
  STAGEK(0, 0);
  STAGEK(1, 1);
  int sel = 0, nsl = 2;

  for (int i = 0; i < NI; ++i) {
    if (i < NI - 1) asm volatile("s_waitcnt vmcnt(3)" ::: "memory");
    else            asm volatile("s_waitcnt vmcnt(0)" ::: "memory");
    __builtin_amdgcn_s_barrier();
    __builtin_amdgcn_sched_barrier(0);
    if (i + 2 < NI) STAGEK(i + 2, nsl);
    const char* Ar = AsB + sel * ABYTES;
    const char* Br = BsB + sel * BBYTES;
    s8v af[4], bf[4];
#pragma unroll
    for (int m = 0; m < 4; ++m)
      af[m] = *(const s8v*)(Ar + (wrow + m * 16 + l15) * 64 + l4 * 16);
#pragma unroll
    for (int n = 0; n < 4; ++n)
      bf[n] = *(const s8v*)(Br + (wcol + n * 16 + l15) * 64 + l4 * 16);
    __builtin_amdgcn_s_setprio(1);
#pragma unroll
    for (int m = 0; m < 4; ++m)
#pragma unroll
      for (int n = 0; n < 4; ++n) acc[m][n] = MFMA16(af[m], bf[n], acc[m][n]);
    __builtin_amdgcn_s_setprio(0);
    sel = (sel == 2) ? 0 : sel + 1;
    nsl = (nsl == 2) ? 0 : nsl + 1;
  }
#undef STAGEK

  const int row0 = bm * 256 + wrow;
  const int col0 = bn * 128 + wcol;

  if (EPI == 3) {                  // val = silu(rn*g) * (rn*u); rn from ssq
    const int colb = (bn * 2 + wn) * 32;
#pragma unroll
    for (int m = 0; m < 4; ++m)
#pragma unroll
      for (int r = 0; r < 4; ++r) {
        const int row = row0 + m * 16 + l4 * 4 + r;
        const float rn = rsqrtf(ssq[row] * (1.0f / 768.0f) + 1e-6f);
#pragma unroll
        for (int n = 0; n < 2; ++n) {
          const float g = acc[m][n][r] * rn, u = acc[m][n + 2][r] * rn;
          const float val = g * u / (1.0f + __expf(-g));
          Cb[(size_t)row * 2048 + colb + n * 16 + l15] = f2b(val);
        }
      }
    return;
  }

#pragma unroll
  for (int m = 0; m < 4; ++m)
#pragma unroll
    for (int n = 0; n < 4; ++n)
#pragma unroll
      for (int r = 0; r < 4; ++r) {
        const int row = row0 + m * 16 + l4 * 4 + r;
        const int col = col0 + n * 16 + l15;
        Cb[(size_t)row * ldc + col] = f2b(acc[m][n][r]);
      }
}

// ---------------- causal flash attention: 32x32 swapped-QK, 2-way parity, NO online max ----------------
__global__ __launch_bounds__(256, 4) void flash_k(const unsigned short* __restrict__ qkv,
    uint2* __restrict__ Opart, float* __restrict__ ml) {
  const int kh = blockIdx.x, p = blockIdx.y, h = blockIdx.z;
  const int qbA = 63 - p;
  const int tid = threadIdx.x;
  const int wv = tid >> 6, lane = tid & 63;
  const int l31 = lane & 31, h8 = lane >> 5;
  const int myqb = (wv & 1) ? p : qbA;
  const int qrel = (wv >> 1) * 32 + l31;
  const int q_abs = myqb * 64 + qrel;

  __shared__ unsigned short Ks[2][64 * 72];
  __shared__ unsigned short Vt[2][64 * 72];

  const unsigned short* qp = qkv + h * 64;
  const unsigned short* kp = qkv + 768 + h * 64;
  const unsigned short* vp = qkv + 1536 + h * 64;

  s8v qf[4];
#pragma unroll
  for (int cc = 0; cc < 4; ++cc)
    qf[cc] = *(const s8v*)(qp + (size_t)q_abs * 2304 + cc * 16 + h8 * 8);

  f16v o0 = {}, o1 = {};
  float lp = 0.f;

  const int krow = tid >> 3, kc = (tid & 7) * 8;
  const int vj = tid & 31, vd0 = (tid >> 5) * 8;

  s8v ka, kb, va, vb;
#define LOADT(T) do { const size_t k0n = (size_t)(T) * 64;                    \
    ka = *(const s8v*)(kp + (k0n + krow) * 2304 + kc);                        \
    kb = *(const s8v*)(kp + (k0n + krow + 32) * 2304 + kc);                   \
    va = *(const s8v*)(vp + (k0n + 2 * vj) * 2304 + vd0);                     \
    vb = *(const s8v*)(vp + (k0n + 2 * vj + 1) * 2304 + vd0); } while (0)
#define WRITET(BUF) do {                                                      \
    *(s8v*)(Ks[BUF] + krow * 72 + kc) = ka;                                   \
    *(s8v*)(Ks[BUF] + (krow + 32) * 72 + kc) = kb;                            \
    unsigned* vtw = (unsigned*)(Vt[BUF] + (size_t)vd0 * 72 + 2 * vj);         \
    _Pragma("unroll")                                                         \
    for (int i = 0; i < 8; ++i)                                               \
      vtw[i * 36] = ((unsigned)(unsigned short)va[i]) |                       \
                    (((unsigned)(unsigned short)vb[i]) << 16); } while (0)

  LOADT(kh);
  WRITET(0);
  if (kh + 2 <= qbA) LOADT(kh + 2);
  __syncthreads();

  for (int t = kh; t <= qbA; t += 2) {
    const int cur = (t >> 1) & 1;
    if (t <= myqb) {
      f16v s0 = {}, s1 = {};
      __builtin_amdgcn_s_setprio(1);
#pragma unroll
      for (int cc = 0; cc < 4; ++cc) {
        const s8v kf0 = *(const s8v*)(Ks[cur] + l31 * 72 + cc * 16 + h8 * 8);
        const s8v kf1 = *(const s8v*)(Ks[cur] + (32 + l31) * 72 + cc * 16 + h8 * 8);
        s0 = MFMA32(kf0, qf[cc], s0);
        s1 = MFMA32(kf1, qf[cc], s1);
      }
      __builtin_amdgcn_s_setprio(0);
      if (t == myqb) {
#pragma unroll
        for (int rr = 0; rr < 16; ++rr) {
          const int koff = (rr & 3) + 8 * (rr >> 2) + 4 * h8;
          if (koff > qrel) s0[rr] = -1e30f;
          if (koff + 32 > qrel) s1[rr] = -1e30f;
        }
      }
#pragma unroll
      for (int rr = 0; rr < 16; ++rr) {
        s0[rr] = exp2f(s0[rr]);
        s1[rr] = exp2f(s1[rr]);
      }
      float sm[8];
#pragma unroll
      for (int i = 0; i < 8; ++i) sm[i] = (s0[i] + s0[i + 8]) + (s1[i] + s1[i + 8]);
#pragma unroll
      for (int i = 0; i < 4; ++i) sm[i] += sm[i + 4];
      lp += (sm[0] + sm[1]) + (sm[2] + sm[3]);

      unsigned pk0[8], pk1[8];
#pragma unroll
      for (int g = 0; g < 4; ++g)
#pragma unroll
        for (int j = 0; j < 2; ++j) {
          pk0[g * 2 + j] = pk2(s0[g * 4 + 2 * j], s0[g * 4 + 2 * j + 1]);
          pk1[g * 2 + j] = pk2(s1[g * 4 + 2 * j], s1[g * 4 + 2 * j + 1]);
        }
      __builtin_amdgcn_s_setprio(1);
#pragma unroll
      for (int cc = 0; cc < 4; ++cc) {
        const int g0 = (cc & 1) * 2, g1 = g0 + 1;
        const unsigned pA0 = (cc & 2) ? pk1[g0 * 2 + 0] : pk0[g0 * 2 + 0];
        const unsigned pA1 = (cc & 2) ? pk1[g0 * 2 + 1] : pk0[g0 * 2 + 1];
        const unsigned pB0 = (cc & 2) ? pk1[g1 * 2 + 0] : pk0[g1 * 2 + 0];
        const unsigned pB1 = (cc & 2) ? pk1[g1 * 2 + 1] : pk0[g1 * 2 + 1];
        const unsigned t00 = __shfl_xor((int)pA0, 32);
        const unsigned t01 = __shfl_xor((int)pA1, 32);
        const unsigned t10 = __shfl_xor((int)pB0, 32);
        const unsigned t11 = __shfl_xor((int)pB1, 32);
        union { u4v u; s8v s; } pf;
        pf.u[0] = h8 ? t10 : pA0;
        pf.u[1] = h8 ? t11 : pA1;
        pf.u[2] = h8 ? pB0 : t00;
        pf.u[3] = h8 ? pB1 : t01;
        const s8v vf0 = *(const s8v*)(Vt[cur] + l31 * 72 + cc * 16 + h8 * 8);
        const s8v vf1 = *(const s8v*)(Vt[cur] + (32 + l31) * 72 + cc * 16 + h8 * 8);
        o0 = MFMA32(vf0, pf.s, o0);
        o1 = MFMA32(vf1, pf.s, o1);
      }
      __builtin_amdgcn_s_setprio(0);
    }
    if (t + 2 <= qbA) {
      WRITET(cur ^ 1);
      if (t + 4 <= qbA) LOADT(t + 4);
      __syncthreads();
    }
  }

  lp += __shfl_xor(lp, 32);

  const size_t obase = ((size_t)kh * 12 + h) * 16 * 4096;
#pragma unroll
  for (int g = 0; g < 4; ++g) {
    const uint2 v0 = make_uint2(pk2(o0[g * 4], o0[g * 4 + 1]), pk2(o0[g * 4 + 2], o0[g * 4 + 3]));
    const uint2 v1 = make_uint2(pk2(o1[g * 4], o1[g * 4 + 1]), pk2(o1[g * 4 + 2], o1[g * 4 + 3]));
    Opart[obase + (size_t)(2 * g + h8) * 4096 + q_abs] = v0;
    Opart[obase + (size_t)(8 + 2 * g + h8) * 4096 + q_abs] = v1;
  }
  if (h8 == 0)
    ml[((size_t)kh * 12 + h) * 4096 + q_abs] = lp;
#undef LOADT
#undef WRITET
}

// ---------------- combine 2 key-parity partials -> attn bf16 [q][768]; zero ssq ----------------
__global__ __launch_bounds__(256) void combine_k(const uint2* __restrict__ Opart,
    const float* __restrict__ ml, unsigned short* __restrict__ out, float* __restrict__ ssq) {
  const int u = blockIdx.x * 256 + threadIdx.x;
  if (u < 4096) ssq[u] = 0.f;      // zero accumulator for wo's atomic row-sums
  const int q = u & 4095;
  const int rest = u >> 12;
  const int dgrp = rest & 15;
  const int h = rest >> 4;
  const float l0 = ml[h * 4096 + q];
  const float l1 = ml[12 * 4096 + h * 4096 + q];
  const float inv = 1.0f / (l0 + l1);
  const size_t idx = ((size_t)h * 16 + dgrp) * 4096 + q;
  const uint2 a = Opart[idx];
  const uint2 b = Opart[(size_t)12 * 16 * 4096 + idx];
  const int dbase = (dgrp < 8) ? 4 * dgrp : 32 + 4 * (dgrp - 8);
  ushort4 r;
  r.x = f2b((b2f(a.x) + b2f(b.x)) * inv);
  r.y = f2b((b2f(a.x >> 16) + b2f(b.x >> 16)) * inv);
  r.z = f2b((b2f(a.y) + b2f(b.y)) * inv);
  r.w = f2b((b2f(a.y >> 16) + b2f(b.y >> 16)) * inv);
  *(ushort4*)(out + (size_t)q * 768 + h * 64 + dbase) = r;
}

extern "C" void kernel_launch(void* const* d_in, const int* in_sizes, int n_in,
                              void* d_out, int out_size, void* d_ws, size_t ws_size,
                              hipStream_t stream) {
  const float* x    = (const float*)d_in[0];
  const float* w_q  = (const float*)d_in[1];
  const float* w_k  = (const float*)d_in[2];
  const float* w_v  = (const float*)d_in[3];
  const float* w_o  = (const float*)d_in[4];
  const float* w_g  = (const float*)d_in[5];
  const float* w_u  = (const float*)d_in[6];
  const float* w_d  = (const float*)d_in[7];
  const float* w_n1 = (const float*)d_in[8];
  const float* w_n2 = (const float*)d_in[9];
  (void)in_sizes; (void)n_in; (void)out_size; (void)ws_size;

  char* ws = (char*)d_ws;
  size_t off = 0;
  auto alloc = [&](size_t bytes) { char* p = ws + off; off += (bytes + 255) & ~(size_t)255; return p; };
  unsigned short* wqkvT = (unsigned short*)alloc(2304ull * 768 * 2);
  unsigned short* woT   = (unsigned short*)alloc(768ull * 768 * 2);
  unsigned short* wguT  = (unsigned short*)alloc(4096ull * 768 * 2);
  unsigned short* wdT   = (unsigned short*)alloc(768ull * 2048 * 2);
  float* ct             = (float*)alloc(4096ull * 32 * 4);
  float* st             = (float*)alloc(4096ull * 32 * 4);
  unsigned short* xn    = (unsigned short*)alloc(4096ull * 768 * 2);
  unsigned short* qkv   = (unsigned short*)alloc(4096ull * 2304 * 2);
  unsigned short* attn  = (unsigned short*)alloc(4096ull * 768 * 2);
  unsigned short* hb16  = (unsigned short*)alloc(4096ull * 768 * 2);
  float* ssq            = (float*)alloc(4096ull * 4);
  unsigned short* ffn   = (unsigned short*)alloc(4096ull * 2048 * 2);
  uint2* Opart          = (uint2*)alloc(2ull * 12 * 16 * 4096 * 8);
  float* mlb            = (float*)alloc(2ull * 12 * 4096 * 4);

  PrepArgs pa;
  pa.seg[0] = { w_q, wqkvT,                 768,  768, 24,  576, 0 };
  pa.seg[1] = { w_k, wqkvT + 768 * 768,     768,  768, 24,  576, 0 };
  pa.seg[2] = { w_v, wqkvT + 2 * 768 * 768, 768,  768, 24,  576, 0 };
  pa.seg[3] = { w_o, woT,                   768,  768, 24,  576, 0 };
  pa.seg[4] = { w_g, wguT,                  768, 2048, 64, 1536, 1 };
  pa.seg[5] = { w_u, wguT,                  768, 2048, 64, 1536, 2 };
  pa.seg[6] = { w_d, wdT,                  2048,  768, 24, 1536, 0 };
  pa.seg[7] = { nullptr, nullptr, 0, 0, 0, 512, 3 };
  pa.seg[8] = { x, xn, 0, 0, 0, 4096, 4 };
  pa.ct = ct; pa.st = st; pa.wn1 = w_n1; pa.wn2 = w_n2;
  const int prep_blocks = 576 * 4 + 1536 * 3 + 512 + 4096;   // 11520

  prep_k<<<prep_blocks, 256, 0, stream>>>(pa);
  // qkv = xn @ [Wq|Wk|Wv] + RoPE + Q pre-scale; 576 blocks = 32(M/128) x 18(N/128)
  gemm_bt<2, 128, 128><<<576, 256, 0, stream>>>(xn, wqkvT, qkv, nullptr, nullptr, nullptr, 768, 2304, ct, st, 18);
  flash_k<<<dim3(2, 32, 12), 256, 0, stream>>>(qkv, Opart, mlb);
  combine_k<<<3072, 256, 0, stream>>>(Opart, mlb, attn, ssq);
  // h = attn @ Wo + x (bf16) + atomic row-sums of h^2; BK=64, 768 blocks, 3/CU
  gemm_k64<4><<<768, 256, 0, stream>>>(attn, woT, hb16, nullptr, x, nullptr, ssq, 768, 768, 12);
  // ffn = silu(rn*(h@Wg'))*(rn*(h@Wu')), rn inline from ssq; 512 blocks = 16 x 32
  gemm_big<3><<<512, 512, 0, stream>>>(hb16, wguT, ffn, ssq, 768, 2048, 32);
  // out = ffn @ Wd + h(bf16); BK=64, 768 blocks, 3/CU
  gemm_k64<5><<<768, 256, 0, stream>>>(ffn, wdT, nullptr, (float*)d_out, nullptr, hb16, nullptr, 2048, 768, 12);
}

// Round 21
// 187.187 us; speedup vs baseline: 1.1350x; 1.0550x over previous
//
#include <hip/hip_runtime.h>
#include <hip/hip_bf16.h>

typedef __attribute__((ext_vector_type(8))) short s8v;
typedef __attribute__((ext_vector_type(4))) float f4v;
typedef __attribute__((ext_vector_type(16))) float f16v;
typedef __attribute__((ext_vector_type(4))) unsigned u4v;

typedef __attribute__((address_space(1))) const void as1_void;
typedef __attribute__((address_space(3))) void as3_void;

__device__ __forceinline__ void gl16(const void* g, void* l) {
  __builtin_amdgcn_global_load_lds((as1_void*)g, (as3_void*)l, 16, 0, 0);
}

__device__ __forceinline__ float b2f(int u) {
  union { float f; unsigned i; } c; c.i = ((unsigned)(u & 0xFFFF)) << 16; return c.f;
}
__device__ __forceinline__ unsigned short f2b(float f) {   // RNE
  union { float f; unsigned i; } c; c.f = f;
  unsigned r = c.i + 0x7FFFu + ((c.i >> 16) & 1u);
  return (unsigned short)(r >> 16);
}
__device__ __forceinline__ unsigned pk2(float lo, float hi) {  // 2xbf16 pack
  unsigned u;
  asm("v_cvt_pk_bf16_f32 %0, %1, %2" : "=v"(u) : "v"(lo), "v"(hi));
  return u;
}

#define MFMA16(a, b, c) __builtin_amdgcn_mfma_f32_16x16x32_bf16((a), (b), (c), 0, 0, 0)
#define MFMA32(a, b, c) __builtin_amdgcn_mfma_f32_32x32x16_bf16((a), (b), (c), 0, 0, 0)

// XCD-aware bijective block remap (grid % 8 == 0): contiguous logical blocks per XCD.
__device__ __forceinline__ void xcd_remap(int nbn, int& bm, int& bn) {
  const int flat = blockIdx.x;
  const int u = (flat & 7) * ((int)gridDim.x >> 3) + (flat >> 3);
  bm = u / nbn;
  bn = u - bm * nbn;
}

// -------- fused prep: weight converts (+gu interleave +w_norm2 fold) + rope + rmsnorm1 --------
struct Seg { const float* src; unsigned short* dst; int K; int N; int nbn; int nblocks; int mode; };
struct PrepArgs { Seg seg[9]; float* ct; float* st; const float* wn1; const float* wn2; };

__global__ __launch_bounds__(256) void prep_k(PrepArgs a) {
  int b = blockIdx.x, si = 0;
  while (si < 8 && b >= a.seg[si].nblocks) { b -= a.seg[si].nblocks; ++si; }
  const Seg s = a.seg[si];
  const int tid = threadIdx.x;
  if (s.mode == 3) {               // rope tables [4096][32]
    const int t = b * 256 + tid;
    const int sq = t >> 5, d = t & 31;
    const float inv = powf(10000.0f, -(float)d * (1.0f / 32.0f));
    const float ang = (float)sq * inv;
    a.ct[t] = cosf(ang);
    a.st[t] = sinf(ang);
    return;
  }
  if (s.mode == 4) {               // rmsnorm1: x row b -> bf16
    const float* xr = s.src + (size_t)b * 768;
    float v0 = xr[tid], v1 = xr[tid + 256], v2 = xr[tid + 512];
    float ss = v0 * v0 + v1 * v1 + v2 * v2;
#pragma unroll
    for (int m = 1; m < 64; m <<= 1) ss += __shfl_xor(ss, m, 64);
    __shared__ float sred[4];
    if ((tid & 63) == 0) sred[tid >> 6] = ss;
    __syncthreads();
    const float tot = sred[0] + sred[1] + sred[2] + sred[3];
    const float rn = rsqrtf(tot * (1.0f / 768.0f) + 1e-6f);
    unsigned short* orow = s.dst + (size_t)b * 768;
    orow[tid]       = f2b(v0 * rn * a.wn1[tid]);
    orow[tid + 256] = f2b(v1 * rn * a.wn1[tid + 256]);
    orow[tid + 512] = f2b(v2 * rn * a.wn1[tid + 512]);
    return;
  }
  __shared__ float tile[32][33];
  const int tx = tid & 31, ty = tid >> 5;
  const int bn = b % s.nbn, bk = b / s.nbn;
#pragma unroll
  for (int i = 0; i < 32; i += 8)
    tile[ty + i][tx] = s.src[(size_t)(bk * 32 + ty + i) * s.N + bn * 32 + tx];
  __syncthreads();
  const float kscale = (s.mode == 1 || s.mode == 2) ? a.wn2[bk * 32 + tx] : 1.0f;
#pragma unroll
  for (int i = 0; i < 32; i += 8) {
    int row;
    if (s.mode == 0)      row = bn * 32 + ty + i;
    else                  row = bn * 64 + (s.mode == 2 ? 32 : 0) + ty + i;
    s.dst[(size_t)row * s.K + bk * 32 + tx] = f2b(tile[tx][ty + i] * kscale);
  }
}

// ---------------- GEMM template: BM x BN tile, 256 thr, 3-buffer counted-vmcnt, BK=32 ----
// LDS bank-conflict swizzle: slot (row,chunk) holds global (row, chunk^(row&3)); reads XOR l15&3.
// EPI 2: bf16 store + RoPE (cols<1536) + Q pre-scale (cols<768); BM=BN=128
template <int EPI, int BM, int BN>
__global__ __launch_bounds__(256) void gemm_bt(const unsigned short* __restrict__ A,
    const unsigned short* __restrict__ Bt, unsigned short* __restrict__ Cb,
    float* __restrict__ Cf, const float* __restrict__ Rf, const unsigned short* __restrict__ Rb,
    int K, int ldc, const float* __restrict__ ct, const float* __restrict__ st, int nbn) {
  constexpr int ABYTES = BM * 32 * 2;
  constexpr int BBYTES = BN * 32 * 2;
  constexpr int APASS = BM / 64, BPASS = BN / 64;
  constexpr int LPS = APASS + BPASS;
  constexpr bool W2x2 = (BN == 128);
  constexpr int MR = W2x2 ? (BM / 32) : (BM / 64);
  __shared__ unsigned short As[3 * BM * 32];
  __shared__ unsigned short Bs[3 * BN * 32];
  const int tid = threadIdx.x;
  const int lane = tid & 63, wid = tid >> 6;
  const int wrow = W2x2 ? (wid >> 1) * (BM / 2) : wid * (BM / 4);
  const int wcol = W2x2 ? (wid & 1) * 64 : 0;
  const int l15 = lane & 15, l4 = lane >> 4;
  int bm, bn;
  xcd_remap(nbn, bm, bn);

  f4v acc[MR][4] = {};

  // staging: dest row = wid*16 + (lane>>2), chunk = lane&3; source chunk ^= row&3
  const int r0 = tid >> 2;
  const int c0 = ((tid & 3) ^ ((tid >> 2) & 3)) * 16;
  const size_t ldab = (size_t)K * 2;
  const char* Abyte = (const char*)A;
  const char* Bbyte = (const char*)Bt;
  const size_t a0 = (size_t)(bm * BM + r0) * ldab + c0;
  const size_t a1 = (size_t)(bm * BM + (APASS == 2 ? r0 + 64 : r0)) * ldab + c0;
  const size_t b0 = (size_t)(bn * BN + r0) * ldab + c0;
  const size_t b1 = (size_t)(bn * BN + (BPASS == 2 ? r0 + 64 : r0)) * ldab + c0;
  char* AsB = (char*)As;
  char* BsB = (char*)Bs;
  const int uoff = wid << 10;
  const int rsw = (l4 ^ (l15 & 3)) * 16;   // swizzled read chunk byte

#define STAGEK(I, SL) do { const size_t kb = (size_t)(I) * 64;                 \
    char* Aw = AsB + (SL) * ABYTES;                                            \
    char* Bw = BsB + (SL) * BBYTES;                                            \
    gl16(Abyte + a0 + kb, Aw + uoff);                                          \
    if constexpr (APASS == 2) gl16(Abyte + a1 + kb, Aw + uoff + 4096);         \
    gl16(Bbyte + b0 + kb, Bw + uoff);                                          \
    if constexpr (BPASS == 2) gl16(Bbyte + b1 + kb, Bw + uoff + 4096); } while (0)

  const int NI = K >> 5;
  STAGEK(0, 0);
  STAGEK(1, 1);
  int sel = 0, nsl = 2;

  for (int i = 0; i < NI; ++i) {
    if (i < NI - 1) {
      if constexpr (LPS == 4)      asm volatile("s_waitcnt vmcnt(4)" ::: "memory");
      else if constexpr (LPS == 3) asm volatile("s_waitcnt vmcnt(3)" ::: "memory");
      else                         asm volatile("s_waitcnt vmcnt(2)" ::: "memory");
    } else {
      asm volatile("s_waitcnt vmcnt(0)" ::: "memory");
    }
    __builtin_amdgcn_s_barrier();
    __builtin_amdgcn_sched_barrier(0);
    if (i + 2 < NI) STAGEK(i + 2, nsl);
    const char* Ar = AsB + sel * ABYTES;
    const char* Br = BsB + sel * BBYTES;
    s8v af[MR], bf[4];
#pragma unroll
    for (int m = 0; m < MR; ++m)
      af[m] = *(const s8v*)(Ar + (wrow + m * 16 + l15) * 64 + rsw);
#pragma unroll
    for (int n = 0; n < 4; ++n)
      bf[n] = *(const s8v*)(Br + (wcol + n * 16 + l15) * 64 + rsw);
    __builtin_amdgcn_s_setprio(1);
#pragma unroll
    for (int m = 0; m < MR; ++m)
#pragma unroll
      for (int n = 0; n < 4; ++n) acc[m][n] = MFMA16(af[m], bf[n], acc[m][n]);
    __builtin_amdgcn_s_setprio(0);
    sel = (sel == 2) ? 0 : sel + 1;
    nsl = (nsl == 2) ? 0 : nsl + 1;
  }
#undef STAGEK

  const int row0 = bm * BM + wrow;
  const int col0 = bn * BN + wcol;

  if constexpr (EPI == 2) {        // RoPE + Q pre-scale (BN=128: wave spans one head)
    const int colw = col0;
    if (colw < 1536) {             // q|k region: RoPE
#pragma unroll
      for (int m = 0; m < MR; ++m)
#pragma unroll
        for (int r = 0; r < 4; ++r) {
          const int row = row0 + m * 16 + l4 * 4 + r;
#pragma unroll
          for (int n = 0; n < 2; ++n) {
            const int d = n * 16 + l15;
            const float c  = ct[row * 32 + d];
            const float sn = st[row * 32 + d];
            const float aa = acc[m][n][r], bb = acc[m][n + 2][r];
            acc[m][n][r]     = aa * c - bb * sn;
            acc[m][n + 2][r] = bb * c + aa * sn;
          }
        }
    }
    if (colw < 768) {              // q region: pre-scale by 0.125*log2e
      const float QSC = 0.18033688011112042f;
#pragma unroll
      for (int m = 0; m < MR; ++m)
#pragma unroll
        for (int n = 0; n < 4; ++n)
#pragma unroll
          for (int r = 0; r < 4; ++r) acc[m][n][r] *= QSC;
    }
  }

#pragma unroll
  for (int m = 0; m < MR; ++m)
#pragma unroll
    for (int n = 0; n < 4; ++n)
#pragma unroll
      for (int r = 0; r < 4; ++r) {
        const int row = row0 + m * 16 + l4 * 4 + r;
        const int col = col0 + n * 16 + l15;
        Cb[(size_t)row * ldc + col] = f2b(acc[m][n][r]);
      }
}

// ---------------- 64x64 GEMM, BK=64 (128B rows): swizzle chunk^(row&7) -> conflict-free ----
// EPI 4: bf16 store of h=(v+Rf[fp32]) + atomic row-sum of h^2 into ssq (wo)
// EPI 5: fp32 store of (v + b2f(Rb[bf16]))  (down + residual -> d_out)
template <int EPI>
__global__ __launch_bounds__(256) void gemm_k64(const unsigned short* __restrict__ A,
    const unsigned short* __restrict__ Bt, unsigned short* __restrict__ Cb,
    float* __restrict__ Cf, const float* __restrict__ Rf, const unsigned short* __restrict__ Rb,
    float* __restrict__ ssq, int K, int ldc, int nbn) {
  constexpr int TBYTES = 64 * 64 * 2;   // 8 KB per operand per stage
  __shared__ unsigned short As[3 * 64 * 64];
  __shared__ unsigned short Bs[3 * 64 * 64];
  const int tid = threadIdx.x;
  const int lane = tid & 63, wid = tid >> 6;
  const int wrow = wid * 16;
  const int l15 = lane & 15, l4 = lane >> 4;
  int bm, bn;
  xcd_remap(nbn, bm, bn);

  f4v acc[4] = {};

  // staging: dest row = wid*8 + (lane>>3), chunk = lane&7; source chunk ^= row&7
  const int r0 = tid >> 3;
  const int c0 = ((tid & 7) ^ ((tid >> 3) & 7)) * 16;
  const size_t ldab = (size_t)K * 2;
  const char* Abyte = (const char*)A;
  const char* Bbyte = (const char*)Bt;
  const size_t a0 = (size_t)(bm * 64 + r0) * ldab + c0;
  const size_t a1 = (size_t)(bm * 64 + 32 + r0) * ldab + c0;
  const size_t b0 = (size_t)(bn * 64 + r0) * ldab + c0;
  const size_t b1 = (size_t)(bn * 64 + 32 + r0) * ldab + c0;
  char* AsB = (char*)As;
  char* BsB = (char*)Bs;
  const int uoff = wid << 10;
  const int s7 = l15 & 7;                  // row&7 for fragment reads

#define STAGEK(I, SL) do { const size_t kb = (size_t)(I) * 128;                \
    char* Aw = AsB + (SL) * TBYTES;                                            \
    char* Bw = BsB + (SL) * TBYTES;                                            \
    gl16(Abyte + a0 + kb, Aw + uoff);                                          \
    gl16(Abyte + a1 + kb, Aw + uoff + 4096);                                   \
    gl16(Bbyte + b0 + kb, Bw + uoff);                                          \
    gl16(Bbyte + b1 + kb, Bw + uoff + 4096); } while (0)

  const int NI = K >> 6;
  STAGEK(0, 0);
  STAGEK(1, 1);
  int sel = 0, nsl = 2;

  for (int i = 0; i < NI; ++i) {
    if (i < NI - 1) asm volatile("s_waitcnt vmcnt(4)" ::: "memory");
    else            asm volatile("s_waitcnt vmcnt(0)" ::: "memory");
    __builtin_amdgcn_s_barrier();
    __builtin_amdgcn_sched_barrier(0);
    if (i + 2 < NI) STAGEK(i + 2, nsl);
    const char* Ar = AsB + sel * TBYTES;
    const char* Br = BsB + sel * TBYTES;
#pragma unroll
    for (int kk = 0; kk < 2; ++kk) {
      const int ch = ((kk * 4 + l4) ^ s7) * 16;      // swizzled chunk byte
      const s8v af = *(const s8v*)(Ar + (wrow + l15) * 128 + ch);
      s8v bf[4];
#pragma unroll
      for (int n = 0; n < 4; ++n)
        bf[n] = *(const s8v*)(Br + (n * 16 + l15) * 128 + ch);
      __builtin_amdgcn_s_setprio(1);
#pragma unroll
      for (int n = 0; n < 4; ++n) acc[n] = MFMA16(af, bf[n], acc[n]);
      __builtin_amdgcn_s_setprio(0);
    }
    sel = (sel == 2) ? 0 : sel + 1;
    nsl = (nsl == 2) ? 0 : nsl + 1;
  }
#undef STAGEK

  const int row0 = bm * 64 + wrow;
  const int col0 = bn * 64;
#pragma unroll
  for (int r = 0; r < 4; ++r) {
    const int row = row0 + l4 * 4 + r;
    float ps = 0.f;
#pragma unroll
    for (int n = 0; n < 4; ++n) {
      const int col = col0 + n * 16 + l15;
      const float v = acc[n][r];
      const size_t idx = (size_t)row * ldc + col;
      if (EPI == 4) {
        const float hv = v + Rf[idx];
        Cb[idx] = f2b(hv);
        ps += hv * hv;
      } else {
        Cf[idx] = v + b2f(Rb[idx]);
      }
    }
    if (EPI == 4) {                 // reduce over the 16 l15 lanes -> one atomic per (row, block)
#pragma unroll
      for (int mm = 1; mm < 16; mm <<= 1) ps += __shfl_xor(ps, mm, 64);
      if (l15 == 0) atomicAdd(&ssq[row], ps);
    }
  }
}

// ---------------- big GEMM: 256(M)x128(N) tile, 512 thr, 8 waves (4Mx2N), BK=32 ----------------
// LDS swizzle chunk^(row&3). EPI 3: rn-scaled silu(g)*u; rn inline from ssq.
template <int EPI>
__global__ __launch_bounds__(512, 2) void gemm_big(const unsigned short* __restrict__ A,
    const unsigned short* __restrict__ Bt, unsigned short* __restrict__ Cb,
    const float* __restrict__ ssq, int K, int ldc, int nbn) {
  constexpr int ABYTES = 256 * 32 * 2;
  constexpr int BBYTES = 128 * 32 * 2;
  __shared__ unsigned short As[3 * 256 * 32];
  __shared__ unsigned short Bs[3 * 128 * 32];
  const int tid = threadIdx.x;
  const int lane = tid & 63, wid = tid >> 6;
  const int wm = wid >> 1, wn = wid & 1;
  const int wrow = wm * 64, wcol = wn * 64;
  const int l15 = lane & 15, l4 = lane >> 4;
  int bm, bn;
  xcd_remap(nbn, bm, bn);

  f4v acc[4][4] = {};

  const size_t ldab = (size_t)K * 2;
  const char* Ab = (const char*)A;
  const char* Bb = (const char*)Bt;
  const int lrow = lane >> 2;
  const int lch = ((lane & 3) ^ (lrow & 3)) * 16;   // source chunk ^= row&3
  const size_t aS0 = (size_t)(bm * 256 + wid * 16 + lrow) * ldab + lch;
  const size_t aS1 = (size_t)(bm * 256 + (wid + 8) * 16 + lrow) * ldab + lch;
  const size_t bS  = (size_t)(bn * 128 + wid * 16 + lrow) * ldab + lch;
  char* AsB = (char*)As;
  char* BsB = (char*)Bs;
  const int uA0 = wid << 10, uA1 = (wid + 8) << 10, uB = wid << 10;
  const int rsw = (l4 ^ (l15 & 3)) * 16;            // swizzled read chunk byte

#define STAGEK(I, SL) do { const size_t kb = (size_t)(I) * 64;                 \
    gl16(Ab + aS0 + kb, AsB + (SL) * ABYTES + uA0);                            \
    gl16(Ab + aS1 + kb, AsB + (SL) * ABYTES + uA1);                            \
    gl16(Bb + bS  + kb, BsB + (SL) * BBYTES + uB); } while (0)

  const int NI = K >> 5;
  STAGEK(0, 0);
  STAGEK(1, 1);
  int sel = 0, nsl = 2;

  for (int i = 0; i < NI; ++i) {
    if (i < NI - 1) asm volatile("s_waitcnt vmcnt(3)" ::: "memory");
    else            asm volatile("s_waitcnt vmcnt(0)" ::: "memory");
    __builtin_amdgcn_s_barrier();
    __builtin_amdgcn_sched_barrier(0);
    if (i + 2 < NI) STAGEK(i + 2, nsl);
    const char* Ar = AsB + sel * ABYTES;
    const char* Br = BsB + sel * BBYTES;
    s8v af[4], bf[4];
#pragma unroll
    for (int m = 0; m < 4; ++m)
      af[m] = *(const s8v*)(Ar + (wrow + m * 16 + l15) * 64 + rsw);
#pragma unroll
    for (int n = 0; n < 4; ++n)
      bf[n] = *(const s8v*)(Br + (wcol + n * 16 + l15) * 64 + rsw);
    __builtin_amdgcn_s_setprio(1);
#pragma unroll
    for (int m = 0; m < 4; ++m)
#pragma unroll
      for (int n = 0; n < 4; ++n) acc[m][n] = MFMA16(af[m], bf[n], acc[m][n]);
    __builtin_amdgcn_s_setprio(0);
    sel = (sel == 2) ? 0 : sel + 1;
    nsl = (nsl == 2) ? 0 : nsl + 1;
  }
#undef STAGEK

  const int row0 = bm * 256 + wrow;
  const int col0 = bn * 128 + wcol;

  if (EPI == 3) {                  // val = silu(rn*g) * (rn*u); rn from ssq
    const int colb = (bn * 2 + wn) * 32;
#pragma unroll
    for (int m = 0; m < 4; ++m)
#pragma unroll
      for (int r = 0; r < 4; ++r) {
        const int row = row0 + m * 16 + l4 * 4 + r;
        const float rn = rsqrtf(ssq[row] * (1.0f / 768.0f) + 1e-6f);
#pragma unroll
        for (int n = 0; n < 2; ++n) {
          const float g = acc[m][n][r] * rn, u = acc[m][n + 2][r] * rn;
          const float val = g * u / (1.0f + __expf(-g));
          Cb[(size_t)row * 2048 + colb + n * 16 + l15] = f2b(val);
        }
      }
    return;
  }

#pragma unroll
  for (int m = 0; m < 4; ++m)
#pragma unroll
    for (int n = 0; n < 4; ++n)
#pragma unroll
      for (int r = 0; r < 4; ++r) {
        const int row = row0 + m * 16 + l4 * 4 + r;
        const int col = col0 + n * 16 + l15;
        Cb[(size_t)row * ldc + col] = f2b(acc[m][n][r]);
      }
}

// ---------------- causal flash attention: 32x32 swapped-QK, 2-way parity, NO online max ----------------
__global__ __launch_bounds__(256, 4) void flash_k(const unsigned short* __restrict__ qkv,
    uint2* __restrict__ Opart, float* __restrict__ ml) {
  const int kh = blockIdx.x, p = blockIdx.y, h = blockIdx.z;
  const int qbA = 63 - p;
  const int tid = threadIdx.x;
  const int wv = tid >> 6, lane = tid & 63;
  const int l31 = lane & 31, h8 = lane >> 5;
  const int myqb = (wv & 1) ? p : qbA;
  const int qrel = (wv >> 1) * 32 + l31;
  const int q_abs = myqb * 64 + qrel;

  __shared__ unsigned short Ks[2][64 * 72];
  __shared__ unsigned short Vt[2][64 * 72];

  const unsigned short* qp = qkv + h * 64;
  const unsigned short* kp = qkv + 768 + h * 64;
  const unsigned short* vp = qkv + 1536 + h * 64;

  s8v qf[4];
#pragma unroll
  for (int cc = 0; cc < 4; ++cc)
    qf[cc] = *(const s8v*)(qp + (size_t)q_abs * 2304 + cc * 16 + h8 * 8);

  f16v o0 = {}, o1 = {};
  float lp = 0.f;

  const int krow = tid >> 3, kc = (tid & 7) * 8;
  const int vj = tid & 31, vd0 = (tid >> 5) * 8;

  s8v ka, kb, va, vb;
#define LOADT(T) do { const size_t k0n = (size_t)(T) * 64;                    \
    ka = *(const s8v*)(kp + (k0n + krow) * 2304 + kc);                        \
    kb = *(const s8v*)(kp + (k0n + krow + 32) * 2304 + kc);                   \
    va = *(const s8v*)(vp + (k0n + 2 * vj) * 2304 + vd0);                     \
    vb = *(const s8v*)(vp + (k0n + 2 * vj + 1) * 2304 + vd0); } while (0)
#define WRITET(BUF) do {                                                      \
    *(s8v*)(Ks[BUF] + krow * 72 + kc) = ka;                                   \
    *(s8v*)(Ks[BUF] + (krow + 32) * 72 + kc) = kb;                            \
    unsigned* vtw = (unsigned*)(Vt[BUF] + (size_t)vd0 * 72 + 2 * vj);         \
    _Pragma("unroll")                                                         \
    for (int i = 0; i < 8; ++i)                                               \
      vtw[i * 36] = ((unsigned)(unsigned short)va[i]) |                       \
                    (((unsigned)(unsigned short)vb[i]) << 16); } while (0)

  LOADT(kh);
  WRITET(0);
  if (kh + 2 <= qbA) LOADT(kh + 2);
  __syncthreads();

  for (int t = kh; t <= qbA; t += 2) {
    const int cur = (t >> 1) & 1;
    if (t <= myqb) {
      f16v s0 = {}, s1 = {};
      __builtin_amdgcn_s_setprio(1);
#pragma unroll
      for (int cc = 0; cc < 4; ++cc) {
        const s8v kf0 = *(const s8v*)(Ks[cur] + l31 * 72 + cc * 16 + h8 * 8);
        const s8v kf1 = *(const s8v*)(Ks[cur] + (32 + l31) * 72 + cc * 16 + h8 * 8);
        s0 = MFMA32(kf0, qf[cc], s0);
        s1 = MFMA32(kf1, qf[cc], s1);
      }
      __builtin_amdgcn_s_setprio(0);
      if (t == myqb) {
#pragma unroll
        for (int rr = 0; rr < 16; ++rr) {
          const int koff = (rr & 3) + 8 * (rr >> 2) + 4 * h8;
          if (koff > qrel) s0[rr] = -1e30f;
          if (koff + 32 > qrel) s1[rr] = -1e30f;
        }
      }
#pragma unroll
      for (int rr = 0; rr < 16; ++rr) {
        s0[rr] = exp2f(s0[rr]);
        s1[rr] = exp2f(s1[rr]);
      }
      float sm[8];
#pragma unroll
      for (int i = 0; i < 8; ++i) sm[i] = (s0[i] + s0[i + 8]) + (s1[i] + s1[i + 8]);
#pragma unroll
      for (int i = 0; i < 4; ++i) sm[i] += sm[i + 4];
      lp += (sm[0] + sm[1]) + (sm[2] + sm[3]);

      unsigned pk0[8], pk1[8];
#pragma unroll
      for (int g = 0; g < 4; ++g)
#pragma unroll
        for (int j = 0; j < 2; ++j) {
          pk0[g * 2 + j] = pk2(s0[g * 4 + 2 * j], s0[g * 4 + 2 * j + 1]);
          pk1[g * 2 + j] = pk2(s1[g * 4 + 2 * j], s1[g * 4 + 2 * j + 1]);
        }
      __builtin_amdgcn_s_setprio(1);
#pragma unroll
      for (int cc = 0; cc < 4; ++cc) {
        const int g0 = (cc & 1) * 2, g1 = g0 + 1;
        const unsigned pA0 = (cc & 2) ? pk1[g0 * 2 + 0] : pk0[g0 * 2 + 0];
        const unsigned pA1 = (cc & 2) ? pk1[g0 * 2 + 1] : pk0[g0 * 2 + 1];
        const unsigned pB0 = (cc & 2) ? pk1[g1 * 2 + 0] : pk0[g1 * 2 + 0];
        const unsigned pB1 = (cc & 2) ? pk1[g1 * 2 + 1] : pk0[g1 * 2 + 1];
        const unsigned t00 = __shfl_xor((int)pA0, 32);
        const unsigned t01 = __shfl_xor((int)pA1, 32);
        const unsigned t10 = __shfl_xor((int)pB0, 32);
        const unsigned t11 = __shfl_xor((int)pB1, 32);
        union { u4v u; s8v s; } pf;
        pf.u[0] = h8 ? t10 : pA0;
        pf.u[1] = h8 ? t11 : pA1;
        pf.u[2] = h8 ? pB0 : t00;
        pf.u[3] = h8 ? pB1 : t01;
        const s8v vf0 = *(const s8v*)(Vt[cur] + l31 * 72 + cc * 16 + h8 * 8);
        const s8v vf1 = *(const s8v*)(Vt[cur] + (32 + l31) * 72 + cc * 16 + h8 * 8);
        o0 = MFMA32(vf0, pf.s, o0);
        o1 = MFMA32(vf1, pf.s, o1);
      }
      __builtin_amdgcn_s_setprio(0);
    }
    if (t + 2 <= qbA) {
      WRITET(cur ^ 1);
      if (t + 4 <= qbA) LOADT(t + 4);
      __syncthreads();
    }
  }

  lp += __shfl_xor(lp, 32);

  const size_t obase = ((size_t)kh * 12 + h) * 16 * 4096;
#pragma unroll
  for (int g = 0; g < 4; ++g) {
    const uint2 v0 = make_uint2(pk2(o0[g * 4], o0[g * 4 + 1]), pk2(o0[g * 4 + 2], o0[g * 4 + 3]));
    const uint2 v1 = make_uint2(pk2(o1[g * 4], o1[g * 4 + 1]), pk2(o1[g * 4 + 2], o1[g * 4 + 3]));
    Opart[obase + (size_t)(2 * g + h8) * 4096 + q_abs] = v0;
    Opart[obase + (size_t)(8 + 2 * g + h8) * 4096 + q_abs] = v1;
  }
  if (h8 == 0)
    ml[((size_t)kh * 12 + h) * 4096 + q_abs] = lp;
#undef LOADT
#undef WRITET
}

// ---------------- combine 2 key-parity partials -> attn bf16 [q][768]; zero ssq ----------------
__global__ __launch_bounds__(256) void combine_k(const uint2* __restrict__ Opart,
    const float* __restrict__ ml, unsigned short* __restrict__ out, float* __restrict__ ssq) {
  const int u = blockIdx.x * 256 + threadIdx.x;
  if (u < 4096) ssq[u] = 0.f;      // zero accumulator for wo's atomic row-sums
  const int q = u & 4095;
  const int rest = u >> 12;
  const int dgrp = rest & 15;
  const int h = rest >> 4;
  const float l0 = ml[h * 4096 + q];
  const float l1 = ml[12 * 4096 + h * 4096 + q];
  const float inv = 1.0f / (l0 + l1);
  const size_t idx = ((size_t)h * 16 + dgrp) * 4096 + q;
  const uint2 a = Opart[idx];
  const uint2 b = Opart[(size_t)12 * 16 * 4096 + idx];
  const int dbase = (dgrp < 8) ? 4 * dgrp : 32 + 4 * (dgrp - 8);
  ushort4 r;
  r.x = f2b((b2f(a.x) + b2f(b.x)) * inv);
  r.y = f2b((b2f(a.x >> 16) + b2f(b.x >> 16)) * inv);
  r.z = f2b((b2f(a.y) + b2f(b.y)) * inv);
  r.w = f2b((b2f(a.y >> 16) + b2f(b.y >> 16)) * inv);
  *(ushort4*)(out + (size_t)q * 768 + h * 64 + dbase) = r;
}

extern "C" void kernel_launch(void* const* d_in, const int* in_sizes, int n_in,
                              void* d_out, int out_size, void* d_ws, size_t ws_size,
                              hipStream_t stream) {
  const float* x    = (const float*)d_in[0];
  const float* w_q  = (const float*)d_in[1];
  const float* w_k  = (const float*)d_in[2];
  const float* w_v  = (const float*)d_in[3];
  const float* w_o  = (const float*)d_in[4];
  const float* w_g  = (const float*)d_in[5];
  const float* w_u  = (const float*)d_in[6];
  const float* w_d  = (const float*)d_in[7];
  const float* w_n1 = (const float*)d_in[8];
  const float* w_n2 = (const float*)d_in[9];
  (void)in_sizes; (void)n_in; (void)out_size; (void)ws_size;

  char* ws = (char*)d_ws;
  size_t off = 0;
  auto alloc = [&](size_t bytes) { char* p = ws + off; off += (bytes + 255) & ~(size_t)255; return p; };
  unsigned short* wqkvT = (unsigned short*)alloc(2304ull * 768 * 2);
  unsigned short* woT   = (unsigned short*)alloc(768ull * 768 * 2);
  unsigned short* wguT  = (unsigned short*)alloc(4096ull * 768 * 2);
  unsigned short* wdT   = (unsigned short*)alloc(768ull * 2048 * 2);
  float* ct             = (float*)alloc(4096ull * 32 * 4);
  float* st             = (float*)alloc(4096ull * 32 * 4);
  unsigned short* xn    = (unsigned short*)alloc(4096ull * 768 * 2);
  unsigned short* qkv   = (unsigned short*)alloc(4096ull * 2304 * 2);
  unsigned short* attn  = (unsigned short*)alloc(4096ull * 768 * 2);
  unsigned short* hb16  = (unsigned short*)alloc(4096ull * 768 * 2);
  float* ssq            = (float*)alloc(4096ull * 4);
  unsigned short* ffn   = (unsigned short*)alloc(4096ull * 2048 * 2);
  uint2* Opart          = (uint2*)alloc(2ull * 12 * 16 * 4096 * 8);
  float* mlb            = (float*)alloc(2ull * 12 * 4096 * 4);

  PrepArgs pa;
  pa.seg[0] = { w_q, wqkvT,                 768,  768, 24,  576, 0 };
  pa.seg[1] = { w_k, wqkvT + 768 * 768,     768,  768, 24,  576, 0 };
  pa.seg[2] = { w_v, wqkvT + 2 * 768 * 768, 768,  768, 24,  576, 0 };
  pa.seg[3] = { w_o, woT,                   768,  768, 24,  576, 0 };
  pa.seg[4] = { w_g, wguT,                  768, 2048, 64, 1536, 1 };
  pa.seg[5] = { w_u, wguT,                  768, 2048, 64, 1536, 2 };
  pa.seg[6] = { w_d, wdT,                  2048,  768, 24, 1536, 0 };
  pa.seg[7] = { nullptr, nullptr, 0, 0, 0, 512, 3 };
  pa.seg[8] = { x, xn, 0, 0, 0, 4096, 4 };
  pa.ct = ct; pa.st = st; pa.wn1 = w_n1; pa.wn2 = w_n2;
  const int prep_blocks = 576 * 4 + 1536 * 3 + 512 + 4096;   // 11520

  prep_k<<<prep_blocks, 256, 0, stream>>>(pa);
  // qkv = xn @ [Wq|Wk|Wv] + RoPE + Q pre-scale; 576 blocks = 32(M/128) x 18(N/128)
  gemm_bt<2, 128, 128><<<576, 256, 0, stream>>>(xn, wqkvT, qkv, nullptr, nullptr, nullptr, 768, 2304, ct, st, 18);
  flash_k<<<dim3(2, 32, 12), 256, 0, stream>>>(qkv, Opart, mlb);
  combine_k<<<3072, 256, 0, stream>>>(Opart, mlb, attn, ssq);
  // h = attn @ Wo + x (bf16) + atomic row-sums of h^2; BK=64, 768 blocks, 3/CU
  gemm_k64<4><<<768, 256, 0, stream>>>(attn, woT, hb16, nullptr, x, nullptr, ssq, 768, 768, 12);
  // ffn = silu(rn*(h@Wg'))*(rn*(h@Wu')), rn inline from ssq; 512 blocks = 16 x 32
  gemm_big<3><<<512, 512, 0, stream>>>(hb16, wguT, ffn, ssq, 768, 2048, 32);
  // out = ffn @ Wd + h(bf16); BK=64, 768 blocks, 3/CU
  gemm_k64<5><<<768, 256, 0, stream>>>(ffn, wdT, nullptr, (float*)d_out, nullptr, hb16, nullptr, 2048, 768, 12);
}

// Round 22
// 187.185 us; speedup vs baseline: 1.1350x; 1.0000x over previous
//
#include <hip/hip_runtime.h>
#include <hip/hip_bf16.h>

typedef __attribute__((ext_vector_type(8))) short s8v;
typedef __attribute__((ext_vector_type(4))) float f4v;
typedef __attribute__((ext_vector_type(16))) float f16v;
typedef __attribute__((ext_vector_type(4))) unsigned u4v;

typedef __attribute__((address_space(1))) const void as1_void;
typedef __attribute__((address_space(3))) void as3_void;

__device__ __forceinline__ void gl16(const void* g, void* l) {
  __builtin_amdgcn_global_load_lds((as1_void*)g, (as3_void*)l, 16, 0, 0);
}

__device__ __forceinline__ float b2f(int u) {
  union { float f; unsigned i; } c; c.i = ((unsigned)(u & 0xFFFF)) << 16; return c.f;
}
__device__ __forceinline__ unsigned short f2b(float f) {   // RNE
  union { float f; unsigned i; } c; c.f = f;
  unsigned r = c.i + 0x7FFFu + ((c.i >> 16) & 1u);
  return (unsigned short)(r >> 16);
}
__device__ __forceinline__ unsigned pk2(float lo, float hi) {  // 2xbf16 pack
  unsigned u;
  asm("v_cvt_pk_bf16_f32 %0, %1, %2" : "=v"(u) : "v"(lo), "v"(hi));
  return u;
}

#define MFMA16(a, b, c) __builtin_amdgcn_mfma_f32_16x16x32_bf16((a), (b), (c), 0, 0, 0)
#define MFMA32(a, b, c) __builtin_amdgcn_mfma_f32_32x32x16_bf16((a), (b), (c), 0, 0, 0)

// XCD-aware bijective block remap (grid % 8 == 0): contiguous logical blocks per XCD.
__device__ __forceinline__ void xcd_remap(int nbn, int& bm, int& bn) {
  const int flat = blockIdx.x;
  const int u = (flat & 7) * ((int)gridDim.x >> 3) + (flat >> 3);
  bm = u / nbn;
  bn = u - bm * nbn;
}

// -------- fused prep: weight converts (+gu interleave +w_norm2 fold) + rope + rmsnorm1 --------
struct Seg { const float* src; unsigned short* dst; int K; int N; int nbn; int nblocks; int mode; };
struct PrepArgs { Seg seg[9]; float* ct; float* st; const float* wn1; const float* wn2; };

__global__ __launch_bounds__(256) void prep_k(PrepArgs a) {
  int b = blockIdx.x, si = 0;
  while (si < 8 && b >= a.seg[si].nblocks) { b -= a.seg[si].nblocks; ++si; }
  const Seg s = a.seg[si];
  const int tid = threadIdx.x;
  if (s.mode == 3) {               // rope tables [4096][32]
    const int t = b * 256 + tid;
    const int sq = t >> 5, d = t & 31;
    const float inv = powf(10000.0f, -(float)d * (1.0f / 32.0f));
    const float ang = (float)sq * inv;
    a.ct[t] = cosf(ang);
    a.st[t] = sinf(ang);
    return;
  }
  if (s.mode == 4) {               // rmsnorm1: x row b -> bf16
    const float* xr = s.src + (size_t)b * 768;
    float v0 = xr[tid], v1 = xr[tid + 256], v2 = xr[tid + 512];
    float ss = v0 * v0 + v1 * v1 + v2 * v2;
#pragma unroll
    for (int m = 1; m < 64; m <<= 1) ss += __shfl_xor(ss, m, 64);
    __shared__ float sred[4];
    if ((tid & 63) == 0) sred[tid >> 6] = ss;
    __syncthreads();
    const float tot = sred[0] + sred[1] + sred[2] + sred[3];
    const float rn = rsqrtf(tot * (1.0f / 768.0f) + 1e-6f);
    unsigned short* orow = s.dst + (size_t)b * 768;
    orow[tid]       = f2b(v0 * rn * a.wn1[tid]);
    orow[tid + 256] = f2b(v1 * rn * a.wn1[tid + 256]);
    orow[tid + 512] = f2b(v2 * rn * a.wn1[tid + 512]);
    return;
  }
  __shared__ float tile[32][33];
  const int tx = tid & 31, ty = tid >> 5;
  const int bn = b % s.nbn, bk = b / s.nbn;
#pragma unroll
  for (int i = 0; i < 32; i += 8)
    tile[ty + i][tx] = s.src[(size_t)(bk * 32 + ty + i) * s.N + bn * 32 + tx];
  __syncthreads();
  const float kscale = (s.mode == 1 || s.mode == 2) ? a.wn2[bk * 32 + tx] : 1.0f;
#pragma unroll
  for (int i = 0; i < 32; i += 8) {
    int row;
    if (s.mode == 0)      row = bn * 32 + ty + i;
    else                  row = bn * 64 + (s.mode == 2 ? 32 : 0) + ty + i;
    s.dst[(size_t)row * s.K + bk * 32 + tx] = f2b(tile[tx][ty + i] * kscale);
  }
}

// ---------------- GEMM template: BM x BN tile, 256 thr, 3-buffer counted-vmcnt, BK=32 ----
// LDS swizzle f(row) = (row&3)^((row>>2)&3): slot (row,c) holds global (row, c^f(row)).
// Reads XOR (l15&3)^((l15>>2)&3) -> 2 lanes/bank (free).
// EPI 2: bf16 store + RoPE (cols<1536) + Q pre-scale (cols<768); BM=BN=128
template <int EPI, int BM, int BN>
__global__ __launch_bounds__(256) void gemm_bt(const unsigned short* __restrict__ A,
    const unsigned short* __restrict__ Bt, unsigned short* __restrict__ Cb,
    float* __restrict__ Cf, const float* __restrict__ Rf, const unsigned short* __restrict__ Rb,
    int K, int ldc, const float* __restrict__ ct, const float* __restrict__ st, int nbn) {
  constexpr int ABYTES = BM * 32 * 2;
  constexpr int BBYTES = BN * 32 * 2;
  constexpr int APASS = BM / 64, BPASS = BN / 64;
  constexpr int LPS = APASS + BPASS;
  constexpr bool W2x2 = (BN == 128);
  constexpr int MR = W2x2 ? (BM / 32) : (BM / 64);
  __shared__ unsigned short As[3 * BM * 32];
  __shared__ unsigned short Bs[3 * BN * 32];
  const int tid = threadIdx.x;
  const int lane = tid & 63, wid = tid >> 6;
  const int wrow = W2x2 ? (wid >> 1) * (BM / 2) : wid * (BM / 4);
  const int wcol = W2x2 ? (wid & 1) * 64 : 0;
  const int l15 = lane & 15, l4 = lane >> 4;
  int bm, bn;
  xcd_remap(nbn, bm, bn);

  f4v acc[MR][4] = {};

  // staging: dest row = tid>>2, chunk = tid&3; source chunk ^= (row&3)^((row>>2)&3)
  const int r0 = tid >> 2;
  const int c0 = ((tid & 3) ^ (r0 & 3) ^ ((r0 >> 2) & 3)) * 16;
  const size_t ldab = (size_t)K * 2;
  const char* Abyte = (const char*)A;
  const char* Bbyte = (const char*)Bt;
  const size_t a0 = (size_t)(bm * BM + r0) * ldab + c0;
  const size_t a1 = (size_t)(bm * BM + (APASS == 2 ? r0 + 64 : r0)) * ldab + c0;
  const size_t b0 = (size_t)(bn * BN + r0) * ldab + c0;
  const size_t b1 = (size_t)(bn * BN + (BPASS == 2 ? r0 + 64 : r0)) * ldab + c0;
  char* AsB = (char*)As;
  char* BsB = (char*)Bs;
  const int uoff = wid << 10;
  const int rsw = (l4 ^ (l15 & 3) ^ ((l15 >> 2) & 3)) * 16;   // swizzled read chunk byte

#define STAGEK(I, SL) do { const size_t kb = (size_t)(I) * 64;                 \
    char* Aw = AsB + (SL) * ABYTES;                                            \
    char* Bw = BsB + (SL) * BBYTES;                                            \
    gl16(Abyte + a0 + kb, Aw + uoff);                                          \
    if constexpr (APASS == 2) gl16(Abyte + a1 + kb, Aw + uoff + 4096);         \
    gl16(Bbyte + b0 + kb, Bw + uoff);                                          \
    if constexpr (BPASS == 2) gl16(Bbyte + b1 + kb, Bw + uoff + 4096); } while (0)

  const int NI = K >> 5;
  STAGEK(0, 0);
  STAGEK(1, 1);
  int sel = 0, nsl = 2;

  for (int i = 0; i < NI; ++i) {
    if (i < NI - 1) {
      if constexpr (LPS == 4)      asm volatile("s_waitcnt vmcnt(4)" ::: "memory");
      else if constexpr (LPS == 3) asm volatile("s_waitcnt vmcnt(3)" ::: "memory");
      else                         asm volatile("s_waitcnt vmcnt(2)" ::: "memory");
    } else {
      asm volatile("s_waitcnt vmcnt(0)" ::: "memory");
    }
    __builtin_amdgcn_s_barrier();
    __builtin_amdgcn_sched_barrier(0);
    if (i + 2 < NI) STAGEK(i + 2, nsl);
    const char* Ar = AsB + sel * ABYTES;
    const char* Br = BsB + sel * BBYTES;
    s8v af[MR], bf[4];
#pragma unroll
    for (int m = 0; m < MR; ++m)
      af[m] = *(const s8v*)(Ar + (wrow + m * 16 + l15) * 64 + rsw);
#pragma unroll
    for (int n = 0; n < 4; ++n)
      bf[n] = *(const s8v*)(Br + (wcol + n * 16 + l15) * 64 + rsw);
    __builtin_amdgcn_s_setprio(1);
#pragma unroll
    for (int m = 0; m < MR; ++m)
#pragma unroll
      for (int n = 0; n < 4; ++n) acc[m][n] = MFMA16(af[m], bf[n], acc[m][n]);
    __builtin_amdgcn_s_setprio(0);
    sel = (sel == 2) ? 0 : sel + 1;
    nsl = (nsl == 2) ? 0 : nsl + 1;
  }
#undef STAGEK

  const int row0 = bm * BM + wrow;
  const int col0 = bn * BN + wcol;

  if constexpr (EPI == 2) {        // RoPE + Q pre-scale (BN=128: wave spans one head)
    const int colw = col0;
    if (colw < 1536) {             // q|k region: RoPE
#pragma unroll
      for (int m = 0; m < MR; ++m)
#pragma unroll
        for (int r = 0; r < 4; ++r) {
          const int row = row0 + m * 16 + l4 * 4 + r;
#pragma unroll
          for (int n = 0; n < 2; ++n) {
            const int d = n * 16 + l15;
            const float c  = ct[row * 32 + d];
            const float sn = st[row * 32 + d];
            const float aa = acc[m][n][r], bb = acc[m][n + 2][r];
            acc[m][n][r]     = aa * c - bb * sn;
            acc[m][n + 2][r] = bb * c + aa * sn;
          }
        }
    }
    if (colw < 768) {              // q region: pre-scale by 0.125*log2e
      const float QSC = 0.18033688011112042f;
#pragma unroll
      for (int m = 0; m < MR; ++m)
#pragma unroll
        for (int n = 0; n < 4; ++n)
#pragma unroll
          for (int r = 0; r < 4; ++r) acc[m][n][r] *= QSC;
    }
  }

#pragma unroll
  for (int m = 0; m < MR; ++m)
#pragma unroll
    for (int n = 0; n < 4; ++n)
#pragma unroll
      for (int r = 0; r < 4; ++r) {
        const int row = row0 + m * 16 + l4 * 4 + r;
        const int col = col0 + n * 16 + l15;
        Cb[(size_t)row * ldc + col] = f2b(acc[m][n][r]);
      }
}

// ---------------- 64x64 GEMM, BK=64 (128B rows): swizzle chunk^(row&7) -> 2-way free ----
// EPI 4: bf16 store of h=(v+Rf[fp32]) + atomic row-sum of h^2 into ssq (wo)
// EPI 5: fp32 store of (v + b2f(Rb[bf16]))  (down + residual -> d_out)
template <int EPI>
__global__ __launch_bounds__(256) void gemm_k64(const unsigned short* __restrict__ A,
    const unsigned short* __restrict__ Bt, unsigned short* __restrict__ Cb,
    float* __restrict__ Cf, const float* __restrict__ Rf, const unsigned short* __restrict__ Rb,
    float* __restrict__ ssq, int K, int ldc, int nbn) {
  constexpr int TBYTES = 64 * 64 * 2;   // 8 KB per operand per stage
  __shared__ unsigned short As[3 * 64 * 64];
  __shared__ unsigned short Bs[3 * 64 * 64];
  const int tid = threadIdx.x;
  const int lane = tid & 63, wid = tid >> 6;
  const int wrow = wid * 16;
  const int l15 = lane & 15, l4 = lane >> 4;
  int bm, bn;
  xcd_remap(nbn, bm, bn);

  f4v acc[4] = {};

  // staging: dest row = tid>>3, chunk = tid&7; source chunk ^= row&7
  const int r0 = tid >> 3;
  const int c0 = ((tid & 7) ^ (r0 & 7)) * 16;
  const size_t ldab = (size_t)K * 2;
  const char* Abyte = (const char*)A;
  const char* Bbyte = (const char*)Bt;
  const size_t a0 = (size_t)(bm * 64 + r0) * ldab + c0;
  const size_t a1 = (size_t)(bm * 64 + 32 + r0) * ldab + c0;
  const size_t b0 = (size_t)(bn * 64 + r0) * ldab + c0;
  const size_t b1 = (size_t)(bn * 64 + 32 + r0) * ldab + c0;
  char* AsB = (char*)As;
  char* BsB = (char*)Bs;
  const int uoff = wid << 10;
  const int s7 = l15 & 7;                  // row&7 for fragment reads

#define STAGEK(I, SL) do { const size_t kb = (size_t)(I) * 128;                \
    char* Aw = AsB + (SL) * TBYTES;                                            \
    char* Bw = BsB + (SL) * TBYTES;                                            \
    gl16(Abyte + a0 + kb, Aw + uoff);                                          \
    gl16(Abyte + a1 + kb, Aw + uoff + 4096);                                   \
    gl16(Bbyte + b0 + kb, Bw + uoff);                                          \
    gl16(Bbyte + b1 + kb, Bw + uoff + 4096); } while (0)

  const int NI = K >> 6;
  STAGEK(0, 0);
  STAGEK(1, 1);
  int sel = 0, nsl = 2;

  for (int i = 0; i < NI; ++i) {
    if (i < NI - 1) asm volatile("s_waitcnt vmcnt(4)" ::: "memory");
    else            asm volatile("s_waitcnt vmcnt(0)" ::: "memory");
    __builtin_amdgcn_s_barrier();
    __builtin_amdgcn_sched_barrier(0);
    if (i + 2 < NI) STAGEK(i + 2, nsl);
    const char* Ar = AsB + sel * TBYTES;
    const char* Br = BsB + sel * TBYTES;
#pragma unroll
    for (int kk = 0; kk < 2; ++kk) {
      const int ch = ((kk * 4 + l4) ^ s7) * 16;      // swizzled chunk byte
      const s8v af = *(const s8v*)(Ar + (wrow + l15) * 128 + ch);
      s8v bf[4];
#pragma unroll
      for (int n = 0; n < 4; ++n)
        bf[n] = *(const s8v*)(Br + (n * 16 + l15) * 128 + ch);
      __builtin_amdgcn_s_setprio(1);
#pragma unroll
      for (int n = 0; n < 4; ++n) acc[n] = MFMA16(af, bf[n], acc[n]);
      __builtin_amdgcn_s_setprio(0);
    }
    sel = (sel == 2) ? 0 : sel + 1;
    nsl = (nsl == 2) ? 0 : nsl + 1;
  }
#undef STAGEK

  const int row0 = bm * 64 + wrow;
  const int col0 = bn * 64;
#pragma unroll
  for (int r = 0; r < 4; ++r) {
    const int row = row0 + l4 * 4 + r;
    float ps = 0.f;
#pragma unroll
    for (int n = 0; n < 4; ++n) {
      const int col = col0 + n * 16 + l15;
      const float v = acc[n][r];
      const size_t idx = (size_t)row * ldc + col;
      if (EPI == 4) {
        const float hv = v + Rf[idx];
        Cb[idx] = f2b(hv);
        ps += hv * hv;
      } else {
        Cf[idx] = v + b2f(Rb[idx]);
      }
    }
    if (EPI == 4) {                 // reduce over the 16 l15 lanes -> one atomic per (row, block)
#pragma unroll
      for (int mm = 1; mm < 16; mm <<= 1) ps += __shfl_xor(ps, mm, 64);
      if (l15 == 0) atomicAdd(&ssq[row], ps);
    }
  }
}

// ---------------- big GEMM: 256(M)x128(N) tile, 512 thr, 8 waves (4Mx2N), BK=32 ----------------
// LDS swizzle f(row) = (row&3)^((row>>2)&3). EPI 3: rn-scaled silu(g)*u; rn inline from ssq.
template <int EPI>
__global__ __launch_bounds__(512, 2) void gemm_big(const unsigned short* __restrict__ A,
    const unsigned short* __restrict__ Bt, unsigned short* __restrict__ Cb,
    const float* __restrict__ ssq, int K, int ldc, int nbn) {
  constexpr int ABYTES = 256 * 32 * 2;
  constexpr int BBYTES = 128 * 32 * 2;
  __shared__ unsigned short As[3 * 256 * 32];
  __shared__ unsigned short Bs[3 * 128 * 32];
  const int tid = threadIdx.x;
  const int lane = tid & 63, wid = tid >> 6;
  const int wm = wid >> 1, wn = wid & 1;
  const int wrow = wm * 64, wcol = wn * 64;
  const int l15 = lane & 15, l4 = lane >> 4;
  int bm, bn;
  xcd_remap(nbn, bm, bn);

  f4v acc[4][4] = {};

  const size_t ldab = (size_t)K * 2;
  const char* Ab = (const char*)A;
  const char* Bb = (const char*)Bt;
  const int lrow = lane >> 2;
  const int lch = ((lane & 3) ^ (lrow & 3) ^ ((lrow >> 2) & 3)) * 16;  // source chunk ^= f(row)
  const size_t aS0 = (size_t)(bm * 256 + wid * 16 + lrow) * ldab + lch;
  const size_t aS1 = (size_t)(bm * 256 + (wid + 8) * 16 + lrow) * ldab + lch;
  const size_t bS  = (size_t)(bn * 128 + wid * 16 + lrow) * ldab + lch;
  char* AsB = (char*)As;
  char* BsB = (char*)Bs;
  const int uA0 = wid << 10, uA1 = (wid + 8) << 10, uB = wid << 10;
  const int rsw = (l4 ^ (l15 & 3) ^ ((l15 >> 2) & 3)) * 16;            // swizzled read chunk

#define STAGEK(I, SL) do { const size_t kb = (size_t)(I) * 64;                 \
    gl16(Ab + aS0 + kb, AsB + (SL) * ABYTES + uA0);                            \
    gl16(Ab + aS1 + kb, AsB + (SL) * ABYTES + uA1);                            \
    gl16(Bb + bS  + kb, BsB + (SL) * BBYTES + uB); } while (0)

  const int NI = K >> 5;
  STAGEK(0, 0);
  STAGEK(1, 1);
  int sel = 0, nsl = 2;

  for (int i = 0; i < NI; ++i) {
    if (i < NI - 1) asm volatile("s_waitcnt vmcnt(3)" ::: "memory");
    else            asm volatile("s_waitcnt vmcnt(0)" ::: "memory");
    __builtin_amdgcn_s_barrier();
    __builtin_amdgcn_sched_barrier(0);
    if (i + 2 < NI) STAGEK(i + 2, nsl);
    const char* Ar = AsB + sel * ABYTES;
    const char* Br = BsB + sel * BBYTES;
    s8v af[4], bf[4];
#pragma unroll
    for (int m = 0; m < 4; ++m)
      af[m] = *(const s8v*)(Ar + (wrow + m * 16 + l15) * 64 + rsw);
#pragma unroll
    for (int n = 0; n < 4; ++n)
      bf[n] = *(const s8v*)(Br + (wcol + n * 16 + l15) * 64 + rsw);
    __builtin_amdgcn_s_setprio(1);
#pragma unroll
    for (int m = 0; m < 4; ++m)
#pragma unroll
      for (int n = 0; n < 4; ++n) acc[m][n] = MFMA16(af[m], bf[n], acc[m][n]);
    __builtin_amdgcn_s_setprio(0);
    sel = (sel == 2) ? 0 : sel + 1;
    nsl = (nsl == 2) ? 0 : nsl + 1;
  }
#undef STAGEK

  const int row0 = bm * 256 + wrow;
  const int col0 = bn * 128 + wcol;

  if (EPI == 3) {                  // val = silu(rn*g) * (rn*u); rn from ssq
    const int colb = (bn * 2 + wn) * 32;
#pragma unroll
    for (int m = 0; m < 4; ++m)
#pragma unroll
      for (int r = 0; r < 4; ++r) {
        const int row = row0 + m * 16 + l4 * 4 + r;
        const float rn = rsqrtf(ssq[row] * (1.0f / 768.0f) + 1e-6f);
#pragma unroll
        for (int n = 0; n < 2; ++n) {
          const float g = acc[m][n][r] * rn, u = acc[m][n + 2][r] * rn;
          const float val = g * u / (1.0f + __expf(-g));
          Cb[(size_t)row * 2048 + colb + n * 16 + l15] = f2b(val);
        }
      }
    return;
  }

#pragma unroll
  for (int m = 0; m < 4; ++m)
#pragma unroll
    for (int n = 0; n < 4; ++n)
#pragma unroll
      for (int r = 0; r < 4; ++r) {
        const int row = row0 + m * 16 + l4 * 4 + r;
        const int col = col0 + n * 16 + l15;
        Cb[(size_t)row * ldc + col] = f2b(acc[m][n][r]);
      }
}

// ---------------- causal flash attention: 32x32 swapped-QK, 2-way parity, NO online max ----------------
__global__ __launch_bounds__(256, 4) void flash_k(const unsigned short* __restrict__ qkv,
    uint2* __restrict__ Opart, float* __restrict__ ml) {
  const int kh = blockIdx.x, p = blockIdx.y, h = blockIdx.z;
  const int qbA = 63 - p;
  const int tid = threadIdx.x;
  const int wv = tid >> 6, lane = tid & 63;
  const int l31 = lane & 31, h8 = lane >> 5;
  const int myqb = (wv & 1) ? p : qbA;
  const int qrel = (wv >> 1) * 32 + l31;
  const int q_abs = myqb * 64 + qrel;

  __shared__ unsigned short Ks[2][64 * 72];
  __shared__ unsigned short Vt[2][64 * 72];

  const unsigned short* qp = qkv + h * 64;
  const unsigned short* kp = qkv + 768 + h * 64;
  const unsigned short* vp = qkv + 1536 + h * 64;

  s8v qf[4];
#pragma unroll
  for (int cc = 0; cc < 4; ++cc)
    qf[cc] = *(const s8v*)(qp + (size_t)q_abs * 2304 + cc * 16 + h8 * 8);

  f16v o0 = {}, o1 = {};
  float lp = 0.f;

  const int krow = tid >> 3, kc = (tid & 7) * 8;
  const int vj = tid & 31, vd0 = (tid >> 5) * 8;

  s8v ka, kb, va, vb;
#define LOADT(T) do { const size_t k0n = (size_t)(T) * 64;                    \
    ka = *(const s8v*)(kp + (k0n + krow) * 2304 + kc);                        \
    kb = *(const s8v*)(kp + (k0n + krow + 32) * 2304 + kc);                   \
    va = *(const s8v*)(vp + (k0n + 2 * vj) * 2304 + vd0);                     \
    vb = *(const s8v*)(vp + (k0n + 2 * vj + 1) * 2304 + vd0); } while (0)
#define WRITET(BUF) do {                                                      \
    *(s8v*)(Ks[BUF] + krow * 72 + kc) = ka;                                   \
    *(s8v*)(Ks[BUF] + (krow + 32) * 72 + kc) = kb;                            \
    unsigned* vtw = (unsigned*)(Vt[BUF] + (size_t)vd0 * 72 + 2 * vj);         \
    _Pragma("unroll")                                                         \
    for (int i = 0; i < 8; ++i)                                               \
      vtw[i * 36] = ((unsigned)(unsigned short)va[i]) |                       \
                    (((unsigned)(unsigned short)vb[i]) << 16); } while (0)

  LOADT(kh);
  WRITET(0);
  if (kh + 2 <= qbA) LOADT(kh + 2);
  __syncthreads();

  for (int t = kh; t <= qbA; t += 2) {
    const int cur = (t >> 1) & 1;
    if (t <= myqb) {
      f16v s0 = {}, s1 = {};
      __builtin_amdgcn_s_setprio(1);
#pragma unroll
      for (int cc = 0; cc < 4; ++cc) {
        const s8v kf0 = *(const s8v*)(Ks[cur] + l31 * 72 + cc * 16 + h8 * 8);
        const s8v kf1 = *(const s8v*)(Ks[cur] + (32 + l31) * 72 + cc * 16 + h8 * 8);
        s0 = MFMA32(kf0, qf[cc], s0);
        s1 = MFMA32(kf1, qf[cc], s1);
      }
      __builtin_amdgcn_s_setprio(0);
      if (t == myqb) {
#pragma unroll
        for (int rr = 0; rr < 16; ++rr) {
          const int koff = (rr & 3) + 8 * (rr >> 2) + 4 * h8;
          if (koff > qrel) s0[rr] = -1e30f;
          if (koff + 32 > qrel) s1[rr] = -1e30f;
        }
      }
#pragma unroll
      for (int rr = 0; rr < 16; ++rr) {
        s0[rr] = exp2f(s0[rr]);
        s1[rr] = exp2f(s1[rr]);
      }
      float sm[8];
#pragma unroll
      for (int i = 0; i < 8; ++i) sm[i] = (s0[i] + s0[i + 8]) + (s1[i] + s1[i + 8]);
#pragma unroll
      for (int i = 0; i < 4; ++i) sm[i] += sm[i + 4];
      lp += (sm[0] + sm[1]) + (sm[2] + sm[3]);

      unsigned pk0[8], pk1[8];
#pragma unroll
      for (int g = 0; g < 4; ++g)
#pragma unroll
        for (int j = 0; j < 2; ++j) {
          pk0[g * 2 + j] = pk2(s0[g * 4 + 2 * j], s0[g * 4 + 2 * j + 1]);
          pk1[g * 2 + j] = pk2(s1[g * 4 + 2 * j], s1[g * 4 + 2 * j + 1]);
        }
      __builtin_amdgcn_s_setprio(1);
#pragma unroll
      for (int cc = 0; cc < 4; ++cc) {
        const int g0 = (cc & 1) * 2, g1 = g0 + 1;
        const unsigned pA0 = (cc & 2) ? pk1[g0 * 2 + 0] : pk0[g0 * 2 + 0];
        const unsigned pA1 = (cc & 2) ? pk1[g0 * 2 + 1] : pk0[g0 * 2 + 1];
        const unsigned pB0 = (cc & 2) ? pk1[g1 * 2 + 0] : pk0[g1 * 2 + 0];
        const unsigned pB1 = (cc & 2) ? pk1[g1 * 2 + 1] : pk0[g1 * 2 + 1];
        const unsigned t00 = __shfl_xor((int)pA0, 32);
        const unsigned t01 = __shfl_xor((int)pA1, 32);
        const unsigned t10 = __shfl_xor((int)pB0, 32);
        const unsigned t11 = __shfl_xor((int)pB1, 32);
        union { u4v u; s8v s; } pf;
        pf.u[0] = h8 ? t10 : pA0;
        pf.u[1] = h8 ? t11 : pA1;
        pf.u[2] = h8 ? pB0 : t00;
        pf.u[3] = h8 ? pB1 : t01;
        const s8v vf0 = *(const s8v*)(Vt[cur] + l31 * 72 + cc * 16 + h8 * 8);
        const s8v vf1 = *(const s8v*)(Vt[cur] + (32 + l31) * 72 + cc * 16 + h8 * 8);
        o0 = MFMA32(vf0, pf.s, o0);
        o1 = MFMA32(vf1, pf.s, o1);
      }
      __builtin_amdgcn_s_setprio(0);
    }
    if (t + 2 <= qbA) {
      WRITET(cur ^ 1);
      if (t + 4 <= qbA) LOADT(t + 4);
      __syncthreads();
    }
  }

  lp += __shfl_xor(lp, 32);

  const size_t obase = ((size_t)kh * 12 + h) * 16 * 4096;
#pragma unroll
  for (int g = 0; g < 4; ++g) {
    const uint2 v0 = make_uint2(pk2(o0[g * 4], o0[g * 4 + 1]), pk2(o0[g * 4 + 2], o0[g * 4 + 3]));
    const uint2 v1 = make_uint2(pk2(o1[g * 4], o1[g * 4 + 1]), pk2(o1[g * 4 + 2], o1[g * 4 + 3]));
    Opart[obase + (size_t)(2 * g + h8) * 4096 + q_abs] = v0;
    Opart[obase + (size_t)(8 + 2 * g + h8) * 4096 + q_abs] = v1;
  }
  if (h8 == 0)
    ml[((size_t)kh * 12 + h) * 4096 + q_abs] = lp;
#undef LOADT
#undef WRITET
}

// ---------------- combine 2 key-parity partials -> attn bf16 [q][768]; zero ssq ----------------
__global__ __launch_bounds__(256) void combine_k(const uint2* __restrict__ Opart,
    const float* __restrict__ ml, unsigned short* __restrict__ out, float* __restrict__ ssq) {
  const int u = blockIdx.x * 256 + threadIdx.x;
  if (u < 4096) ssq[u] = 0.f;      // zero accumulator for wo's atomic row-sums
  const int q = u & 4095;
  const int rest = u >> 12;
  const int dgrp = rest & 15;
  const int h = rest >> 4;
  const float l0 = ml[h * 4096 + q];
  const float l1 = ml[12 * 4096 + h * 4096 + q];
  const float inv = 1.0f / (l0 + l1);
  const size_t idx = ((size_t)h * 16 + dgrp) * 4096 + q;
  const uint2 a = Opart[idx];
  const uint2 b = Opart[(size_t)12 * 16 * 4096 + idx];
  const int dbase = (dgrp < 8) ? 4 * dgrp : 32 + 4 * (dgrp - 8);
  ushort4 r;
  r.x = f2b((b2f(a.x) + b2f(b.x)) * inv);
  r.y = f2b((b2f(a.x >> 16) + b2f(b.x >> 16)) * inv);
  r.z = f2b((b2f(a.y) + b2f(b.y)) * inv);
  r.w = f2b((b2f(a.y >> 16) + b2f(b.y >> 16)) * inv);
  *(ushort4*)(out + (size_t)q * 768 + h * 64 + dbase) = r;
}

extern "C" void kernel_launch(void* const* d_in, const int* in_sizes, int n_in,
                              void* d_out, int out_size, void* d_ws, size_t ws_size,
                              hipStream_t stream) {
  const float* x    = (const float*)d_in[0];
  const float* w_q  = (const float*)d_in[1];
  const float* w_k  = (const float*)d_in[2];
  const float* w_v  = (const float*)d_in[3];
  const float* w_o  = (const float*)d_in[4];
  const float* w_g  = (const float*)d_in[5];
  const float* w_u  = (const float*)d_in[6];
  const float* w_d  = (const float*)d_in[7];
  const float* w_n1 = (const float*)d_in[8];
  const float* w_n2 = (const float*)d_in[9];
  (void)in_sizes; (void)n_in; (void)out_size; (void)ws_size;

  char* ws = (char*)d_ws;
  size_t off = 0;
  auto alloc = [&](size_t bytes) { char* p = ws + off; off += (bytes + 255) & ~(size_t)255; return p; };
  unsigned short* wqkvT = (unsigned short*)alloc(2304ull * 768 * 2);
  unsigned short* woT   = (unsigned short*)alloc(768ull * 768 * 2);
  unsigned short* wguT  = (unsigned short*)alloc(4096ull * 768 * 2);
  unsigned short* wdT   = (unsigned short*)alloc(768ull * 2048 * 2);
  float* ct             = (float*)alloc(4096ull * 32 * 4);
  float* st             = (float*)alloc(4096ull * 32 * 4);
  unsigned short* xn    = (unsigned short*)alloc(4096ull * 768 * 2);
  unsigned short* qkv   = (unsigned short*)alloc(4096ull * 2304 * 2);
  unsigned short* attn  = (unsigned short*)alloc(4096ull * 768 * 2);
  unsigned short* hb16  = (unsigned short*)alloc(4096ull * 768 * 2);
  float* ssq            = (float*)alloc(4096ull * 4);
  unsigned short* ffn   = (unsigned short*)alloc(4096ull * 2048 * 2);
  uint2* Opart          = (uint2*)alloc(2ull * 12 * 16 * 4096 * 8);
  float* mlb            = (float*)alloc(2ull * 12 * 4096 * 4);

  PrepArgs pa;
  pa.seg[0] = { w_q, wqkvT,                 768,  768, 24,  576, 0 };
  pa.seg[1] = { w_k, wqkvT + 768 * 768,     768,  768, 24,  576, 0 };
  pa.seg[2] = { w_v, wqkvT + 2 * 768 * 768, 768,  768, 24,  576, 0 };
  pa.seg[3] = { w_o, woT,                   768,  768, 24,  576, 0 };
  pa.seg[4] = { w_g, wguT,                  768, 2048, 64, 1536, 1 };
  pa.seg[5] = { w_u, wguT,                  768, 2048, 64, 1536, 2 };
  pa.seg[6] = { w_d, wdT,                  2048,  768, 24, 1536, 0 };
  pa.seg[7] = { nullptr, nullptr, 0, 0, 0, 512, 3 };
  pa.seg[8] = { x, xn, 0, 0, 0, 4096, 4 };
  pa.ct = ct; pa.st = st; pa.wn1 = w_n1; pa.wn2 = w_n2;
  const int prep_blocks = 576 * 4 + 1536 * 3 + 512 + 4096;   // 11520

  prep_k<<<prep_blocks, 256, 0, stream>>>(pa);
  // qkv = xn @ [Wq|Wk|Wv] + RoPE + Q pre-scale; 576 blocks = 32(M/128) x 18(N/128)
  gemm_bt<2, 128, 128><<<576, 256, 0, stream>>>(xn, wqkvT, qkv, nullptr, nullptr, nullptr, 768, 2304, ct, st, 18);
  flash_k<<<dim3(2, 32, 12), 256, 0, stream>>>(qkv, Opart, mlb);
  combine_k<<<3072, 256, 0, stream>>>(Opart, mlb, attn, ssq);
  // h = attn @ Wo + x (bf16) + atomic row-sums of h^2; BK=64, 768 blocks, 3/CU
  gemm_k64<4><<<768, 256, 0, stream>>>(attn, woT, hb16, nullptr, x, nullptr, ssq, 768, 768, 12);
  // ffn = silu(rn*(h@Wg'))*(rn*(h@Wu')), rn inline from ssq; 512 blocks = 16 x 32
  gemm_big<3><<<512, 512, 0, stream>>>(hb16, wguT, ffn, ssq, 768, 2048, 32);
  // out = ffn @ Wd + h(bf16); BK=64, 768 blocks, 3/CU
  gemm_k64<5><<<768, 256, 0, stream>>>(ffn, wdT, nullptr, (float*)d_out, nullptr, hb16, nullptr, 2048, 768, 12);
}